// Round 15
// baseline (1684.221 us; speedup 1.0000x reference)
//
#include <hip/hip_runtime.h>
#include <hip/hip_bf16.h>

// B=8, S=1024, D=1024, H=16, DK=DV=64. TEMPER=32.
// CONFIRMED CONTRACT (r14 telemetry): documented input order
//   d_in = q,k,v (fp32 8,1024,1024), attn_mask (int32-or-byte, d3), w_qs,w_ks,w_vs
//   (fp32 16,1024,64 [h][d][kk]), proj_w (fp32 1024,1024 [out,in]), proj_b, ln_g, ln_b (fp32)
// d_out = FLOAT32: out (8,1024,1024) then attns (128,1024,1024)  [570 MB]
//
// Pipeline: fp32->bf16 at MFMA boundaries; all global outputs fp32.
// Path A (ws_size >= 73.4 MB): all intermediates in d_ws.
// Path B: stash in attn tail chunks (116..127), 2-batch scores/pv, reloc tail
//   slices into out-region upper bytes, cascade-phased in-place outproj.

typedef __bf16 bf16x8 __attribute__((ext_vector_type(8)));
typedef float f32x4 __attribute__((ext_vector_type(4)));

#define MFMA(a, b, c) __builtin_amdgcn_mfma_f32_16x16x32_bf16(a, b, c, 0, 0, 0)

static __device__ __forceinline__ bf16x8 ld8(const __bf16* p) {
    return *reinterpret_cast<const bf16x8*>(p);
}
static __device__ __forceinline__ bf16x8 ld8f(const float* f) {
    float4 f0 = *reinterpret_cast<const float4*>(f);
    float4 f1 = *reinterpret_cast<const float4*>(f + 4);
    bf16x8 a;
    a[0] = (__bf16)f0.x; a[1] = (__bf16)f0.y; a[2] = (__bf16)f0.z; a[3] = (__bf16)f0.w;
    a[4] = (__bf16)f1.x; a[5] = (__bf16)f1.y; a[6] = (__bf16)f1.z; a[7] = (__bf16)f1.w;
    return a;
}

// w fp32 [h][d][kk] -> wT bf16 [h][kk][d], for wq/wk/wv (3 * 2^20 elems)
__global__ void transpose_w_kernel(const float* wq, const float* wk, const float* wv,
                                   __bf16* wqT, __bf16* wkT, __bf16* wvT) {
    int idx = blockIdx.x * 256 + threadIdx.x;
    int m   = idx >> 20;
    int rem = idx & 1048575;
    const float* in = (m == 0) ? wq : (m == 1) ? wk : wv;
    __bf16*     o   = (m == 0) ? wqT : (m == 1) ? wkT : wvT;
    int h = rem >> 16, e = rem & 65535;
    int d = e >> 6, kk = e & 63;
    o[h * 65536 + kk * 1024 + d] = (__bf16)in[rem];
}

// X fp32 (8192x1024) @ W (bf16 WT[n][k]) -> bf16. mode0: out[h][b][s][kk]; mode1: out[h][b][kk][s]
__global__ void proj_kernel(const float* __restrict__ X, const __bf16* __restrict__ WT,
                            __bf16* __restrict__ out, int mode) {
    int tid = threadIdx.x;
    int l = tid & 63, w = tid >> 6;
    int lr = l & 15, g = l >> 4;
    int m0 = blockIdx.x * 32 + (w >> 1) * 16;
    int n0 = blockIdx.y * 128 + (w & 1) * 64;

    f32x4 acc[4] = {};
    const float* Arow = X + (size_t)(m0 + lr) * 1024 + g * 8;
    for (int kb = 0; kb < 32; ++kb) {
        bf16x8 a = ld8f(Arow + kb * 32);
#pragma unroll
        for (int nt = 0; nt < 4; ++nt) {
            bf16x8 b = ld8(WT + (size_t)(n0 + nt * 16 + lr) * 1024 + kb * 32 + g * 8);
            acc[nt] = MFMA(a, b, acc[nt]);
        }
    }
#pragma unroll
    for (int nt = 0; nt < 4; ++nt) {
#pragma unroll
        for (int j = 0; j < 4; ++j) {
            int r = m0 + g * 4 + j;
            int n = n0 + nt * 16 + lr;
            size_t o;
            if (mode == 0)
                o = (size_t)(n >> 6) * 524288 + (size_t)(r >> 10) * 65536 + (size_t)(r & 1023) * 64 + (n & 63);
            else
                o = (size_t)(n >> 6) * 524288 + (size_t)(r >> 10) * 65536 + (size_t)(n & 63) * 1024 + (r & 1023);
            out[o] = (__bf16)acc[nt][j];
        }
    }
}

// scores + mask + softmax -> attns (FP32, final output). grid (64, nhb), block 256.
__global__ void scores_kernel(const __bf16* __restrict__ qsb, const __bf16* __restrict__ ksb,
                              size_t stride, int hb0, const void* __restrict__ mask,
                              float* __restrict__ attnF) {
    __shared__ float smem[16][1024];
    int rel = blockIdx.y;
    int hb  = hb0 + rel;
    int q0  = blockIdx.x * 16;
    int tid = threadIdx.x;
    int l = tid & 63, w = tid >> 6;
    int lr = l & 15, g = l >> 4;

    // wave-uniform mask dtype detection (int32 0/1 words never exceed 1)
    unsigned mw = ((const unsigned*)mask)[l];
    int bytemask = __any(mw > 1u) ? 1 : 0;

    const __bf16* qb = qsb + rel * stride + (size_t)q0 * 64;
    const __bf16* ks = ksb + rel * stride;
    bf16x8 a0 = ld8(qb + lr * 64 + g * 8);
    bf16x8 a1 = ld8(qb + lr * 64 + 32 + g * 8);

    for (int kt = 0; kt < 16; ++kt) {
        int kcol = w * 256 + kt * 16;
        const __bf16* bp = ks + (size_t)(kcol + lr) * 64 + g * 8;
        bf16x8 b0 = ld8(bp);
        bf16x8 b1 = ld8(bp + 32);
        f32x4 acc = {};
        acc = MFMA(a0, b0, acc);
        acc = MFMA(a1, b1, acc);
#pragma unroll
        for (int j = 0; j < 4; ++j) smem[g * 4 + j][kcol + lr] = acc[j] * 0.03125f;  // /32
    }
    __syncthreads();

    int row = tid >> 4, j16 = tid & 15;
    int b = hb & 7;
    size_t roff = ((size_t)b * 1024 + q0 + row) * 1024;
    const unsigned char* m8  = (const unsigned char*)mask + roff;
    const int*           m32 = (const int*)mask + roff;

    float mx = -INFINITY;
    for (int k = j16; k < 1024; k += 16) {
        float s = smem[row][k];
        bool mk = bytemask ? (m8[k] != 0) : (m32[k] != 0);
        if (mk) s = -INFINITY;
        smem[row][k] = s;
        mx = fmaxf(mx, s);
    }
#pragma unroll
    for (int m = 8; m >= 1; m >>= 1) mx = fmaxf(mx, __shfl_xor(mx, m));

    bool dead = (mx == -INFINITY);  // all-masked row: emit 0 instead of NaN
    float mxs = dead ? 0.f : mx;
    float sum = 0.f;
    for (int k = j16; k < 1024; k += 16) {
        float s = smem[row][k];
        float e = (s == -INFINITY) ? 0.f : __expf(s - mxs);
        smem[row][k] = e;
        sum += e;
    }
#pragma unroll
    for (int m = 8; m >= 1; m >>= 1) sum += __shfl_xor(sum, m);
    float inv = dead ? 0.f : 1.0f / sum;

    float* arow = attnF + (size_t)hb * 1048576 + (size_t)(q0 + row) * 1024;
    for (int k = j16; k < 1024; k += 16) arow[k] = smem[row][k] * inv;
}

// x[b][s][h*64+vv] (bf16) = attns[hb] (fp32) @ v_sT[hb] (bf16). grid (16, nhb), block 256.
__global__ void pv_kernel(const float* __restrict__ attnF, const __bf16* __restrict__ vsb,
                          size_t stride, int hb0, __bf16* __restrict__ x) {
    int rel = blockIdx.y;
    int hb  = hb0 + rel;
    int mt  = blockIdx.x;
    int tid = threadIdx.x;
    int l = tid & 63, w = tid >> 6;
    int lr = l & 15, g = l >> 4;
    int r0 = mt * 64 + w * 16;

    const float*  ab = attnF + (size_t)hb * 1048576;
    const __bf16* vb = vsb + rel * stride;
    f32x4 acc[4] = {};
    for (int kb = 0; kb < 32; ++kb) {
        bf16x8 a = ld8f(ab + (size_t)(r0 + lr) * 1024 + kb * 32 + g * 8);
#pragma unroll
        for (int nt = 0; nt < 4; ++nt) {
            bf16x8 b = ld8(vb + (size_t)(nt * 16 + lr) * 1024 + kb * 32 + g * 8);
            acc[nt] = MFMA(a, b, acc[nt]);
        }
    }
    int h = hb >> 3, b = hb & 7;
#pragma unroll
    for (int nt = 0; nt < 4; ++nt) {
#pragma unroll
        for (int j = 0; j < 4; ++j) {
            int s = r0 + g * 4 + j;
            int vv = nt * 16 + lr;
            x[(size_t)b * 1048576 + (size_t)s * 1024 + h * 64 + vv] = (__bf16)acc[nt][j];
        }
    }
}

// copy q_s/k_s/v_sT tail slices (hb 116..127) into reloc buffer
__global__ void reloc_kernel(const __bf16* qs, const __bf16* ks, const __bf16* vs,
                             __bf16* rel) {
    int i = blockIdx.x * 256 + threadIdx.x;  // uint4 units: 12*3*8192 = 294912
    if (i >= 294912) return;
    int hbi = i / 24576;
    int r   = i % 24576;
    int t   = r / 8192, j = r % 8192;
    const __bf16* src = ((t == 0) ? qs : (t == 1) ? ks : vs) + (size_t)(116 + hbi) * 65536;
    __bf16* dst = rel + (size_t)hbi * 196608 + t * 65536;
    reinterpret_cast<uint4*>(dst)[j] = reinterpret_cast<const uint4*>(src)[j];
}

// out fp32 = LN(x @ proj_w.T + pb + q)*lg + lb.  Rows [row0, row0 + 16*gridDim.x).
__global__ void outproj_ln_kernel(const __bf16* __restrict__ x, const float* __restrict__ pw,
                                  const float* __restrict__ pb, const float* __restrict__ q,
                                  const float* __restrict__ lg, const float* __restrict__ lb,
                                  float* __restrict__ out, int row0) {
    __shared__ float smem[16][1024];
    int tid = threadIdx.x;
    int l = tid & 63, w = tid >> 6;
    int lr = l & 15, g = l >> 4;
    int r0 = row0 + blockIdx.x * 16;

    f32x4 acc[16] = {};
    for (int kb = 0; kb < 32; ++kb) {
        bf16x8 a = ld8(x + (size_t)(r0 + lr) * 1024 + kb * 32 + g * 8);
#pragma unroll
        for (int nt = 0; nt < 16; ++nt) {
            int n = w * 256 + nt * 16 + lr;
            bf16x8 b = ld8f(pw + (size_t)n * 1024 + kb * 32 + g * 8);
            acc[nt] = MFMA(a, b, acc[nt]);
        }
    }
#pragma unroll
    for (int nt = 0; nt < 16; ++nt) {
#pragma unroll
        for (int j = 0; j < 4; ++j) {
            int row = g * 4 + j;
            int col = w * 256 + nt * 16 + lr;
            float v = acc[nt][j] + pb[col] + q[(size_t)(r0 + row) * 1024 + col];
            smem[row][col] = v;
        }
    }
    __syncthreads();

    int row = tid >> 4, j16 = tid & 15;
    float s1 = 0.f, s2 = 0.f;
    for (int k = j16; k < 1024; k += 16) {
        float v = smem[row][k];
        s1 += v;
        s2 += v * v;
    }
#pragma unroll
    for (int m = 8; m >= 1; m >>= 1) {
        s1 += __shfl_xor(s1, m);
        s2 += __shfl_xor(s2, m);
    }
    float mu  = s1 * (1.0f / 1024.0f);
    float var = fmaxf(s2 * (1.0f / 1024.0f) - mu * mu, 0.f);
    float rs  = rsqrtf(var + 1e-5f);
    for (int k = j16; k < 1024; k += 16) {
        float v = (smem[row][k] - mu) * rs * lg[k] + lb[k];
        out[(size_t)(r0 + row) * 1024 + k] = v;
    }
}

extern "C" void kernel_launch(void* const* d_in, const int* in_sizes, int n_in,
                              void* d_out, int out_size, void* d_ws, size_t ws_size,
                              hipStream_t stream) {
    const float* Q  = (const float*)d_in[0];
    const float* K  = (const float*)d_in[1];
    const float* V  = (const float*)d_in[2];
    const void*  M  = d_in[3];
    const float* WQ = (const float*)d_in[4];
    const float* WK = (const float*)d_in[5];
    const float* WV = (const float*)d_in[6];
    const float* PW = (const float*)d_in[7];
    const float* PB = (const float*)d_in[8];
    const float* LG = (const float*)d_in[9];
    const float* LB = (const float*)d_in[10];

    float* outF  = (float*)d_out;           // 8,388,608 fp32
    float* attnF = outF + 8388608;          // 134,217,728 fp32 = 128 chunks of 1,048,576

    if (ws_size >= (size_t)73400320) {
        // ---------- Path A: all intermediates in d_ws ----------
        char* ws = (char*)d_ws;
        __bf16* wqT  = (__bf16*)ws;                        // 2 MB
        __bf16* wkT  = (__bf16*)(ws + 2097152);            // 2 MB
        __bf16* wvT  = (__bf16*)(ws + 4194304);            // 2 MB
        __bf16* q_s  = (__bf16*)(ws + 6291456);            // 16 MB [hb][s][kk]
        __bf16* k_s  = (__bf16*)(ws + 23068672);           // 16 MB
        __bf16* v_sT = (__bf16*)(ws + 39845888);           // 16 MB [hb][vv][s]
        __bf16* x    = (__bf16*)(ws + 56623104);           // 16 MB [b][s][h*64+vv]

        transpose_w_kernel<<<12288, 256, 0, stream>>>(WQ, WK, WV, wqT, wkT, wvT);
        proj_kernel<<<dim3(256, 8), 256, 0, stream>>>(Q, wqT, q_s, 0);
        proj_kernel<<<dim3(256, 8), 256, 0, stream>>>(K, wkT, k_s, 0);
        proj_kernel<<<dim3(256, 8), 256, 0, stream>>>(V, wvT, v_sT, 1);
        scores_kernel<<<dim3(64, 128), 256, 0, stream>>>(q_s, k_s, (size_t)65536, 0, M, attnF);
        pv_kernel<<<dim3(16, 128), 256, 0, stream>>>(attnF, v_sT, (size_t)65536, 0, x);
        outproj_ln_kernel<<<512, 256, 0, stream>>>(x, PW, PB, Q, LG, LB, outF, 0);
    } else {
        // ---------- Path B: scratch carved from d_out ----------
        // stash (bf16) in attn fp32 chunks 116..127; weights in chunks 0..2.
        __bf16* wqT  = (__bf16*)attnF;                          // 2 MB in chunk 0
        __bf16* wkT  = (__bf16*)(attnF + 1048576);              // chunk 1
        __bf16* wvT  = (__bf16*)(attnF + 2097152);              // chunk 2
        __bf16* q_s  = (__bf16*)(attnF + (size_t)116 * 1048576);  // chunks 116-119
        __bf16* k_s  = q_s + 8388608;                             // chunks 120-123
        __bf16* v_sT = k_s + 8388608;                             // chunks 124-127
        __bf16* x    = (__bf16*)outF;                     // out bytes [0, 16.7M)
        __bf16* rel  = (__bf16*)(outF + 4194304);         // out bytes [16.7M, 21.3M)

        transpose_w_kernel<<<12288, 256, 0, stream>>>(WQ, WK, WV, wqT, wkT, wvT);
        proj_kernel<<<dim3(256, 8), 256, 0, stream>>>(Q, wqT, q_s, 0);
        proj_kernel<<<dim3(256, 8), 256, 0, stream>>>(K, wkT, k_s, 0);
        proj_kernel<<<dim3(256, 8), 256, 0, stream>>>(V, wvT, v_sT, 1);
        // batch 1: hb in [0,116)
        scores_kernel<<<dim3(64, 116), 256, 0, stream>>>(q_s, k_s, (size_t)65536, 0, M, attnF);
        pv_kernel<<<dim3(16, 116), 256, 0, stream>>>(attnF, v_sT, (size_t)65536, 0, x);
        // relocate tail slices, then batch 2: hb in [116,128)
        reloc_kernel<<<1152, 256, 0, stream>>>(q_s, k_s, v_sT, rel);
        scores_kernel<<<dim3(64, 12), 256, 0, stream>>>(rel, rel + 65536, (size_t)196608, 116,
                                                        M, attnF);
        pv_kernel<<<dim3(16, 12), 256, 0, stream>>>(attnF, rel + 131072, (size_t)196608, 116, x);
        // cascade-phased in-place outproj: phase [J0,J1) with J1 <= 2*J0 so each
        // phase's fp32 writes (x rows [32*J0, 32*J1)) touch only already-consumed x.
        int J1 = 512;
        for (int J0 = 256;; J0 >>= 1) {
            outproj_ln_kernel<<<J1 - J0, 256, 0, stream>>>(x, PW, PB, Q, LG, LB,
                                                           outF, J0 * 16);
            J1 = J0;
            if (J0 == 0) break;
        }
    }
}

// Round 16
// 1378.834 us; speedup vs baseline: 1.2215x; 1.2215x over previous
//
#include <hip/hip_runtime.h>
#include <hip/hip_bf16.h>

// B=8, S=1024, D=1024, H=16, DK=DV=64. TEMPER=32.
// Contract (verified r15): documented input order, fp32 floats, int32-or-byte mask at d3,
// d_out FLOAT32: out (8,1024,1024) then attns (128,1024,1024).
// r16: fused scores+softmax+PV kernel (register softmax, bf16 P in LDS, no attns re-read).

typedef __bf16 bf16x8 __attribute__((ext_vector_type(8)));
typedef float f32x4 __attribute__((ext_vector_type(4)));

#define MFMA(a, b, c) __builtin_amdgcn_mfma_f32_16x16x32_bf16(a, b, c, 0, 0, 0)

static __device__ __forceinline__ bf16x8 ld8(const __bf16* p) {
    return *reinterpret_cast<const bf16x8*>(p);
}
static __device__ __forceinline__ bf16x8 ld8f(const float* f) {
    float4 f0 = *reinterpret_cast<const float4*>(f);
    float4 f1 = *reinterpret_cast<const float4*>(f + 4);
    bf16x8 a;
    a[0] = (__bf16)f0.x; a[1] = (__bf16)f0.y; a[2] = (__bf16)f0.z; a[3] = (__bf16)f0.w;
    a[4] = (__bf16)f1.x; a[5] = (__bf16)f1.y; a[6] = (__bf16)f1.z; a[7] = (__bf16)f1.w;
    return a;
}

// w fp32 [h][d][kk] -> wT bf16 [h][kk][d], for wq/wk/wv (3 * 2^20 elems)
__global__ void transpose_w_kernel(const float* wq, const float* wk, const float* wv,
                                   __bf16* wqT, __bf16* wkT, __bf16* wvT) {
    int idx = blockIdx.x * 256 + threadIdx.x;
    int m   = idx >> 20;
    int rem = idx & 1048575;
    const float* in = (m == 0) ? wq : (m == 1) ? wk : wv;
    __bf16*     o   = (m == 0) ? wqT : (m == 1) ? wkT : wvT;
    int h = rem >> 16, e = rem & 65535;
    int d = e >> 6, kk = e & 63;
    o[h * 65536 + kk * 1024 + d] = (__bf16)in[rem];
}

// X fp32 (8192x1024) @ W (bf16 WT[n][k]) -> bf16. mode0: out[h][b][s][kk]; mode1: out[h][b][kk][s]
__global__ void proj_kernel(const float* __restrict__ X, const __bf16* __restrict__ WT,
                            __bf16* __restrict__ out, int mode) {
    int tid = threadIdx.x;
    int l = tid & 63, w = tid >> 6;
    int lr = l & 15, g = l >> 4;
    int m0 = blockIdx.x * 32 + (w >> 1) * 16;
    int n0 = blockIdx.y * 128 + (w & 1) * 64;

    f32x4 acc[4] = {};
    const float* Arow = X + (size_t)(m0 + lr) * 1024 + g * 8;
    for (int kb = 0; kb < 32; ++kb) {
        bf16x8 a = ld8f(Arow + kb * 32);
#pragma unroll
        for (int nt = 0; nt < 4; ++nt) {
            bf16x8 b = ld8(WT + (size_t)(n0 + nt * 16 + lr) * 1024 + kb * 32 + g * 8);
            acc[nt] = MFMA(a, b, acc[nt]);
        }
    }
#pragma unroll
    for (int nt = 0; nt < 4; ++nt) {
#pragma unroll
        for (int j = 0; j < 4; ++j) {
            int r = m0 + g * 4 + j;
            int n = n0 + nt * 16 + lr;
            size_t o;
            if (mode == 0)
                o = (size_t)(n >> 6) * 524288 + (size_t)(r >> 10) * 65536 + (size_t)(r & 1023) * 64 + (n & 63);
            else
                o = (size_t)(n >> 6) * 524288 + (size_t)(r >> 10) * 65536 + (size_t)(n & 63) * 1024 + (r & 1023);
            out[o] = (__bf16)acc[nt][j];
        }
    }
}

// Fused scores + softmax + attns-write + PV. grid (64, nhb), block 256 = 4 waves.
// Register-resident scores; bf16 P tile in LDS (32 KB); x written directly.
__global__ void fused_attn_kernel(const __bf16* __restrict__ qsb, const __bf16* __restrict__ ksb,
                                  const __bf16* __restrict__ vsb, size_t stride, int hb0,
                                  const void* __restrict__ mask,
                                  float* __restrict__ attnF, __bf16* __restrict__ x) {
    __shared__ __bf16 P[16][1024];           // 32 KB
    __shared__ float redm[4][16], reds[4][16];

    int rel = blockIdx.y;
    int hb  = hb0 + rel;
    int q0  = blockIdx.x * 16;
    int tid = threadIdx.x;
    int l = tid & 63, w = tid >> 6;
    int lr = l & 15, g = l >> 4;

    // wave-uniform mask dtype detection (int32 0/1 words never exceed 1)
    unsigned mw = ((const unsigned*)mask)[l];
    int bytemask = __any(mw > 1u) ? 1 : 0;

    const __bf16* qb = qsb + rel * stride + (size_t)q0 * 64;
    const __bf16* ks = ksb + rel * stride;
    bf16x8 a0 = ld8(qb + lr * 64 + g * 8);
    bf16x8 a1 = ld8(qb + lr * 64 + 32 + g * 8);

    int b = hb & 7;
    const unsigned char* m8  = (const unsigned char*)mask;
    const int*           m32 = (const int*)mask;
    size_t mbase = ((size_t)b * 1024 + q0) * 1024;

    // Phase 1: QK^T -> registers, masked + scaled
    float s[16][4];
#pragma unroll
    for (int kt = 0; kt < 16; ++kt) {
        int kcol = w * 256 + kt * 16;
        const __bf16* bp = ks + (size_t)(kcol + lr) * 64 + g * 8;
        bf16x8 b0 = ld8(bp);
        bf16x8 b1 = ld8(bp + 32);
        f32x4 acc = {};
        acc = MFMA(a0, b0, acc);
        acc = MFMA(a1, b1, acc);
        int col = kcol + lr;
#pragma unroll
        for (int j = 0; j < 4; ++j) {
            size_t mi = mbase + (size_t)(g * 4 + j) * 1024 + col;
            bool mk = bytemask ? (m8[mi] != 0) : (m32[mi] != 0);
            s[kt][j] = mk ? -INFINITY : acc[j] * 0.03125f;  // /TEMPER
        }
    }

    // Phase 2a: row max (kt-chain, lr-group shfl, cross-wave LDS)
    float mx[4];
#pragma unroll
    for (int j = 0; j < 4; ++j) {
        float m = -INFINITY;
#pragma unroll
        for (int kt = 0; kt < 16; ++kt) m = fmaxf(m, s[kt][j]);
#pragma unroll
        for (int o = 8; o >= 1; o >>= 1) m = fmaxf(m, __shfl_xor(m, o));
        mx[j] = m;
    }
    if (lr == 0) {
#pragma unroll
        for (int j = 0; j < 4; ++j) redm[w][g * 4 + j] = mx[j];
    }
    __syncthreads();
#pragma unroll
    for (int j = 0; j < 4; ++j) {
        int row = g * 4 + j;
        mx[j] = fmaxf(fmaxf(redm[0][row], redm[1][row]), fmaxf(redm[2][row], redm[3][row]));
    }

    // Phase 2b: exp + row sum
    float sum[4];
#pragma unroll
    for (int j = 0; j < 4; ++j) {
        float m = (mx[j] == -INFINITY) ? 0.f : mx[j];
        float t = 0.f;
#pragma unroll
        for (int kt = 0; kt < 16; ++kt) {
            float e = (s[kt][j] == -INFINITY) ? 0.f : __expf(s[kt][j] - m);
            s[kt][j] = e;
            t += e;
        }
#pragma unroll
        for (int o = 8; o >= 1; o >>= 1) t += __shfl_xor(t, o);
        sum[j] = t;
    }
    if (lr == 0) {
#pragma unroll
        for (int j = 0; j < 4; ++j) reds[w][g * 4 + j] = sum[j];
    }
    __syncthreads();

    // Phase 3: normalize -> P (bf16, LDS)
#pragma unroll
    for (int j = 0; j < 4; ++j) {
        int row = g * 4 + j;
        float tot = reds[0][row] + reds[1][row] + reds[2][row] + reds[3][row];
        float inv = (mx[j] == -INFINITY) ? 0.f : 1.0f / tot;
#pragma unroll
        for (int kt = 0; kt < 16; ++kt)
            P[row][w * 256 + kt * 16 + lr] = (__bf16)(s[kt][j] * inv);
    }
    __syncthreads();

    // Phase 4: coalesced attns write (fp32 from bf16 P)
    float* abase = attnF + (size_t)hb * 1048576 + (size_t)q0 * 1024;
#pragma unroll
    for (int i = 0; i < 8; ++i) {
        int idx = i * 256 + tid;           // 0..2047 chunks of 8
        int row = idx >> 7;
        int c8  = (idx & 127) * 8;
        bf16x8 pv = *reinterpret_cast<const bf16x8*>(&P[row][c8]);
        float4 f0 = {(float)pv[0], (float)pv[1], (float)pv[2], (float)pv[3]};
        float4 f1 = {(float)pv[4], (float)pv[5], (float)pv[6], (float)pv[7]};
        float* dst = abase + (size_t)row * 1024 + c8;
        *reinterpret_cast<float4*>(dst)     = f0;
        *reinterpret_cast<float4*>(dst + 4) = f1;
    }

    // Phase 5: PV from LDS. Wave w -> vv cols [w*16, w*16+16)
    const __bf16* vb = vsb + rel * stride;
    f32x4 acc2 = {};
    for (int kb = 0; kb < 32; ++kb) {
        bf16x8 pa  = *reinterpret_cast<const bf16x8*>(&P[lr][kb * 32 + g * 8]);
        bf16x8 vb8 = ld8(vb + (size_t)(w * 16 + lr) * 1024 + kb * 32 + g * 8);
        acc2 = MFMA(pa, vb8, acc2);
    }
    int h = hb >> 3;
#pragma unroll
    for (int j = 0; j < 4; ++j) {
        int srow = q0 + g * 4 + j;
        int vv = w * 16 + lr;
        x[(size_t)b * 1048576 + (size_t)srow * 1024 + h * 64 + vv] = (__bf16)acc2[j];
    }
}

// copy q_s/k_s/v_sT tail slices (hb 116..127) into reloc buffer
__global__ void reloc_kernel(const __bf16* qs, const __bf16* ks, const __bf16* vs,
                             __bf16* rel) {
    int i = blockIdx.x * 256 + threadIdx.x;  // uint4 units: 12*3*8192 = 294912
    if (i >= 294912) return;
    int hbi = i / 24576;
    int r   = i % 24576;
    int t   = r / 8192, j = r % 8192;
    const __bf16* src = ((t == 0) ? qs : (t == 1) ? ks : vs) + (size_t)(116 + hbi) * 65536;
    __bf16* dst = rel + (size_t)hbi * 196608 + t * 65536;
    reinterpret_cast<uint4*>(dst)[j] = reinterpret_cast<const uint4*>(src)[j];
}

// out fp32 = LN(x @ proj_w.T + pb + q)*lg + lb.  Rows [row0, row0 + 16*gridDim.x).
__global__ void outproj_ln_kernel(const __bf16* __restrict__ x, const float* __restrict__ pw,
                                  const float* __restrict__ pb, const float* __restrict__ q,
                                  const float* __restrict__ lg, const float* __restrict__ lb,
                                  float* __restrict__ out, int row0) {
    __shared__ float smem[16][1024];
    int tid = threadIdx.x;
    int l = tid & 63, w = tid >> 6;
    int lr = l & 15, g = l >> 4;
    int r0 = row0 + blockIdx.x * 16;

    f32x4 acc[16] = {};
    for (int kb = 0; kb < 32; ++kb) {
        bf16x8 a = ld8(x + (size_t)(r0 + lr) * 1024 + kb * 32 + g * 8);
#pragma unroll
        for (int nt = 0; nt < 16; ++nt) {
            int n = w * 256 + nt * 16 + lr;
            bf16x8 b = ld8f(pw + (size_t)n * 1024 + kb * 32 + g * 8);
            acc[nt] = MFMA(a, b, acc[nt]);
        }
    }
#pragma unroll
    for (int nt = 0; nt < 16; ++nt) {
#pragma unroll
        for (int j = 0; j < 4; ++j) {
            int row = g * 4 + j;
            int col = w * 256 + nt * 16 + lr;
            float v = acc[nt][j] + pb[col] + q[(size_t)(r0 + row) * 1024 + col];
            smem[row][col] = v;
        }
    }
    __syncthreads();

    int row = tid >> 4, j16 = tid & 15;
    float s1 = 0.f, s2 = 0.f;
    for (int k = j16; k < 1024; k += 16) {
        float v = smem[row][k];
        s1 += v;
        s2 += v * v;
    }
#pragma unroll
    for (int m = 8; m >= 1; m >>= 1) {
        s1 += __shfl_xor(s1, m);
        s2 += __shfl_xor(s2, m);
    }
    float mu  = s1 * (1.0f / 1024.0f);
    float var = fmaxf(s2 * (1.0f / 1024.0f) - mu * mu, 0.f);
    float rs  = rsqrtf(var + 1e-5f);
    for (int k = j16; k < 1024; k += 16) {
        float v = (smem[row][k] - mu) * rs * lg[k] + lb[k];
        out[(size_t)(r0 + row) * 1024 + k] = v;
    }
}

extern "C" void kernel_launch(void* const* d_in, const int* in_sizes, int n_in,
                              void* d_out, int out_size, void* d_ws, size_t ws_size,
                              hipStream_t stream) {
    const float* Q  = (const float*)d_in[0];
    const float* K  = (const float*)d_in[1];
    const float* V  = (const float*)d_in[2];
    const void*  M  = d_in[3];
    const float* WQ = (const float*)d_in[4];
    const float* WK = (const float*)d_in[5];
    const float* WV = (const float*)d_in[6];
    const float* PW = (const float*)d_in[7];
    const float* PB = (const float*)d_in[8];
    const float* LG = (const float*)d_in[9];
    const float* LB = (const float*)d_in[10];

    float* outF  = (float*)d_out;           // 8,388,608 fp32
    float* attnF = outF + 8388608;          // 134,217,728 fp32 = 128 chunks of 1,048,576

    if (ws_size >= (size_t)73400320) {
        // ---------- Path A: all intermediates in d_ws ----------
        char* ws = (char*)d_ws;
        __bf16* wqT  = (__bf16*)ws;                        // 2 MB
        __bf16* wkT  = (__bf16*)(ws + 2097152);            // 2 MB
        __bf16* wvT  = (__bf16*)(ws + 4194304);            // 2 MB
        __bf16* q_s  = (__bf16*)(ws + 6291456);            // 16 MB [hb][s][kk]
        __bf16* k_s  = (__bf16*)(ws + 23068672);           // 16 MB
        __bf16* v_sT = (__bf16*)(ws + 39845888);           // 16 MB [hb][vv][s]
        __bf16* x    = (__bf16*)(ws + 56623104);           // 16 MB [b][s][h*64+vv]

        transpose_w_kernel<<<12288, 256, 0, stream>>>(WQ, WK, WV, wqT, wkT, wvT);
        proj_kernel<<<dim3(256, 8), 256, 0, stream>>>(Q, wqT, q_s, 0);
        proj_kernel<<<dim3(256, 8), 256, 0, stream>>>(K, wkT, k_s, 0);
        proj_kernel<<<dim3(256, 8), 256, 0, stream>>>(V, wvT, v_sT, 1);
        fused_attn_kernel<<<dim3(64, 128), 256, 0, stream>>>(q_s, k_s, v_sT, (size_t)65536, 0,
                                                             M, attnF, x);
        outproj_ln_kernel<<<512, 256, 0, stream>>>(x, PW, PB, Q, LG, LB, outF, 0);
    } else {
        // ---------- Path B: scratch carved from d_out ----------
        __bf16* wqT  = (__bf16*)attnF;                            // chunk 0
        __bf16* wkT  = (__bf16*)(attnF + 1048576);                // chunk 1
        __bf16* wvT  = (__bf16*)(attnF + 2097152);                // chunk 2
        __bf16* q_s  = (__bf16*)(attnF + (size_t)116 * 1048576);  // chunks 116-119
        __bf16* k_s  = q_s + 8388608;                             // chunks 120-123
        __bf16* v_sT = k_s + 8388608;                             // chunks 124-127
        __bf16* x    = (__bf16*)outF;                     // out bytes [0, 16.7M)
        __bf16* rel  = (__bf16*)(outF + 4194304);         // out bytes [16.7M, 21.3M)

        transpose_w_kernel<<<12288, 256, 0, stream>>>(WQ, WK, WV, wqT, wkT, wvT);
        proj_kernel<<<dim3(256, 8), 256, 0, stream>>>(Q, wqT, q_s, 0);
        proj_kernel<<<dim3(256, 8), 256, 0, stream>>>(K, wkT, k_s, 0);
        proj_kernel<<<dim3(256, 8), 256, 0, stream>>>(V, wvT, v_sT, 1);
        // batch 1: hb in [0,116)
        fused_attn_kernel<<<dim3(64, 116), 256, 0, stream>>>(q_s, k_s, v_sT, (size_t)65536, 0,
                                                             M, attnF, x);
        // relocate tail slices, then batch 2: hb in [116,128)
        reloc_kernel<<<1152, 256, 0, stream>>>(q_s, k_s, v_sT, rel);
        fused_attn_kernel<<<dim3(64, 12), 256, 0, stream>>>(rel, rel + 65536, rel + 131072,
                                                            (size_t)196608, 116, M, attnF, x);
        // cascade-phased in-place outproj (J1 <= 2*J0 keeps reads ahead of writes)
        int J1 = 512;
        for (int J0 = 256;; J0 >>= 1) {
            outproj_ln_kernel<<<J1 - J0, 256, 0, stream>>>(x, PW, PB, Q, LG, LB,
                                                           outF, J0 * 16);
            J1 = J0;
            if (J0 == 0) break;
        }
    }
}

// Round 17
// 1283.979 us; speedup vs baseline: 1.3117x; 1.0739x over previous
//
#include <hip/hip_runtime.h>
#include <hip/hip_bf16.h>

// B=8, S=1024, D=1024, H=16, DK=DV=64. TEMPER=32.
// Contract (verified r15/r16): documented input order, fp32 floats, i32-or-byte mask at d3,
// d_out FLOAT32: out (8,1024,1024) then attns (128,1024,1024).
// r17: fused kernel v2 -- two-pass recompute (no VGPR spill), mask bits cached in u64,
// unnormalized-P trick (inv applied at write/PV-epilogue), P padded [16][1040]
// (conflict-free PV reads), XCD-swizzled grid. Tiled transpose; bf16 proj_w copy.

typedef __bf16 bf16x8 __attribute__((ext_vector_type(8)));
typedef __bf16 bf16x4 __attribute__((ext_vector_type(4)));
typedef float f32x4 __attribute__((ext_vector_type(4)));

#define MFMA(a, b, c) __builtin_amdgcn_mfma_f32_16x16x32_bf16(a, b, c, 0, 0, 0)

static __device__ __forceinline__ bf16x8 ld8(const __bf16* p) {
    return *reinterpret_cast<const bf16x8*>(p);
}
static __device__ __forceinline__ bf16x8 ld8f(const float* f) {
    float4 f0 = *reinterpret_cast<const float4*>(f);
    float4 f1 = *reinterpret_cast<const float4*>(f + 4);
    bf16x8 a;
    a[0] = (__bf16)f0.x; a[1] = (__bf16)f0.y; a[2] = (__bf16)f0.z; a[3] = (__bf16)f0.w;
    a[4] = (__bf16)f1.x; a[5] = (__bf16)f1.y; a[6] = (__bf16)f1.z; a[7] = (__bf16)f1.w;
    return a;
}

// tiled w transpose: [h][d][kk] fp32 -> [h][kk][d] bf16. grid 768 = 3 tensors*16h*16 dblocks.
__global__ void transpose_w_kernel(const float* wq, const float* wk, const float* wv,
                                   __bf16* wqT, __bf16* wkT, __bf16* wvT) {
    __shared__ __bf16 tile[64][65];
    int bid = blockIdx.x;
    int m  = bid >> 8;
    int h  = (bid >> 4) & 15;
    int db = bid & 15;
    const float* in = (m == 0) ? wq : (m == 1) ? wk : wv;
    __bf16*     out = (m == 0) ? wqT : (m == 1) ? wkT : wvT;
    int t = threadIdx.x;
#pragma unroll
    for (int i = 0; i < 16; ++i) {
        int idx = i * 256 + t;
        int dd = idx >> 6, kk = idx & 63;
        tile[kk][dd] = (__bf16)in[h * 65536 + (db * 64 + dd) * 64 + kk];
    }
    __syncthreads();
#pragma unroll
    for (int i = 0; i < 16; ++i) {
        int idx = i * 256 + t;
        int kk = idx >> 6, dd = idx & 63;
        out[h * 65536 + kk * 1024 + db * 64 + dd] = tile[kk][dd];
    }
}

// proj_w fp32 -> bf16 copy (1M elems, 4/thread, grid 1024)
__global__ void convert_pw_kernel(const float* pw, __bf16* pwb) {
    int i = blockIdx.x * 256 + threadIdx.x;
    float4 f = *reinterpret_cast<const float4*>(pw + (size_t)i * 4);
    bf16x4 o;
    o[0] = (__bf16)f.x; o[1] = (__bf16)f.y; o[2] = (__bf16)f.z; o[3] = (__bf16)f.w;
    *reinterpret_cast<bf16x4*>(pwb + (size_t)i * 4) = o;
}

// X fp32 (8192x1024) @ W (bf16 WT[n][k]) -> bf16. mode0: out[h][b][s][kk]; mode1: out[h][b][kk][s]
__global__ void proj_kernel(const float* __restrict__ X, const __bf16* __restrict__ WT,
                            __bf16* __restrict__ out, int mode) {
    int tid = threadIdx.x;
    int l = tid & 63, w = tid >> 6;
    int lr = l & 15, g = l >> 4;
    int m0 = blockIdx.x * 32 + (w >> 1) * 16;
    int n0 = blockIdx.y * 128 + (w & 1) * 64;

    f32x4 acc[4] = {};
    const float* Arow = X + (size_t)(m0 + lr) * 1024 + g * 8;
    for (int kb = 0; kb < 32; ++kb) {
        bf16x8 a = ld8f(Arow + kb * 32);
#pragma unroll
        for (int nt = 0; nt < 4; ++nt) {
            bf16x8 b = ld8(WT + (size_t)(n0 + nt * 16 + lr) * 1024 + kb * 32 + g * 8);
            acc[nt] = MFMA(a, b, acc[nt]);
        }
    }
#pragma unroll
    for (int nt = 0; nt < 4; ++nt) {
#pragma unroll
        for (int j = 0; j < 4; ++j) {
            int r = m0 + g * 4 + j;
            int n = n0 + nt * 16 + lr;
            size_t o;
            if (mode == 0)
                o = (size_t)(n >> 6) * 524288 + (size_t)(r >> 10) * 65536 + (size_t)(r & 1023) * 64 + (n & 63);
            else
                o = (size_t)(n >> 6) * 524288 + (size_t)(r >> 10) * 65536 + (size_t)(n & 63) * 1024 + (r & 1023);
            out[o] = (__bf16)acc[nt][j];
        }
    }
}

// Fused scores+softmax+attns+PV, v2. 1-D grid n = 64*nhb (n % 8 == 0), XCD-swizzled.
__global__ void fused_attn_kernel(const __bf16* __restrict__ qsb, const __bf16* __restrict__ ksb,
                                  const __bf16* __restrict__ vsb, size_t stride, int hb0,
                                  const void* __restrict__ mask,
                                  float* __restrict__ attnF, __bf16* __restrict__ x) {
    __shared__ __bf16 P[16][1040];           // pad -> row stride 8 banks (mod 32)
    __shared__ float redm[4][16], reds[4][16];

    int nb = gridDim.x;
    int sb = (blockIdx.x & 7) * (nb >> 3) + (blockIdx.x >> 3);  // XCD swizzle (nb%8==0)
    int rel = sb >> 6;
    int q0  = (sb & 63) * 16;
    int hb  = hb0 + rel;
    int tid = threadIdx.x;
    int l = tid & 63, w = tid >> 6;
    int lr = l & 15, g = l >> 4;

    unsigned mw = ((const unsigned*)mask)[l];
    int bytemask = __any(mw > 1u) ? 1 : 0;

    const __bf16* qb = qsb + rel * stride + (size_t)q0 * 64;
    const __bf16* ks = ksb + rel * stride;
    bf16x8 a0 = ld8(qb + lr * 64 + g * 8);
    bf16x8 a1 = ld8(qb + lr * 64 + 32 + g * 8);

    int b = hb & 7;
    const unsigned char* m8  = (const unsigned char*)mask;
    const int*           m32 = (const int*)mask;
    size_t mbase = ((size_t)b * 1024 + q0) * 1024;

    // Pass 1: QK^T -> row max; cache mask decisions in a u64 (one bit per (kt,j))
    unsigned long long mbits = 0ull;
    float mx[4] = {-INFINITY, -INFINITY, -INFINITY, -INFINITY};
#pragma unroll
    for (int kt = 0; kt < 16; ++kt) {
        int kcol = w * 256 + kt * 16;
        const __bf16* bp = ks + (size_t)(kcol + lr) * 64 + g * 8;
        f32x4 acc = {};
        acc = MFMA(a0, ld8(bp), acc);
        acc = MFMA(a1, ld8(bp + 32), acc);
        int col = kcol + lr;
#pragma unroll
        for (int j = 0; j < 4; ++j) {
            size_t mi = mbase + (size_t)(g * 4 + j) * 1024 + col;
            bool mk = bytemask ? (m8[mi] != 0) : (m32[mi] != 0);
            if (mk) mbits |= (1ull << (kt * 4 + j));
            else    mx[j] = fmaxf(mx[j], acc[j] * 0.03125f);
        }
    }
#pragma unroll
    for (int j = 0; j < 4; ++j) {
#pragma unroll
        for (int o = 8; o >= 1; o >>= 1) mx[j] = fmaxf(mx[j], __shfl_xor(mx[j], o));
    }
    if (lr == 0) {
#pragma unroll
        for (int j = 0; j < 4; ++j) redm[w][g * 4 + j] = mx[j];
    }
    __syncthreads();
#pragma unroll
    for (int j = 0; j < 4; ++j) {
        int row = g * 4 + j;
        mx[j] = fmaxf(fmaxf(redm[0][row], redm[1][row]), fmaxf(redm[2][row], redm[3][row]));
    }

    // Pass 2: recompute scores; e = exp(s-m) UNNORMALIZED -> P; accumulate sum
    float sum[4] = {0.f, 0.f, 0.f, 0.f};
#pragma unroll
    for (int kt = 0; kt < 16; ++kt) {
        int kcol = w * 256 + kt * 16;
        const __bf16* bp = ks + (size_t)(kcol + lr) * 64 + g * 8;
        f32x4 acc = {};
        acc = MFMA(a0, ld8(bp), acc);
        acc = MFMA(a1, ld8(bp + 32), acc);
        int col = kcol + lr;
#pragma unroll
        for (int j = 0; j < 4; ++j) {
            int row = g * 4 + j;
            bool mk = (mbits >> (kt * 4 + j)) & 1ull;
            float m = (mx[j] == -INFINITY) ? 0.f : mx[j];
            float e = mk ? 0.f : __expf(acc[j] * 0.03125f - m);
            sum[j] += e;
            P[row][col] = (__bf16)e;
        }
    }
#pragma unroll
    for (int j = 0; j < 4; ++j) {
#pragma unroll
        for (int o = 8; o >= 1; o >>= 1) sum[j] += __shfl_xor(sum[j], o);
    }
    if (lr == 0) {
#pragma unroll
        for (int j = 0; j < 4; ++j) reds[w][g * 4 + j] = sum[j];
    }
    __syncthreads();

    // Phase 3: coalesced attns write, scaling by inv[row] on the fly
    float* abase = attnF + (size_t)hb * 1048576 + (size_t)q0 * 1024;
#pragma unroll
    for (int i = 0; i < 8; ++i) {
        int idx = i * 256 + tid;
        int row = idx >> 7;
        int c8  = (idx & 127) * 8;
        float tot  = reds[0][row] + reds[1][row] + reds[2][row] + reds[3][row];
        float mrow = fmaxf(fmaxf(redm[0][row], redm[1][row]),
                           fmaxf(redm[2][row], redm[3][row]));
        float inv = (mrow == -INFINITY) ? 0.f : 1.0f / tot;
        bf16x8 pv = *reinterpret_cast<const bf16x8*>(&P[row][c8]);
        float4 f0 = {(float)pv[0] * inv, (float)pv[1] * inv,
                     (float)pv[2] * inv, (float)pv[3] * inv};
        float4 f1 = {(float)pv[4] * inv, (float)pv[5] * inv,
                     (float)pv[6] * inv, (float)pv[7] * inv};
        float* dst = abase + (size_t)row * 1024 + c8;
        *reinterpret_cast<float4*>(dst)     = f0;
        *reinterpret_cast<float4*>(dst + 4) = f1;
    }

    // Phase 4: PV on unnormalized P; scale epilogue by inv[row]
    const __bf16* vb = vsb + rel * stride;
    f32x4 acc2 = {};
    for (int kb = 0; kb < 32; ++kb) {
        bf16x8 pa  = *reinterpret_cast<const bf16x8*>(&P[lr][kb * 32 + g * 8]);
        bf16x8 vb8 = ld8(vb + (size_t)(w * 16 + lr) * 1024 + kb * 32 + g * 8);
        acc2 = MFMA(pa, vb8, acc2);
    }
    int h = hb >> 3;
#pragma unroll
    for (int j = 0; j < 4; ++j) {
        int row = g * 4 + j;
        float tot  = reds[0][row] + reds[1][row] + reds[2][row] + reds[3][row];
        float mrow = fmaxf(fmaxf(redm[0][row], redm[1][row]),
                           fmaxf(redm[2][row], redm[3][row]));
        float inv = (mrow == -INFINITY) ? 0.f : 1.0f / tot;
        int srow = q0 + row;
        int vv = w * 16 + lr;
        x[(size_t)b * 1048576 + (size_t)srow * 1024 + h * 64 + vv] = (__bf16)(acc2[j] * inv);
    }
}

// copy q_s/k_s/v_sT tail slices (hb 116..127) into reloc buffer
__global__ void reloc_kernel(const __bf16* qs, const __bf16* ks, const __bf16* vs,
                             __bf16* rel) {
    int i = blockIdx.x * 256 + threadIdx.x;  // uint4 units: 12*3*8192 = 294912
    if (i >= 294912) return;
    int hbi = i / 24576;
    int r   = i % 24576;
    int t   = r / 8192, j = r % 8192;
    const __bf16* src = ((t == 0) ? qs : (t == 1) ? ks : vs) + (size_t)(116 + hbi) * 65536;
    __bf16* dst = rel + (size_t)hbi * 196608 + t * 65536;
    reinterpret_cast<uint4*>(dst)[j] = reinterpret_cast<const uint4*>(src)[j];
}

// out fp32 = LN(x @ proj_w.T + pb + q)*lg + lb.  Rows [row0, row0 + 16*gridDim.x).
__global__ void outproj_ln_kernel(const __bf16* __restrict__ x, const float* __restrict__ pw,
                                  const __bf16* __restrict__ pwb, int use_pwb,
                                  const float* __restrict__ pb, const float* __restrict__ q,
                                  const float* __restrict__ lg, const float* __restrict__ lb,
                                  float* __restrict__ out, int row0) {
    __shared__ float smem[16][1024];
    int tid = threadIdx.x;
    int l = tid & 63, w = tid >> 6;
    int lr = l & 15, g = l >> 4;
    int r0 = row0 + blockIdx.x * 16;

    f32x4 acc[16] = {};
    for (int kb = 0; kb < 32; ++kb) {
        bf16x8 a = ld8(x + (size_t)(r0 + lr) * 1024 + kb * 32 + g * 8);
#pragma unroll
        for (int nt = 0; nt < 16; ++nt) {
            int n = w * 256 + nt * 16 + lr;
            size_t off = (size_t)n * 1024 + kb * 32 + g * 8;
            bf16x8 b = use_pwb ? ld8(pwb + off) : ld8f(pw + off);
            acc[nt] = MFMA(a, b, acc[nt]);
        }
    }
#pragma unroll
    for (int nt = 0; nt < 16; ++nt) {
#pragma unroll
        for (int j = 0; j < 4; ++j) {
            int row = g * 4 + j;
            int col = w * 256 + nt * 16 + lr;
            float v = acc[nt][j] + pb[col] + q[(size_t)(r0 + row) * 1024 + col];
            smem[row][col] = v;
        }
    }
    __syncthreads();

    int row = tid >> 4, j16 = tid & 15;
    float s1 = 0.f, s2 = 0.f;
    for (int k = j16; k < 1024; k += 16) {
        float v = smem[row][k];
        s1 += v;
        s2 += v * v;
    }
#pragma unroll
    for (int m = 8; m >= 1; m >>= 1) {
        s1 += __shfl_xor(s1, m);
        s2 += __shfl_xor(s2, m);
    }
    float mu  = s1 * (1.0f / 1024.0f);
    float var = fmaxf(s2 * (1.0f / 1024.0f) - mu * mu, 0.f);
    float rs  = rsqrtf(var + 1e-5f);
    for (int k = j16; k < 1024; k += 16) {
        float v = (smem[row][k] - mu) * rs * lg[k] + lb[k];
        out[(size_t)(r0 + row) * 1024 + k] = v;
    }
}

extern "C" void kernel_launch(void* const* d_in, const int* in_sizes, int n_in,
                              void* d_out, int out_size, void* d_ws, size_t ws_size,
                              hipStream_t stream) {
    const float* Q  = (const float*)d_in[0];
    const float* K  = (const float*)d_in[1];
    const float* V  = (const float*)d_in[2];
    const void*  M  = d_in[3];
    const float* WQ = (const float*)d_in[4];
    const float* WK = (const float*)d_in[5];
    const float* WV = (const float*)d_in[6];
    const float* PW = (const float*)d_in[7];
    const float* PB = (const float*)d_in[8];
    const float* LG = (const float*)d_in[9];
    const float* LB = (const float*)d_in[10];

    float* outF  = (float*)d_out;           // 8,388,608 fp32
    float* attnF = outF + 8388608;          // 134,217,728 fp32 = 128 chunks of 1,048,576

    if (ws_size >= (size_t)73400320) {
        // ---------- Path A: intermediates in d_ws ----------
        char* ws = (char*)d_ws;
        __bf16* wqT  = (__bf16*)ws;                        // 2 MB
        __bf16* wkT  = (__bf16*)(ws + 2097152);            // 2 MB
        __bf16* wvT  = (__bf16*)(ws + 4194304);            // 2 MB
        __bf16* q_s  = (__bf16*)(ws + 6291456);            // 16 MB [hb][s][kk]
        __bf16* k_s  = (__bf16*)(ws + 23068672);           // 16 MB
        __bf16* v_sT = (__bf16*)(ws + 39845888);           // 16 MB [hb][vv][s]
        __bf16* x    = (__bf16*)(ws + 56623104);           // 16 MB [b][s][h*64+vv]
        bool has_pwb = (ws_size >= (size_t)75497472);      // +2 MB tail
        __bf16* pwb  = (__bf16*)(ws + 73400320);

        transpose_w_kernel<<<768, 256, 0, stream>>>(WQ, WK, WV, wqT, wkT, wvT);
        if (has_pwb) convert_pw_kernel<<<1024, 256, 0, stream>>>(PW, pwb);
        proj_kernel<<<dim3(256, 8), 256, 0, stream>>>(Q, wqT, q_s, 0);
        proj_kernel<<<dim3(256, 8), 256, 0, stream>>>(K, wkT, k_s, 0);
        proj_kernel<<<dim3(256, 8), 256, 0, stream>>>(V, wvT, v_sT, 1);
        fused_attn_kernel<<<8192, 256, 0, stream>>>(q_s, k_s, v_sT, (size_t)65536, 0,
                                                    M, attnF, x);
        outproj_ln_kernel<<<512, 256, 0, stream>>>(x, PW, pwb, has_pwb ? 1 : 0,
                                                   PB, Q, LG, LB, outF, 0);
    } else {
        // ---------- Path B: scratch carved from d_out ----------
        __bf16* wqT  = (__bf16*)attnF;                            // chunk 0
        __bf16* wkT  = (__bf16*)(attnF + 1048576);                // chunk 1
        __bf16* wvT  = (__bf16*)(attnF + 2097152);                // chunk 2
        __bf16* q_s  = (__bf16*)(attnF + (size_t)116 * 1048576);  // chunks 116-119
        __bf16* k_s  = q_s + 8388608;                             // chunks 120-123
        __bf16* v_sT = k_s + 8388608;                             // chunks 124-127
        __bf16* x    = (__bf16*)outF;                     // out bytes [0, 16.7M)
        __bf16* rel  = (__bf16*)(outF + 4194304);         // out bytes [16.7M, 21.3M)

        transpose_w_kernel<<<768, 256, 0, stream>>>(WQ, WK, WV, wqT, wkT, wvT);
        proj_kernel<<<dim3(256, 8), 256, 0, stream>>>(Q, wqT, q_s, 0);
        proj_kernel<<<dim3(256, 8), 256, 0, stream>>>(K, wkT, k_s, 0);
        proj_kernel<<<dim3(256, 8), 256, 0, stream>>>(V, wvT, v_sT, 1);
        // batch 1: hb in [0,116)
        fused_attn_kernel<<<64 * 116, 256, 0, stream>>>(q_s, k_s, v_sT, (size_t)65536, 0,
                                                        M, attnF, x);
        // relocate tail slices, then batch 2: hb in [116,128)
        reloc_kernel<<<1152, 256, 0, stream>>>(q_s, k_s, v_sT, rel);
        fused_attn_kernel<<<64 * 12, 256, 0, stream>>>(rel, rel + 65536, rel + 131072,
                                                       (size_t)196608, 116, M, attnF, x);
        // cascade-phased in-place outproj (J1 <= 2*J0 keeps reads ahead of writes)
        int J1 = 512;
        for (int J0 = 256;; J0 >>= 1) {
            outproj_ln_kernel<<<J1 - J0, 256, 0, stream>>>(x, PW, nullptr, 0,
                                                           PB, Q, LG, LB, outF, J0 * 16);
            J1 = J0;
            if (J0 == 0) break;
        }
    }
}

// Round 18
// 1212.215 us; speedup vs baseline: 1.3894x; 1.0592x over previous
//
#include <hip/hip_runtime.h>
#include <hip/hip_bf16.h>

// B=8, S=1024, D=1024, H=16, DK=DV=64. TEMPER=32.
// Contract (verified r15/r16): documented input order, fp32 floats, i32-or-byte mask at d3,
// d_out FLOAT32: out (8,1024,1024) then attns (128,1024,1024).
// r18: __launch_bounds__ to match LDS-bound occupancy -> full VGPR budget ->
// single-pass register-resident scores (no spill, no recompute). Padded P, XCD swizzle,
// unnormalized-P trick retained.

typedef __bf16 bf16x8 __attribute__((ext_vector_type(8)));
typedef __bf16 bf16x4 __attribute__((ext_vector_type(4)));
typedef float f32x4 __attribute__((ext_vector_type(4)));

#define MFMA(a, b, c) __builtin_amdgcn_mfma_f32_16x16x32_bf16(a, b, c, 0, 0, 0)

static __device__ __forceinline__ bf16x8 ld8(const __bf16* p) {
    return *reinterpret_cast<const bf16x8*>(p);
}
static __device__ __forceinline__ bf16x8 ld8f(const float* f) {
    float4 f0 = *reinterpret_cast<const float4*>(f);
    float4 f1 = *reinterpret_cast<const float4*>(f + 4);
    bf16x8 a;
    a[0] = (__bf16)f0.x; a[1] = (__bf16)f0.y; a[2] = (__bf16)f0.z; a[3] = (__bf16)f0.w;
    a[4] = (__bf16)f1.x; a[5] = (__bf16)f1.y; a[6] = (__bf16)f1.z; a[7] = (__bf16)f1.w;
    return a;
}

// tiled w transpose: [h][d][kk] fp32 -> [h][kk][d] bf16. grid 768 = 3 tensors*16h*16 dblocks.
__global__ void transpose_w_kernel(const float* wq, const float* wk, const float* wv,
                                   __bf16* wqT, __bf16* wkT, __bf16* wvT) {
    __shared__ __bf16 tile[64][65];
    int bid = blockIdx.x;
    int m  = bid >> 8;
    int h  = (bid >> 4) & 15;
    int db = bid & 15;
    const float* in = (m == 0) ? wq : (m == 1) ? wk : wv;
    __bf16*     out = (m == 0) ? wqT : (m == 1) ? wkT : wvT;
    int t = threadIdx.x;
#pragma unroll
    for (int i = 0; i < 16; ++i) {
        int idx = i * 256 + t;
        int dd = idx >> 6, kk = idx & 63;
        tile[kk][dd] = (__bf16)in[h * 65536 + (db * 64 + dd) * 64 + kk];
    }
    __syncthreads();
#pragma unroll
    for (int i = 0; i < 16; ++i) {
        int idx = i * 256 + t;
        int kk = idx >> 6, dd = idx & 63;
        out[h * 65536 + kk * 1024 + db * 64 + dd] = tile[kk][dd];
    }
}

// proj_w fp32 -> bf16 copy (1M elems, 4/thread, grid 1024)
__global__ void convert_pw_kernel(const float* pw, __bf16* pwb) {
    int i = blockIdx.x * 256 + threadIdx.x;
    float4 f = *reinterpret_cast<const float4*>(pw + (size_t)i * 4);
    bf16x4 o;
    o[0] = (__bf16)f.x; o[1] = (__bf16)f.y; o[2] = (__bf16)f.z; o[3] = (__bf16)f.w;
    *reinterpret_cast<bf16x4*>(pwb + (size_t)i * 4) = o;
}

// X fp32 (8192x1024) @ W (bf16 WT[n][k]) -> bf16. mode0: out[h][b][s][kk]; mode1: out[h][b][kk][s]
__global__ __launch_bounds__(256, 4)
void proj_kernel(const float* __restrict__ X, const __bf16* __restrict__ WT,
                 __bf16* __restrict__ out, int mode) {
    int tid = threadIdx.x;
    int l = tid & 63, w = tid >> 6;
    int lr = l & 15, g = l >> 4;
    int m0 = blockIdx.x * 32 + (w >> 1) * 16;
    int n0 = blockIdx.y * 128 + (w & 1) * 64;

    f32x4 acc[4] = {};
    const float* Arow = X + (size_t)(m0 + lr) * 1024 + g * 8;
    for (int kb = 0; kb < 32; ++kb) {
        bf16x8 a = ld8f(Arow + kb * 32);
#pragma unroll
        for (int nt = 0; nt < 4; ++nt) {
            bf16x8 b = ld8(WT + (size_t)(n0 + nt * 16 + lr) * 1024 + kb * 32 + g * 8);
            acc[nt] = MFMA(a, b, acc[nt]);
        }
    }
#pragma unroll
    for (int nt = 0; nt < 4; ++nt) {
#pragma unroll
        for (int j = 0; j < 4; ++j) {
            int r = m0 + g * 4 + j;
            int n = n0 + nt * 16 + lr;
            size_t o;
            if (mode == 0)
                o = (size_t)(n >> 6) * 524288 + (size_t)(r >> 10) * 65536 + (size_t)(r & 1023) * 64 + (n & 63);
            else
                o = (size_t)(n >> 6) * 524288 + (size_t)(r >> 10) * 65536 + (size_t)(n & 63) * 1024 + (r & 1023);
            out[o] = (__bf16)acc[nt][j];
        }
    }
}

// Fused scores+softmax+attns+PV, v3: single pass, register scores, launch_bounds(256,4).
// 1-D grid n = 64*nhb (n % 8 == 0), XCD-swizzled.
__global__ __launch_bounds__(256, 4)
void fused_attn_kernel(const __bf16* __restrict__ qsb, const __bf16* __restrict__ ksb,
                       const __bf16* __restrict__ vsb, size_t stride, int hb0,
                       const void* __restrict__ mask,
                       float* __restrict__ attnF, __bf16* __restrict__ x) {
    __shared__ __bf16 P[16][1040];           // pad -> row stride 8 banks (mod 32)
    __shared__ float redm[4][16], reds[4][16];

    int nb = gridDim.x;
    int sb = (blockIdx.x & 7) * (nb >> 3) + (blockIdx.x >> 3);  // XCD swizzle (nb%8==0)
    int rel = sb >> 6;
    int q0  = (sb & 63) * 16;
    int hb  = hb0 + rel;
    int tid = threadIdx.x;
    int l = tid & 63, w = tid >> 6;
    int lr = l & 15, g = l >> 4;

    unsigned mw = ((const unsigned*)mask)[l];
    int bytemask = __any(mw > 1u) ? 1 : 0;

    const __bf16* qb = qsb + rel * stride + (size_t)q0 * 64;
    const __bf16* ks = ksb + rel * stride;
    bf16x8 a0 = ld8(qb + lr * 64 + g * 8);
    bf16x8 a1 = ld8(qb + lr * 64 + 32 + g * 8);

    int b = hb & 7;
    const unsigned char* m8  = (const unsigned char*)mask;
    const int*           m32 = (const int*)mask;
    size_t mbase = ((size_t)b * 1024 + q0) * 1024;

    // Pass 1 (only): QK^T -> registers, masked + scaled; row max
    float s[16][4];
    float mx[4] = {-INFINITY, -INFINITY, -INFINITY, -INFINITY};
#pragma unroll
    for (int kt = 0; kt < 16; ++kt) {
        int kcol = w * 256 + kt * 16;
        const __bf16* bp = ks + (size_t)(kcol + lr) * 64 + g * 8;
        f32x4 acc = {};
        acc = MFMA(a0, ld8(bp), acc);
        acc = MFMA(a1, ld8(bp + 32), acc);
        int col = kcol + lr;
#pragma unroll
        for (int j = 0; j < 4; ++j) {
            size_t mi = mbase + (size_t)(g * 4 + j) * 1024 + col;
            bool mk = bytemask ? (m8[mi] != 0) : (m32[mi] != 0);
            float v = mk ? -INFINITY : acc[j] * 0.03125f;  // /TEMPER
            s[kt][j] = v;
            mx[j] = fmaxf(mx[j], v);
        }
    }
#pragma unroll
    for (int j = 0; j < 4; ++j) {
#pragma unroll
        for (int o = 8; o >= 1; o >>= 1) mx[j] = fmaxf(mx[j], __shfl_xor(mx[j], o));
    }
    if (lr == 0) {
#pragma unroll
        for (int j = 0; j < 4; ++j) redm[w][g * 4 + j] = mx[j];
    }
    __syncthreads();
#pragma unroll
    for (int j = 0; j < 4; ++j) {
        int row = g * 4 + j;
        mx[j] = fmaxf(fmaxf(redm[0][row], redm[1][row]), fmaxf(redm[2][row], redm[3][row]));
    }

    // exp (unnormalized) -> P; accumulate sum
    float sum[4] = {0.f, 0.f, 0.f, 0.f};
#pragma unroll
    for (int j = 0; j < 4; ++j) {
        int row = g * 4 + j;
        float m = (mx[j] == -INFINITY) ? 0.f : mx[j];
#pragma unroll
        for (int kt = 0; kt < 16; ++kt) {
            float v = s[kt][j];
            float e = (v == -INFINITY) ? 0.f : __expf(v - m);
            sum[j] += e;
            P[row][w * 256 + kt * 16 + lr] = (__bf16)e;
        }
    }
#pragma unroll
    for (int j = 0; j < 4; ++j) {
#pragma unroll
        for (int o = 8; o >= 1; o >>= 1) sum[j] += __shfl_xor(sum[j], o);
    }
    if (lr == 0) {
#pragma unroll
        for (int j = 0; j < 4; ++j) reds[w][g * 4 + j] = sum[j];
    }
    __syncthreads();

    // Phase 3: coalesced attns write, scaled by inv[row]
    float* abase = attnF + (size_t)hb * 1048576 + (size_t)q0 * 1024;
#pragma unroll
    for (int i = 0; i < 8; ++i) {
        int idx = i * 256 + tid;
        int row = idx >> 7;
        int c8  = (idx & 127) * 8;
        float tot  = reds[0][row] + reds[1][row] + reds[2][row] + reds[3][row];
        float mrow = fmaxf(fmaxf(redm[0][row], redm[1][row]),
                           fmaxf(redm[2][row], redm[3][row]));
        float inv = (mrow == -INFINITY) ? 0.f : 1.0f / tot;
        bf16x8 pv = *reinterpret_cast<const bf16x8*>(&P[row][c8]);
        float4 f0 = {(float)pv[0] * inv, (float)pv[1] * inv,
                     (float)pv[2] * inv, (float)pv[3] * inv};
        float4 f1 = {(float)pv[4] * inv, (float)pv[5] * inv,
                     (float)pv[6] * inv, (float)pv[7] * inv};
        float* dst = abase + (size_t)row * 1024 + c8;
        *reinterpret_cast<float4*>(dst)     = f0;
        *reinterpret_cast<float4*>(dst + 4) = f1;
    }

    // Phase 4: PV on unnormalized P; scale epilogue by inv[row]
    const __bf16* vb = vsb + rel * stride;
    f32x4 acc2 = {};
    for (int kb = 0; kb < 32; ++kb) {
        bf16x8 pa  = *reinterpret_cast<const bf16x8*>(&P[lr][kb * 32 + g * 8]);
        bf16x8 vb8 = ld8(vb + (size_t)(w * 16 + lr) * 1024 + kb * 32 + g * 8);
        acc2 = MFMA(pa, vb8, acc2);
    }
    int h = hb >> 3;
#pragma unroll
    for (int j = 0; j < 4; ++j) {
        int row = g * 4 + j;
        float tot  = reds[0][row] + reds[1][row] + reds[2][row] + reds[3][row];
        float mrow = fmaxf(fmaxf(redm[0][row], redm[1][row]),
                           fmaxf(redm[2][row], redm[3][row]));
        float inv = (mrow == -INFINITY) ? 0.f : 1.0f / tot;
        int srow = q0 + row;
        int vv = w * 16 + lr;
        x[(size_t)b * 1048576 + (size_t)srow * 1024 + h * 64 + vv] = (__bf16)(acc2[j] * inv);
    }
}

// copy q_s/k_s/v_sT tail slices (hb 116..127) into reloc buffer
__global__ void reloc_kernel(const __bf16* qs, const __bf16* ks, const __bf16* vs,
                             __bf16* rel) {
    int i = blockIdx.x * 256 + threadIdx.x;  // uint4 units: 12*3*8192 = 294912
    if (i >= 294912) return;
    int hbi = i / 24576;
    int r   = i % 24576;
    int t   = r / 8192, j = r % 8192;
    const __bf16* src = ((t == 0) ? qs : (t == 1) ? ks : vs) + (size_t)(116 + hbi) * 65536;
    __bf16* dst = rel + (size_t)hbi * 196608 + t * 65536;
    reinterpret_cast<uint4*>(dst)[j] = reinterpret_cast<const uint4*>(src)[j];
}

// out fp32 = LN(x @ proj_w.T + pb + q)*lg + lb.  Rows [row0, row0 + 16*gridDim.x).
__global__ __launch_bounds__(256, 2)
void outproj_ln_kernel(const __bf16* __restrict__ x, const float* __restrict__ pw,
                       const __bf16* __restrict__ pwb, int use_pwb,
                       const float* __restrict__ pb, const float* __restrict__ q,
                       const float* __restrict__ lg, const float* __restrict__ lb,
                       float* __restrict__ out, int row0) {
    __shared__ float smem[16][1024];
    int tid = threadIdx.x;
    int l = tid & 63, w = tid >> 6;
    int lr = l & 15, g = l >> 4;
    int r0 = row0 + blockIdx.x * 16;

    f32x4 acc[16] = {};
    for (int kb = 0; kb < 32; ++kb) {
        bf16x8 a = ld8(x + (size_t)(r0 + lr) * 1024 + kb * 32 + g * 8);
#pragma unroll
        for (int nt = 0; nt < 16; ++nt) {
            int n = w * 256 + nt * 16 + lr;
            size_t off = (size_t)n * 1024 + kb * 32 + g * 8;
            bf16x8 b = use_pwb ? ld8(pwb + off) : ld8f(pw + off);
            acc[nt] = MFMA(a, b, acc[nt]);
        }
    }
#pragma unroll
    for (int nt = 0; nt < 16; ++nt) {
#pragma unroll
        for (int j = 0; j < 4; ++j) {
            int row = g * 4 + j;
            int col = w * 256 + nt * 16 + lr;
            float v = acc[nt][j] + pb[col] + q[(size_t)(r0 + row) * 1024 + col];
            smem[row][col] = v;
        }
    }
    __syncthreads();

    int row = tid >> 4, j16 = tid & 15;
    float s1 = 0.f, s2 = 0.f;
    for (int k = j16; k < 1024; k += 16) {
        float v = smem[row][k];
        s1 += v;
        s2 += v * v;
    }
#pragma unroll
    for (int m = 8; m >= 1; m >>= 1) {
        s1 += __shfl_xor(s1, m);
        s2 += __shfl_xor(s2, m);
    }
    float mu  = s1 * (1.0f / 1024.0f);
    float var = fmaxf(s2 * (1.0f / 1024.0f) - mu * mu, 0.f);
    float rs  = rsqrtf(var + 1e-5f);
    for (int k = j16; k < 1024; k += 16) {
        float v = (smem[row][k] - mu) * rs * lg[k] + lb[k];
        out[(size_t)(r0 + row) * 1024 + k] = v;
    }
}

extern "C" void kernel_launch(void* const* d_in, const int* in_sizes, int n_in,
                              void* d_out, int out_size, void* d_ws, size_t ws_size,
                              hipStream_t stream) {
    const float* Q  = (const float*)d_in[0];
    const float* K  = (const float*)d_in[1];
    const float* V  = (const float*)d_in[2];
    const void*  M  = d_in[3];
    const float* WQ = (const float*)d_in[4];
    const float* WK = (const float*)d_in[5];
    const float* WV = (const float*)d_in[6];
    const float* PW = (const float*)d_in[7];
    const float* PB = (const float*)d_in[8];
    const float* LG = (const float*)d_in[9];
    const float* LB = (const float*)d_in[10];

    float* outF  = (float*)d_out;           // 8,388,608 fp32
    float* attnF = outF + 8388608;          // 134,217,728 fp32 = 128 chunks of 1,048,576

    if (ws_size >= (size_t)73400320) {
        // ---------- Path A: intermediates in d_ws ----------
        char* ws = (char*)d_ws;
        __bf16* wqT  = (__bf16*)ws;                        // 2 MB
        __bf16* wkT  = (__bf16*)(ws + 2097152);            // 2 MB
        __bf16* wvT  = (__bf16*)(ws + 4194304);            // 2 MB
        __bf16* q_s  = (__bf16*)(ws + 6291456);            // 16 MB [hb][s][kk]
        __bf16* k_s  = (__bf16*)(ws + 23068672);           // 16 MB
        __bf16* v_sT = (__bf16*)(ws + 39845888);           // 16 MB [hb][vv][s]
        __bf16* x    = (__bf16*)(ws + 56623104);           // 16 MB [b][s][h*64+vv]
        bool has_pwb = (ws_size >= (size_t)75497472);      // +2 MB tail
        __bf16* pwb  = (__bf16*)(ws + 73400320);

        transpose_w_kernel<<<768, 256, 0, stream>>>(WQ, WK, WV, wqT, wkT, wvT);
        if (has_pwb) convert_pw_kernel<<<1024, 256, 0, stream>>>(PW, pwb);
        proj_kernel<<<dim3(256, 8), 256, 0, stream>>>(Q, wqT, q_s, 0);
        proj_kernel<<<dim3(256, 8), 256, 0, stream>>>(K, wkT, k_s, 0);
        proj_kernel<<<dim3(256, 8), 256, 0, stream>>>(V, wvT, v_sT, 1);
        fused_attn_kernel<<<8192, 256, 0, stream>>>(q_s, k_s, v_sT, (size_t)65536, 0,
                                                    M, attnF, x);
        outproj_ln_kernel<<<512, 256, 0, stream>>>(x, PW, pwb, has_pwb ? 1 : 0,
                                                   PB, Q, LG, LB, outF, 0);
    } else {
        // ---------- Path B: scratch carved from d_out ----------
        __bf16* wqT  = (__bf16*)attnF;                            // chunk 0
        __bf16* wkT  = (__bf16*)(attnF + 1048576);                // chunk 1
        __bf16* wvT  = (__bf16*)(attnF + 2097152);                // chunk 2
        __bf16* q_s  = (__bf16*)(attnF + (size_t)116 * 1048576);  // chunks 116-119
        __bf16* k_s  = q_s + 8388608;                             // chunks 120-123
        __bf16* v_sT = k_s + 8388608;                             // chunks 124-127
        __bf16* x    = (__bf16*)outF;                     // out bytes [0, 16.7M)
        __bf16* rel  = (__bf16*)(outF + 4194304);         // out bytes [16.7M, 21.3M)

        transpose_w_kernel<<<768, 256, 0, stream>>>(WQ, WK, WV, wqT, wkT, wvT);
        proj_kernel<<<dim3(256, 8), 256, 0, stream>>>(Q, wqT, q_s, 0);
        proj_kernel<<<dim3(256, 8), 256, 0, stream>>>(K, wkT, k_s, 0);
        proj_kernel<<<dim3(256, 8), 256, 0, stream>>>(V, wvT, v_sT, 1);
        // batch 1: hb in [0,116)
        fused_attn_kernel<<<64 * 116, 256, 0, stream>>>(q_s, k_s, v_sT, (size_t)65536, 0,
                                                        M, attnF, x);
        // relocate tail slices, then batch 2: hb in [116,128)
        reloc_kernel<<<1152, 256, 0, stream>>>(q_s, k_s, v_sT, rel);
        fused_attn_kernel<<<64 * 12, 256, 0, stream>>>(rel, rel + 65536, rel + 131072,
                                                       (size_t)196608, 116, M, attnF, x);
        // cascade-phased in-place outproj (J1 <= 2*J0 keeps reads ahead of writes)
        int J1 = 512;
        for (int J0 = 256;; J0 >>= 1) {
            outproj_ln_kernel<<<J1 - J0, 256, 0, stream>>>(x, PW, nullptr, 0,
                                                           PB, Q, LG, LB, outF, J0 * 16);
            J1 = J0;
            if (J0 == 0) break;
        }
    }
}

// Round 19
// 1058.447 us; speedup vs baseline: 1.5912x; 1.1453x over previous
//
#include <hip/hip_runtime.h>
#include <hip/hip_bf16.h>

// B=8, S=1024, D=1024, H=16, DK=DV=64. TEMPER=32.
// Contract (verified r15+): documented input order, fp32 floats, i32-or-byte mask at d3,
// d_out FLOAT32: out (8,1024,1024) then attns (128,1024,1024).
// r19: bit-packed mask (1 MB, L2-resident) staged to LDS -> removes 64 scattered
// global mask loads per thread from the fused kernel's critical path.
// mbits live in the out region bytes [22MB,23MB) -- free scratch in both paths.

typedef __bf16 bf16x8 __attribute__((ext_vector_type(8)));
typedef __bf16 bf16x4 __attribute__((ext_vector_type(4)));
typedef float f32x4 __attribute__((ext_vector_type(4)));

#define MFMA(a, b, c) __builtin_amdgcn_mfma_f32_16x16x32_bf16(a, b, c, 0, 0, 0)

static __device__ __forceinline__ bf16x8 ld8(const __bf16* p) {
    return *reinterpret_cast<const bf16x8*>(p);
}
static __device__ __forceinline__ bf16x8 ld8f(const float* f) {
    float4 f0 = *reinterpret_cast<const float4*>(f);
    float4 f1 = *reinterpret_cast<const float4*>(f + 4);
    bf16x8 a;
    a[0] = (__bf16)f0.x; a[1] = (__bf16)f0.y; a[2] = (__bf16)f0.z; a[3] = (__bf16)f0.w;
    a[4] = (__bf16)f1.x; a[5] = (__bf16)f1.y; a[6] = (__bf16)f1.z; a[7] = (__bf16)f1.w;
    return a;
}

// pack mask (int32 or bytes, autodetected) -> 1 bit/elem. 262144 u32 words, grid 1024.
__global__ void pack_mask_kernel(const void* mask, unsigned* mbits) {
    int l = threadIdx.x & 63;
    unsigned w0 = ((const unsigned*)mask)[l];
    int bytemask = __any(w0 > 1u) ? 1 : 0;
    int i = blockIdx.x * 256 + threadIdx.x;
    unsigned out = 0;
    if (bytemask) {
        const unsigned char* m8 = (const unsigned char*)mask + (size_t)i * 32;
#pragma unroll
        for (int bt = 0; bt < 32; ++bt)
            if (m8[bt]) out |= (1u << bt);
    } else {
        const int* m32 = (const int*)mask + (size_t)i * 32;
#pragma unroll
        for (int bt = 0; bt < 32; ++bt)
            if (m32[bt]) out |= (1u << bt);
    }
    mbits[i] = out;
}

// tiled w transpose: [h][d][kk] fp32 -> [h][kk][d] bf16. grid 768.
__global__ void transpose_w_kernel(const float* wq, const float* wk, const float* wv,
                                   __bf16* wqT, __bf16* wkT, __bf16* wvT) {
    __shared__ __bf16 tile[64][65];
    int bid = blockIdx.x;
    int m  = bid >> 8;
    int h  = (bid >> 4) & 15;
    int db = bid & 15;
    const float* in = (m == 0) ? wq : (m == 1) ? wk : wv;
    __bf16*     out = (m == 0) ? wqT : (m == 1) ? wkT : wvT;
    int t = threadIdx.x;
#pragma unroll
    for (int i = 0; i < 16; ++i) {
        int idx = i * 256 + t;
        int dd = idx >> 6, kk = idx & 63;
        tile[kk][dd] = (__bf16)in[h * 65536 + (db * 64 + dd) * 64 + kk];
    }
    __syncthreads();
#pragma unroll
    for (int i = 0; i < 16; ++i) {
        int idx = i * 256 + t;
        int kk = idx >> 6, dd = idx & 63;
        out[h * 65536 + kk * 1024 + db * 64 + dd] = tile[kk][dd];
    }
}

// proj_w fp32 -> bf16 copy (1M elems, grid 1024)
__global__ void convert_pw_kernel(const float* pw, __bf16* pwb) {
    int i = blockIdx.x * 256 + threadIdx.x;
    float4 f = *reinterpret_cast<const float4*>(pw + (size_t)i * 4);
    bf16x4 o;
    o[0] = (__bf16)f.x; o[1] = (__bf16)f.y; o[2] = (__bf16)f.z; o[3] = (__bf16)f.w;
    *reinterpret_cast<bf16x4*>(pwb + (size_t)i * 4) = o;
}

// X fp32 (8192x1024) @ W (bf16 WT[n][k]) -> bf16. mode0: out[h][b][s][kk]; mode1: out[h][b][kk][s]
__global__ __launch_bounds__(256, 4)
void proj_kernel(const float* __restrict__ X, const __bf16* __restrict__ WT,
                 __bf16* __restrict__ out, int mode) {
    int tid = threadIdx.x;
    int l = tid & 63, w = tid >> 6;
    int lr = l & 15, g = l >> 4;
    int m0 = blockIdx.x * 32 + (w >> 1) * 16;
    int n0 = blockIdx.y * 128 + (w & 1) * 64;

    f32x4 acc[4] = {};
    const float* Arow = X + (size_t)(m0 + lr) * 1024 + g * 8;
    for (int kb = 0; kb < 32; ++kb) {
        bf16x8 a = ld8f(Arow + kb * 32);
#pragma unroll
        for (int nt = 0; nt < 4; ++nt) {
            bf16x8 b = ld8(WT + (size_t)(n0 + nt * 16 + lr) * 1024 + kb * 32 + g * 8);
            acc[nt] = MFMA(a, b, acc[nt]);
        }
    }
#pragma unroll
    for (int nt = 0; nt < 4; ++nt) {
#pragma unroll
        for (int j = 0; j < 4; ++j) {
            int r = m0 + g * 4 + j;
            int n = n0 + nt * 16 + lr;
            size_t o;
            if (mode == 0)
                o = (size_t)(n >> 6) * 524288 + (size_t)(r >> 10) * 65536 + (size_t)(r & 1023) * 64 + (n & 63);
            else
                o = (size_t)(n >> 6) * 524288 + (size_t)(r >> 10) * 65536 + (size_t)(n & 63) * 1024 + (r & 1023);
            out[o] = (__bf16)acc[nt][j];
        }
    }
}

// Fused scores+softmax+attns+PV. 1-D grid n = 64*nhb (n % 8 == 0), XCD-swizzled.
// Mask from bit-packed mbits, staged via LDS (broadcast reads).
__global__ __launch_bounds__(256, 4)
void fused_attn_kernel(const __bf16* __restrict__ qsb, const __bf16* __restrict__ ksb,
                       const __bf16* __restrict__ vsb, size_t stride, int hb0,
                       const unsigned* __restrict__ mbits,
                       float* __restrict__ attnF, __bf16* __restrict__ x) {
    __shared__ __bf16 P[16][1040];           // pad -> conflict-free PV reads
    __shared__ float redm[4][16], reds[4][16];
    __shared__ unsigned mb[16][32];          // 2 KB mask bits for this q-tile

    int nb = gridDim.x;
    int sb = (blockIdx.x & 7) * (nb >> 3) + (blockIdx.x >> 3);  // XCD swizzle
    int rel = sb >> 6;
    int q0  = (sb & 63) * 16;
    int hb  = hb0 + rel;
    int tid = threadIdx.x;
    int l = tid & 63, w = tid >> 6;
    int lr = l & 15, g = l >> 4;
    int b = hb & 7;

    // stage mask bits: 512 coalesced u32
#pragma unroll
    for (int i = 0; i < 2; ++i) {
        int idx = i * 256 + tid;
        mb[idx >> 5][idx & 31] = mbits[((size_t)b * 1024 + q0 + (idx >> 5)) * 32 + (idx & 31)];
    }

    const __bf16* qb = qsb + rel * stride + (size_t)q0 * 64;
    const __bf16* ks = ksb + rel * stride;
    bf16x8 a0 = ld8(qb + lr * 64 + g * 8);
    bf16x8 a1 = ld8(qb + lr * 64 + 32 + g * 8);
    __syncthreads();

    // QK^T -> registers (AGPR-parked), masked + scaled; row max
    float s[16][4];
    float mx[4] = {-INFINITY, -INFINITY, -INFINITY, -INFINITY};
#pragma unroll
    for (int kt = 0; kt < 16; ++kt) {
        int kcol = w * 256 + kt * 16;
        const __bf16* bp = ks + (size_t)(kcol + lr) * 64 + g * 8;
        f32x4 acc = {};
        acc = MFMA(a0, ld8(bp), acc);
        acc = MFMA(a1, ld8(bp + 32), acc);
#pragma unroll
        for (int j = 0; j < 4; ++j) {
            unsigned wbits = mb[g * 4 + j][w * 8 + (kt >> 1)];
            bool mk = (wbits >> ((kt & 1) * 16 + lr)) & 1u;
            float v = mk ? -INFINITY : acc[j] * 0.03125f;  // /TEMPER
            s[kt][j] = v;
            mx[j] = fmaxf(mx[j], v);
        }
    }
#pragma unroll
    for (int j = 0; j < 4; ++j) {
#pragma unroll
        for (int o = 8; o >= 1; o >>= 1) mx[j] = fmaxf(mx[j], __shfl_xor(mx[j], o));
    }
    if (lr == 0) {
#pragma unroll
        for (int j = 0; j < 4; ++j) redm[w][g * 4 + j] = mx[j];
    }
    __syncthreads();
#pragma unroll
    for (int j = 0; j < 4; ++j) {
        int row = g * 4 + j;
        mx[j] = fmaxf(fmaxf(redm[0][row], redm[1][row]), fmaxf(redm[2][row], redm[3][row]));
    }

    // exp (unnormalized) -> P; accumulate sum
    float sum[4] = {0.f, 0.f, 0.f, 0.f};
#pragma unroll
    for (int j = 0; j < 4; ++j) {
        int row = g * 4 + j;
        float m = (mx[j] == -INFINITY) ? 0.f : mx[j];
#pragma unroll
        for (int kt = 0; kt < 16; ++kt) {
            float v = s[kt][j];
            float e = (v == -INFINITY) ? 0.f : __expf(v - m);
            sum[j] += e;
            P[row][w * 256 + kt * 16 + lr] = (__bf16)e;
        }
    }
#pragma unroll
    for (int j = 0; j < 4; ++j) {
#pragma unroll
        for (int o = 8; o >= 1; o >>= 1) sum[j] += __shfl_xor(sum[j], o);
    }
    if (lr == 0) {
#pragma unroll
        for (int j = 0; j < 4; ++j) reds[w][g * 4 + j] = sum[j];
    }
    __syncthreads();

    // coalesced attns write, scaled by inv[row]
    float* abase = attnF + (size_t)hb * 1048576 + (size_t)q0 * 1024;
#pragma unroll
    for (int i = 0; i < 8; ++i) {
        int idx = i * 256 + tid;
        int row = idx >> 7;
        int c8  = (idx & 127) * 8;
        float tot  = reds[0][row] + reds[1][row] + reds[2][row] + reds[3][row];
        float mrow = fmaxf(fmaxf(redm[0][row], redm[1][row]),
                           fmaxf(redm[2][row], redm[3][row]));
        float inv = (mrow == -INFINITY) ? 0.f : 1.0f / tot;
        bf16x8 pv = *reinterpret_cast<const bf16x8*>(&P[row][c8]);
        float4 f0 = {(float)pv[0] * inv, (float)pv[1] * inv,
                     (float)pv[2] * inv, (float)pv[3] * inv};
        float4 f1 = {(float)pv[4] * inv, (float)pv[5] * inv,
                     (float)pv[6] * inv, (float)pv[7] * inv};
        float* dst = abase + (size_t)row * 1024 + c8;
        *reinterpret_cast<float4*>(dst)     = f0;
        *reinterpret_cast<float4*>(dst + 4) = f1;
    }

    // PV on unnormalized P; scale epilogue by inv[row]
    const __bf16* vb = vsb + rel * stride;
    f32x4 acc2 = {};
    for (int kb = 0; kb < 32; ++kb) {
        bf16x8 pa  = *reinterpret_cast<const bf16x8*>(&P[lr][kb * 32 + g * 8]);
        bf16x8 vb8 = ld8(vb + (size_t)(w * 16 + lr) * 1024 + kb * 32 + g * 8);
        acc2 = MFMA(pa, vb8, acc2);
    }
    int h = hb >> 3;
#pragma unroll
    for (int j = 0; j < 4; ++j) {
        int row = g * 4 + j;
        float tot  = reds[0][row] + reds[1][row] + reds[2][row] + reds[3][row];
        float mrow = fmaxf(fmaxf(redm[0][row], redm[1][row]),
                           fmaxf(redm[2][row], redm[3][row]));
        float inv = (mrow == -INFINITY) ? 0.f : 1.0f / tot;
        int srow = q0 + row;
        int vv = w * 16 + lr;
        x[(size_t)b * 1048576 + (size_t)srow * 1024 + h * 64 + vv] = (__bf16)(acc2[j] * inv);
    }
}

// copy q_s/k_s/v_sT tail slices (hb 116..127) into reloc buffer
__global__ void reloc_kernel(const __bf16* qs, const __bf16* ks, const __bf16* vs,
                             __bf16* rel) {
    int i = blockIdx.x * 256 + threadIdx.x;  // uint4 units: 12*3*8192 = 294912
    if (i >= 294912) return;
    int hbi = i / 24576;
    int r   = i % 24576;
    int t   = r / 8192, j = r % 8192;
    const __bf16* src = ((t == 0) ? qs : (t == 1) ? ks : vs) + (size_t)(116 + hbi) * 65536;
    __bf16* dst = rel + (size_t)hbi * 196608 + t * 65536;
    reinterpret_cast<uint4*>(dst)[j] = reinterpret_cast<const uint4*>(src)[j];
}

// out fp32 = LN(x @ proj_w.T + pb + q)*lg + lb.  Rows [row0, row0 + 16*gridDim.x).
__global__ __launch_bounds__(256, 2)
void outproj_ln_kernel(const __bf16* __restrict__ x, const float* __restrict__ pw,
                       const __bf16* __restrict__ pwb, int use_pwb,
                       const float* __restrict__ pb, const float* __restrict__ q,
                       const float* __restrict__ lg, const float* __restrict__ lb,
                       float* __restrict__ out, int row0) {
    __shared__ float smem[16][1024];
    int tid = threadIdx.x;
    int l = tid & 63, w = tid >> 6;
    int lr = l & 15, g = l >> 4;
    int r0 = row0 + blockIdx.x * 16;

    f32x4 acc[16] = {};
    for (int kb = 0; kb < 32; ++kb) {
        bf16x8 a = ld8(x + (size_t)(r0 + lr) * 1024 + kb * 32 + g * 8);
#pragma unroll
        for (int nt = 0; nt < 16; ++nt) {
            int n = w * 256 + nt * 16 + lr;
            size_t off = (size_t)n * 1024 + kb * 32 + g * 8;
            bf16x8 b = use_pwb ? ld8(pwb + off) : ld8f(pw + off);
            acc[nt] = MFMA(a, b, acc[nt]);
        }
    }
#pragma unroll
    for (int nt = 0; nt < 16; ++nt) {
#pragma unroll
        for (int j = 0; j < 4; ++j) {
            int row = g * 4 + j;
            int col = w * 256 + nt * 16 + lr;
            float v = acc[nt][j] + pb[col] + q[(size_t)(r0 + row) * 1024 + col];
            smem[row][col] = v;
        }
    }
    __syncthreads();

    int row = tid >> 4, j16 = tid & 15;
    float s1 = 0.f, s2 = 0.f;
    for (int k = j16; k < 1024; k += 16) {
        float v = smem[row][k];
        s1 += v;
        s2 += v * v;
    }
#pragma unroll
    for (int m = 8; m >= 1; m >>= 1) {
        s1 += __shfl_xor(s1, m);
        s2 += __shfl_xor(s2, m);
    }
    float mu  = s1 * (1.0f / 1024.0f);
    float var = fmaxf(s2 * (1.0f / 1024.0f) - mu * mu, 0.f);
    float rs  = rsqrtf(var + 1e-5f);
    for (int k = j16; k < 1024; k += 16) {
        float v = (smem[row][k] - mu) * rs * lg[k] + lb[k];
        out[(size_t)(r0 + row) * 1024 + k] = v;
    }
}

extern "C" void kernel_launch(void* const* d_in, const int* in_sizes, int n_in,
                              void* d_out, int out_size, void* d_ws, size_t ws_size,
                              hipStream_t stream) {
    const float* Q  = (const float*)d_in[0];
    const float* K  = (const float*)d_in[1];
    const float* V  = (const float*)d_in[2];
    const void*  M  = d_in[3];
    const float* WQ = (const float*)d_in[4];
    const float* WK = (const float*)d_in[5];
    const float* WV = (const float*)d_in[6];
    const float* PW = (const float*)d_in[7];
    const float* PB = (const float*)d_in[8];
    const float* LG = (const float*)d_in[9];
    const float* LB = (const float*)d_in[10];

    float* outF  = (float*)d_out;           // 8,388,608 fp32
    float* attnF = outF + 8388608;          // 134,217,728 fp32

    // mask bits live in the out region, bytes [22MB, 23MB): free in both paths,
    // consumed by fused before outproj overwrites that row range.
    unsigned* mbits = (unsigned*)(outF + 5505024);

    pack_mask_kernel<<<1024, 256, 0, stream>>>(M, mbits);

    if (ws_size >= (size_t)73400320) {
        // ---------- Path A: intermediates in d_ws ----------
        char* ws = (char*)d_ws;
        __bf16* wqT  = (__bf16*)ws;                        // 2 MB
        __bf16* wkT  = (__bf16*)(ws + 2097152);            // 2 MB
        __bf16* wvT  = (__bf16*)(ws + 4194304);            // 2 MB
        __bf16* q_s  = (__bf16*)(ws + 6291456);            // 16 MB [hb][s][kk]
        __bf16* k_s  = (__bf16*)(ws + 23068672);           // 16 MB
        __bf16* v_sT = (__bf16*)(ws + 39845888);           // 16 MB [hb][vv][s]
        __bf16* x    = (__bf16*)(ws + 56623104);           // 16 MB [b][s][h*64+vv]
        bool has_pwb = (ws_size >= (size_t)75497472);      // +2 MB tail
        __bf16* pwb  = (__bf16*)(ws + 73400320);

        transpose_w_kernel<<<768, 256, 0, stream>>>(WQ, WK, WV, wqT, wkT, wvT);
        if (has_pwb) convert_pw_kernel<<<1024, 256, 0, stream>>>(PW, pwb);
        proj_kernel<<<dim3(256, 8), 256, 0, stream>>>(Q, wqT, q_s, 0);
        proj_kernel<<<dim3(256, 8), 256, 0, stream>>>(K, wkT, k_s, 0);
        proj_kernel<<<dim3(256, 8), 256, 0, stream>>>(V, wvT, v_sT, 1);
        fused_attn_kernel<<<8192, 256, 0, stream>>>(q_s, k_s, v_sT, (size_t)65536, 0,
                                                    mbits, attnF, x);
        outproj_ln_kernel<<<512, 256, 0, stream>>>(x, PW, pwb, has_pwb ? 1 : 0,
                                                   PB, Q, LG, LB, outF, 0);
    } else {
        // ---------- Path B: scratch carved from d_out ----------
        __bf16* wqT  = (__bf16*)attnF;                            // chunk 0
        __bf16* wkT  = (__bf16*)(attnF + 1048576);                // chunk 1
        __bf16* wvT  = (__bf16*)(attnF + 2097152);                // chunk 2
        __bf16* q_s  = (__bf16*)(attnF + (size_t)116 * 1048576);  // chunks 116-119
        __bf16* k_s  = q_s + 8388608;                             // chunks 120-123
        __bf16* v_sT = k_s + 8388608;                             // chunks 124-127
        __bf16* x    = (__bf16*)outF;                     // out bytes [0, 16.7M)
        __bf16* rel  = (__bf16*)(outF + 4194304);         // out bytes [16.7M, 21.5M)

        transpose_w_kernel<<<768, 256, 0, stream>>>(WQ, WK, WV, wqT, wkT, wvT);
        proj_kernel<<<dim3(256, 8), 256, 0, stream>>>(Q, wqT, q_s, 0);
        proj_kernel<<<dim3(256, 8), 256, 0, stream>>>(K, wkT, k_s, 0);
        proj_kernel<<<dim3(256, 8), 256, 0, stream>>>(V, wvT, v_sT, 1);
        // batch 1: hb in [0,116)
        fused_attn_kernel<<<64 * 116, 256, 0, stream>>>(q_s, k_s, v_sT, (size_t)65536, 0,
                                                        mbits, attnF, x);
        // relocate tail slices, then batch 2: hb in [116,128)
        reloc_kernel<<<1152, 256, 0, stream>>>(q_s, k_s, v_sT, rel);
        fused_attn_kernel<<<64 * 12, 256, 0, stream>>>(rel, rel + 65536, rel + 131072,
                                                       (size_t)196608, 116, mbits, attnF, x);
        // cascade-phased in-place outproj (J1 <= 2*J0 keeps reads ahead of writes)
        int J1 = 512;
        for (int J0 = 256;; J0 >>= 1) {
            outproj_ln_kernel<<<J1 - J0, 256, 0, stream>>>(x, PW, nullptr, 0,
                                                           PB, Q, LG, LB, outF, J0 * 16);
            J1 = J0;
            if (J0 == 0) break;
        }
    }
}

// Round 21
// 685.700 us; speedup vs baseline: 2.4562x; 1.5436x over previous
//
#include <hip/hip_runtime.h>
#include <hip/hip_bf16.h>

// B=8, S=1024, D=1024, H=16, DK=DV=64. TEMPER=32.
// Contract (verified r15+): documented input order, fp32 floats, i32-or-byte mask at d3,
// d_out FLOAT32: out (8,1024,1024) then attns (128,1024,1024).
// r21: fix r20's B-staging width bug (Bs half-written -> NaN). gemm_proj now stages
// the full 128x32 B tile (two uint4 per thread), matching the A path.

typedef __bf16 bf16x8 __attribute__((ext_vector_type(8)));
typedef __bf16 bf16x4 __attribute__((ext_vector_type(4)));
typedef float f32x4 __attribute__((ext_vector_type(4)));

#define MFMA(a, b, c) __builtin_amdgcn_mfma_f32_16x16x32_bf16(a, b, c, 0, 0, 0)

static __device__ __forceinline__ bf16x8 ld8(const __bf16* p) {
    return *reinterpret_cast<const bf16x8*>(p);
}
static __device__ __forceinline__ bf16x8 ld8f(const float* f) {
    float4 f0 = *reinterpret_cast<const float4*>(f);
    float4 f1 = *reinterpret_cast<const float4*>(f + 4);
    bf16x8 a;
    a[0] = (__bf16)f0.x; a[1] = (__bf16)f0.y; a[2] = (__bf16)f0.z; a[3] = (__bf16)f0.w;
    a[4] = (__bf16)f1.x; a[5] = (__bf16)f1.y; a[6] = (__bf16)f1.z; a[7] = (__bf16)f1.w;
    return a;
}
static __device__ __forceinline__ bf16x8 cvt8(float4 x, float4 y) {
    bf16x8 r;
    r[0] = (__bf16)x.x; r[1] = (__bf16)x.y; r[2] = (__bf16)x.z; r[3] = (__bf16)x.w;
    r[4] = (__bf16)y.x; r[5] = (__bf16)y.y; r[6] = (__bf16)y.z; r[7] = (__bf16)y.w;
    return r;
}

// pack mask (int32 or bytes, autodetected) -> 1 bit/elem. 262144 u32 words, grid 1024.
__global__ void pack_mask_kernel(const void* mask, unsigned* mbits) {
    int l = threadIdx.x & 63;
    unsigned w0 = ((const unsigned*)mask)[l];
    int bytemask = __any(w0 > 1u) ? 1 : 0;
    int i = blockIdx.x * 256 + threadIdx.x;
    unsigned out = 0;
    if (bytemask) {
        const unsigned char* m8 = (const unsigned char*)mask + (size_t)i * 32;
#pragma unroll
        for (int bt = 0; bt < 32; ++bt)
            if (m8[bt]) out |= (1u << bt);
    } else {
        const int* m32 = (const int*)mask + (size_t)i * 32;
#pragma unroll
        for (int bt = 0; bt < 32; ++bt)
            if (m32[bt]) out |= (1u << bt);
    }
    mbits[i] = out;
}

// tiled w transpose: [h][d][kk] fp32 -> [h][kk][d] bf16. grid 768.
__global__ void transpose_w_kernel(const float* wq, const float* wk, const float* wv,
                                   __bf16* wqT, __bf16* wkT, __bf16* wvT) {
    __shared__ __bf16 tile[64][65];
    int bid = blockIdx.x;
    int m  = bid >> 8;
    int h  = (bid >> 4) & 15;
    int db = bid & 15;
    const float* in = (m == 0) ? wq : (m == 1) ? wk : wv;
    __bf16*     out = (m == 0) ? wqT : (m == 1) ? wkT : wvT;
    int t = threadIdx.x;
#pragma unroll
    for (int i = 0; i < 16; ++i) {
        int idx = i * 256 + t;
        int dd = idx >> 6, kk = idx & 63;
        tile[kk][dd] = (__bf16)in[h * 65536 + (db * 64 + dd) * 64 + kk];
    }
    __syncthreads();
#pragma unroll
    for (int i = 0; i < 16; ++i) {
        int idx = i * 256 + t;
        int kk = idx >> 6, dd = idx & 63;
        out[h * 65536 + kk * 1024 + db * 64 + dd] = tile[kk][dd];
    }
}

// proj_w fp32 -> bf16 copy (1M elems, grid 1024)
__global__ void convert_pw_kernel(const float* pw, __bf16* pwb) {
    int i = blockIdx.x * 256 + threadIdx.x;
    float4 f = *reinterpret_cast<const float4*>(pw + (size_t)i * 4);
    bf16x4 o;
    o[0] = (__bf16)f.x; o[1] = (__bf16)f.y; o[2] = (__bf16)f.z; o[3] = (__bf16)f.w;
    *reinterpret_cast<bf16x4*>(pwb + (size_t)i * 4) = o;
}

// 128x128-tile GEMM: X fp32 (8192x1024) @ WT bf16 [n][k] -> bf16 out.
// mode0: out[h][b][s][kk]; mode1: out[h][b][kk][s]. grid 512 (64 m-tiles x 8 n-tiles).
__global__ __launch_bounds__(256, 4)
void gemm_proj_kernel(const float* __restrict__ X, const __bf16* __restrict__ WT,
                      __bf16* __restrict__ out, int mode) {
    __shared__ __bf16 As[128][32];
    __shared__ __bf16 Bs[128][32];
    int nb = gridDim.x;
    int sb = (blockIdx.x & 7) * (nb >> 3) + (blockIdx.x >> 3);  // XCD swizzle
    int m0 = (sb >> 3) * 128;
    int n0 = (sb & 7) * 128;
    int tid = threadIdx.x;
    int l = tid & 63, w = tid >> 6;
    int lr = l & 15, g = l >> 4;
    int wm = w >> 1, wn = w & 1;

    int srow = tid >> 1, shalf = tid & 1;    // staging: row 0..127, 16-elem half
    const float*  Ag = X  + (size_t)(m0 + srow) * 1024 + shalf * 16;
    const __bf16* Bg = WT + (size_t)(n0 + srow) * 1024 + shalf * 16;

    f32x4 acc[4][4] = {};
    float4 a0 = *(const float4*)(Ag);
    float4 a1 = *(const float4*)(Ag + 4);
    float4 a2 = *(const float4*)(Ag + 8);
    float4 a3 = *(const float4*)(Ag + 12);
    uint4  bv0 = *(const uint4*)(Bg);
    uint4  bv1 = *(const uint4*)(Bg + 8);

    for (int kt = 0; kt < 32; ++kt) {
        *(bf16x8*)(&As[srow][shalf * 16])     = cvt8(a0, a1);
        *(bf16x8*)(&As[srow][shalf * 16 + 8]) = cvt8(a2, a3);
        *(uint4*)(&Bs[srow][shalf * 16])      = bv0;
        *(uint4*)(&Bs[srow][shalf * 16 + 8])  = bv1;
        __syncthreads();
        if (kt < 31) {                        // issue next-tile loads early (fly under MFMA)
            const float* An = Ag + (kt + 1) * 32;
            a0 = *(const float4*)(An);
            a1 = *(const float4*)(An + 4);
            a2 = *(const float4*)(An + 8);
            a3 = *(const float4*)(An + 12);
            bv0 = *(const uint4*)(Bg + (kt + 1) * 32);
            bv1 = *(const uint4*)(Bg + (kt + 1) * 32 + 8);
        }
        bf16x8 af[4], bfr[4];
#pragma unroll
        for (int mi = 0; mi < 4; ++mi)
            af[mi] = *(const bf16x8*)(&As[wm * 64 + mi * 16 + lr][g * 8]);
#pragma unroll
        for (int ni = 0; ni < 4; ++ni)
            bfr[ni] = *(const bf16x8*)(&Bs[wn * 64 + ni * 16 + lr][g * 8]);
#pragma unroll
        for (int mi = 0; mi < 4; ++mi)
#pragma unroll
            for (int ni = 0; ni < 4; ++ni)
                acc[mi][ni] = MFMA(af[mi], bfr[ni], acc[mi][ni]);
        __syncthreads();
    }

#pragma unroll
    for (int mi = 0; mi < 4; ++mi)
#pragma unroll
        for (int ni = 0; ni < 4; ++ni)
#pragma unroll
            for (int j = 0; j < 4; ++j) {
                int r = m0 + wm * 64 + mi * 16 + g * 4 + j;
                int n = n0 + wn * 64 + ni * 16 + lr;
                size_t o;
                if (mode == 0)
                    o = (size_t)(n >> 6) * 524288 + (size_t)(r >> 10) * 65536 +
                        (size_t)(r & 1023) * 64 + (n & 63);
                else
                    o = (size_t)(n >> 6) * 524288 + (size_t)(r >> 10) * 65536 +
                        (size_t)(n & 63) * 1024 + (r & 1023);
                out[o] = (__bf16)acc[mi][ni][j];
            }
}

// Fused scores+softmax+attns+PV. 1-D grid n = 64*nhb (n % 8 == 0), XCD-swizzled.
__global__ __launch_bounds__(256, 4)
void fused_attn_kernel(const __bf16* __restrict__ qsb, const __bf16* __restrict__ ksb,
                       const __bf16* __restrict__ vsb, size_t stride, int hb0,
                       const unsigned* __restrict__ mbits,
                       float* __restrict__ attnF, __bf16* __restrict__ x) {
    __shared__ __bf16 P[16][1040];           // pad -> conflict-free PV reads
    __shared__ float redm[4][16], reds[4][16];
    __shared__ unsigned mb[16][32];          // 2 KB mask bits for this q-tile

    int nb = gridDim.x;
    int sb = (blockIdx.x & 7) * (nb >> 3) + (blockIdx.x >> 3);  // XCD swizzle
    int rel = sb >> 6;
    int q0  = (sb & 63) * 16;
    int hb  = hb0 + rel;
    int tid = threadIdx.x;
    int l = tid & 63, w = tid >> 6;
    int lr = l & 15, g = l >> 4;
    int b = hb & 7;

#pragma unroll
    for (int i = 0; i < 2; ++i) {
        int idx = i * 256 + tid;
        mb[idx >> 5][idx & 31] = mbits[((size_t)b * 1024 + q0 + (idx >> 5)) * 32 + (idx & 31)];
    }

    const __bf16* qb = qsb + rel * stride + (size_t)q0 * 64;
    const __bf16* ks = ksb + rel * stride;
    bf16x8 a0 = ld8(qb + lr * 64 + g * 8);
    bf16x8 a1 = ld8(qb + lr * 64 + 32 + g * 8);
    __syncthreads();

    float s[16][4];
    float mx[4] = {-INFINITY, -INFINITY, -INFINITY, -INFINITY};
#pragma unroll
    for (int kt = 0; kt < 16; ++kt) {
        int kcol = w * 256 + kt * 16;
        const __bf16* bp = ks + (size_t)(kcol + lr) * 64 + g * 8;
        f32x4 acc = {};
        acc = MFMA(a0, ld8(bp), acc);
        acc = MFMA(a1, ld8(bp + 32), acc);
#pragma unroll
        for (int j = 0; j < 4; ++j) {
            unsigned wbits = mb[g * 4 + j][w * 8 + (kt >> 1)];
            bool mk = (wbits >> ((kt & 1) * 16 + lr)) & 1u;
            float v = mk ? -INFINITY : acc[j] * 0.03125f;  // /TEMPER
            s[kt][j] = v;
            mx[j] = fmaxf(mx[j], v);
        }
    }
#pragma unroll
    for (int j = 0; j < 4; ++j) {
#pragma unroll
        for (int o = 8; o >= 1; o >>= 1) mx[j] = fmaxf(mx[j], __shfl_xor(mx[j], o));
    }
    if (lr == 0) {
#pragma unroll
        for (int j = 0; j < 4; ++j) redm[w][g * 4 + j] = mx[j];
    }
    __syncthreads();
#pragma unroll
    for (int j = 0; j < 4; ++j) {
        int row = g * 4 + j;
        mx[j] = fmaxf(fmaxf(redm[0][row], redm[1][row]), fmaxf(redm[2][row], redm[3][row]));
    }

    float sum[4] = {0.f, 0.f, 0.f, 0.f};
#pragma unroll
    for (int j = 0; j < 4; ++j) {
        int row = g * 4 + j;
        float m = (mx[j] == -INFINITY) ? 0.f : mx[j];
#pragma unroll
        for (int kt = 0; kt < 16; ++kt) {
            float v = s[kt][j];
            float e = (v == -INFINITY) ? 0.f : __expf(v - m);
            sum[j] += e;
            P[row][w * 256 + kt * 16 + lr] = (__bf16)e;
        }
    }
#pragma unroll
    for (int j = 0; j < 4; ++j) {
#pragma unroll
        for (int o = 8; o >= 1; o >>= 1) sum[j] += __shfl_xor(sum[j], o);
    }
    if (lr == 0) {
#pragma unroll
        for (int j = 0; j < 4; ++j) reds[w][g * 4 + j] = sum[j];
    }
    __syncthreads();

    float* abase = attnF + (size_t)hb * 1048576 + (size_t)q0 * 1024;
#pragma unroll
    for (int i = 0; i < 8; ++i) {
        int idx = i * 256 + tid;
        int row = idx >> 7;
        int c8  = (idx & 127) * 8;
        float tot  = reds[0][row] + reds[1][row] + reds[2][row] + reds[3][row];
        float mrow = fmaxf(fmaxf(redm[0][row], redm[1][row]),
                           fmaxf(redm[2][row], redm[3][row]));
        float inv = (mrow == -INFINITY) ? 0.f : 1.0f / tot;
        bf16x8 pv = *reinterpret_cast<const bf16x8*>(&P[row][c8]);
        float4 f0 = {(float)pv[0] * inv, (float)pv[1] * inv,
                     (float)pv[2] * inv, (float)pv[3] * inv};
        float4 f1 = {(float)pv[4] * inv, (float)pv[5] * inv,
                     (float)pv[6] * inv, (float)pv[7] * inv};
        float* dst = abase + (size_t)row * 1024 + c8;
        *reinterpret_cast<float4*>(dst)     = f0;
        *reinterpret_cast<float4*>(dst + 4) = f1;
    }

    const __bf16* vb = vsb + rel * stride;
    f32x4 acc2 = {};
    for (int kb = 0; kb < 32; ++kb) {
        bf16x8 pa  = *reinterpret_cast<const bf16x8*>(&P[lr][kb * 32 + g * 8]);
        bf16x8 vb8 = ld8(vb + (size_t)(w * 16 + lr) * 1024 + kb * 32 + g * 8);
        acc2 = MFMA(pa, vb8, acc2);
    }
    int h = hb >> 3;
#pragma unroll
    for (int j = 0; j < 4; ++j) {
        int row = g * 4 + j;
        float tot  = reds[0][row] + reds[1][row] + reds[2][row] + reds[3][row];
        float mrow = fmaxf(fmaxf(redm[0][row], redm[1][row]),
                           fmaxf(redm[2][row], redm[3][row]));
        float inv = (mrow == -INFINITY) ? 0.f : 1.0f / tot;
        int srow = q0 + row;
        int vv = w * 16 + lr;
        x[(size_t)b * 1048576 + (size_t)srow * 1024 + h * 64 + vv] = (__bf16)(acc2[j] * inv);
    }
}

// copy q_s/k_s/v_sT tail slices (hb 116..127) into reloc buffer
__global__ void reloc_kernel(const __bf16* qs, const __bf16* ks, const __bf16* vs,
                             __bf16* rel) {
    int i = blockIdx.x * 256 + threadIdx.x;  // uint4 units: 12*3*8192 = 294912
    if (i >= 294912) return;
    int hbi = i / 24576;
    int r   = i % 24576;
    int t   = r / 8192, j = r % 8192;
    const __bf16* src = ((t == 0) ? qs : (t == 1) ? ks : vs) + (size_t)(116 + hbi) * 65536;
    __bf16* dst = rel + (size_t)hbi * 196608 + t * 65536;
    reinterpret_cast<uint4*>(dst)[j] = reinterpret_cast<const uint4*>(src)[j];
}

// out fp32 = LN(x @ proj_w.T + pb + q)*lg + lb.  Rows [row0, row0 + 16*gridDim.x).
__global__ __launch_bounds__(256, 2)
void outproj_ln_kernel(const __bf16* __restrict__ x, const float* __restrict__ pw,
                       const __bf16* __restrict__ pwb, int use_pwb,
                       const float* __restrict__ pb, const float* __restrict__ q,
                       const float* __restrict__ lg, const float* __restrict__ lb,
                       float* __restrict__ out, int row0) {
    __shared__ float smem[16][1024];
    int tid = threadIdx.x;
    int l = tid & 63, w = tid >> 6;
    int lr = l & 15, g = l >> 4;
    int r0 = row0 + blockIdx.x * 16;

    f32x4 acc[16] = {};
    for (int kb = 0; kb < 32; ++kb) {
        bf16x8 a = ld8(x + (size_t)(r0 + lr) * 1024 + kb * 32 + g * 8);
#pragma unroll
        for (int nt = 0; nt < 16; ++nt) {
            int n = w * 256 + nt * 16 + lr;
            size_t off = (size_t)n * 1024 + kb * 32 + g * 8;
            bf16x8 b = use_pwb ? ld8(pwb + off) : ld8f(pw + off);
            acc[nt] = MFMA(a, b, acc[nt]);
        }
    }
#pragma unroll
    for (int nt = 0; nt < 16; ++nt) {
#pragma unroll
        for (int j = 0; j < 4; ++j) {
            int row = g * 4 + j;
            int col = w * 256 + nt * 16 + lr;
            float v = acc[nt][j] + pb[col] + q[(size_t)(r0 + row) * 1024 + col];
            smem[row][col] = v;
        }
    }
    __syncthreads();

    int row = tid >> 4, j16 = tid & 15;
    float s1 = 0.f, s2 = 0.f;
    for (int k = j16; k < 1024; k += 16) {
        float v = smem[row][k];
        s1 += v;
        s2 += v * v;
    }
#pragma unroll
    for (int m = 8; m >= 1; m >>= 1) {
        s1 += __shfl_xor(s1, m);
        s2 += __shfl_xor(s2, m);
    }
    float mu  = s1 * (1.0f / 1024.0f);
    float var = fmaxf(s2 * (1.0f / 1024.0f) - mu * mu, 0.f);
    float rs  = rsqrtf(var + 1e-5f);
    for (int k = j16; k < 1024; k += 16) {
        float v = (smem[row][k] - mu) * rs * lg[k] + lb[k];
        out[(size_t)(r0 + row) * 1024 + k] = v;
    }
}

extern "C" void kernel_launch(void* const* d_in, const int* in_sizes, int n_in,
                              void* d_out, int out_size, void* d_ws, size_t ws_size,
                              hipStream_t stream) {
    const float* Q  = (const float*)d_in[0];
    const float* K  = (const float*)d_in[1];
    const float* V  = (const float*)d_in[2];
    const void*  M  = d_in[3];
    const float* WQ = (const float*)d_in[4];
    const float* WK = (const float*)d_in[5];
    const float* WV = (const float*)d_in[6];
    const float* PW = (const float*)d_in[7];
    const float* PB = (const float*)d_in[8];
    const float* LG = (const float*)d_in[9];
    const float* LB = (const float*)d_in[10];

    float* outF  = (float*)d_out;           // 8,388,608 fp32
    float* attnF = outF + 8388608;          // 134,217,728 fp32

    unsigned* mbits = (unsigned*)(outF + 5505024);  // out bytes [22MB,23MB): free both paths

    pack_mask_kernel<<<1024, 256, 0, stream>>>(M, mbits);

    if (ws_size >= (size_t)73400320) {
        // ---------- Path A: intermediates in d_ws ----------
        char* ws = (char*)d_ws;
        __bf16* wqT  = (__bf16*)ws;                        // 2 MB
        __bf16* wkT  = (__bf16*)(ws + 2097152);            // 2 MB
        __bf16* wvT  = (__bf16*)(ws + 4194304);            // 2 MB
        __bf16* q_s  = (__bf16*)(ws + 6291456);            // 16 MB [hb][s][kk]
        __bf16* k_s  = (__bf16*)(ws + 23068672);           // 16 MB
        __bf16* v_sT = (__bf16*)(ws + 39845888);           // 16 MB [hb][vv][s]
        __bf16* x    = (__bf16*)(ws + 56623104);           // 16 MB [b][s][h*64+vv]
        bool has_pwb = (ws_size >= (size_t)75497472);      // +2 MB tail
        __bf16* pwb  = (__bf16*)(ws + 73400320);

        transpose_w_kernel<<<768, 256, 0, stream>>>(WQ, WK, WV, wqT, wkT, wvT);
        if (has_pwb) convert_pw_kernel<<<1024, 256, 0, stream>>>(PW, pwb);
        gemm_proj_kernel<<<512, 256, 0, stream>>>(Q, wqT, q_s, 0);
        gemm_proj_kernel<<<512, 256, 0, stream>>>(K, wkT, k_s, 0);
        gemm_proj_kernel<<<512, 256, 0, stream>>>(V, wvT, v_sT, 1);
        fused_attn_kernel<<<8192, 256, 0, stream>>>(q_s, k_s, v_sT, (size_t)65536, 0,
                                                    mbits, attnF, x);
        outproj_ln_kernel<<<512, 256, 0, stream>>>(x, PW, pwb, has_pwb ? 1 : 0,
                                                   PB, Q, LG, LB, outF, 0);
    } else {
        // ---------- Path B: scratch carved from d_out ----------
        __bf16* wqT  = (__bf16*)attnF;                            // chunk 0
        __bf16* wkT  = (__bf16*)(attnF + 1048576);                // chunk 1
        __bf16* wvT  = (__bf16*)(attnF + 2097152);                // chunk 2
        __bf16* q_s  = (__bf16*)(attnF + (size_t)116 * 1048576);  // chunks 116-119
        __bf16* k_s  = q_s + 8388608;                             // chunks 120-123
        __bf16* v_sT = k_s + 8388608;                             // chunks 124-127
        __bf16* x    = (__bf16*)outF;                     // out bytes [0, 16.7M)
        __bf16* rel  = (__bf16*)(outF + 4194304);         // out bytes [16.7M, 21.5M)

        transpose_w_kernel<<<768, 256, 0, stream>>>(WQ, WK, WV, wqT, wkT, wvT);
        gemm_proj_kernel<<<512, 256, 0, stream>>>(Q, wqT, q_s, 0);
        gemm_proj_kernel<<<512, 256, 0, stream>>>(K, wkT, k_s, 0);
        gemm_proj_kernel<<<512, 256, 0, stream>>>(V, wvT, v_sT, 1);
        // batch 1: hb in [0,116)
        fused_attn_kernel<<<64 * 116, 256, 0, stream>>>(q_s, k_s, v_sT, (size_t)65536, 0,
                                                        mbits, attnF, x);
        // relocate tail slices, then batch 2: hb in [116,128)
        reloc_kernel<<<1152, 256, 0, stream>>>(q_s, k_s, v_sT, rel);
        fused_attn_kernel<<<64 * 12, 256, 0, stream>>>(rel, rel + 65536, rel + 131072,
                                                       (size_t)196608, 116, mbits, attnF, x);
        // cascade-phased in-place outproj (J1 <= 2*J0 keeps reads ahead of writes)
        int J1 = 512;
        for (int J0 = 256;; J0 >>= 1) {
            outproj_ln_kernel<<<J1 - J0, 256, 0, stream>>>(x, PW, nullptr, 0,
                                                           PB, Q, LG, LB, outF, J0 * 16);
            J1 = J0;
            if (J0 == 0) break;
        }
    }
}

// Round 23
// 621.247 us; speedup vs baseline: 2.7110x; 1.1037x over previous
//
#include <hip/hip_runtime.h>
#include <hip/hip_bf16.h>

// B=8, S=1024, D=1024, H=16, DK=DV=64. TEMPER=32.
// Contract (verified r15+): documented input order, fp32 floats, i32-or-byte mask at d3,
// d_out FLOAT32: out (8,1024,1024) then attns (128,1024,1024).
// r23: fix r22 compile error (__builtin_nontemporal_store needs ext_vector_type, not
// HIP float4). Same plan: gemm_out + cascade LN + nontemporal attns stores.

typedef __bf16 bf16x8 __attribute__((ext_vector_type(8)));
typedef float f32x4 __attribute__((ext_vector_type(4)));

#define MFMA(a, b, c) __builtin_amdgcn_mfma_f32_16x16x32_bf16(a, b, c, 0, 0, 0)

static __device__ __forceinline__ bf16x8 ld8(const __bf16* p) {
    return *reinterpret_cast<const bf16x8*>(p);
}
static __device__ __forceinline__ bf16x8 cvt8(float4 x, float4 y) {
    bf16x8 r;
    r[0] = (__bf16)x.x; r[1] = (__bf16)x.y; r[2] = (__bf16)x.z; r[3] = (__bf16)x.w;
    r[4] = (__bf16)y.x; r[5] = (__bf16)y.y; r[6] = (__bf16)y.z; r[7] = (__bf16)y.w;
    return r;
}

// pack mask (int32 or bytes, autodetected) -> 1 bit/elem. 262144 u32 words, grid 1024.
__global__ void pack_mask_kernel(const void* mask, unsigned* mbits) {
    int l = threadIdx.x & 63;
    unsigned w0 = ((const unsigned*)mask)[l];
    int bytemask = __any(w0 > 1u) ? 1 : 0;
    int i = blockIdx.x * 256 + threadIdx.x;
    unsigned out = 0;
    if (bytemask) {
        const unsigned char* m8 = (const unsigned char*)mask + (size_t)i * 32;
#pragma unroll
        for (int bt = 0; bt < 32; ++bt)
            if (m8[bt]) out |= (1u << bt);
    } else {
        const int* m32 = (const int*)mask + (size_t)i * 32;
#pragma unroll
        for (int bt = 0; bt < 32; ++bt)
            if (m32[bt]) out |= (1u << bt);
    }
    mbits[i] = out;
}

// tiled w transpose: [h][d][kk] fp32 -> [h][kk][d] bf16. grid 768.
__global__ void transpose_w_kernel(const float* wq, const float* wk, const float* wv,
                                   __bf16* wqT, __bf16* wkT, __bf16* wvT) {
    __shared__ __bf16 tile[64][65];
    int bid = blockIdx.x;
    int m  = bid >> 8;
    int h  = (bid >> 4) & 15;
    int db = bid & 15;
    const float* in = (m == 0) ? wq : (m == 1) ? wk : wv;
    __bf16*     out = (m == 0) ? wqT : (m == 1) ? wkT : wvT;
    int t = threadIdx.x;
#pragma unroll
    for (int i = 0; i < 16; ++i) {
        int idx = i * 256 + t;
        int dd = idx >> 6, kk = idx & 63;
        tile[kk][dd] = (__bf16)in[h * 65536 + (db * 64 + dd) * 64 + kk];
    }
    __syncthreads();
#pragma unroll
    for (int i = 0; i < 16; ++i) {
        int idx = i * 256 + t;
        int kk = idx >> 6, dd = idx & 63;
        out[h * 65536 + kk * 1024 + db * 64 + dd] = tile[kk][dd];
    }
}

// 128x128-tile GEMM: X fp32 (8192x1024) @ WT bf16 [n][k] -> bf16 out.
// mode0: out[h][b][s][kk]; mode1: out[h][b][kk][s]. grid 512.
__global__ __launch_bounds__(256, 4)
void gemm_proj_kernel(const float* __restrict__ X, const __bf16* __restrict__ WT,
                      __bf16* __restrict__ out, int mode) {
    __shared__ __bf16 As[128][32];
    __shared__ __bf16 Bs[128][32];
    int nb = gridDim.x;
    int sb = (blockIdx.x & 7) * (nb >> 3) + (blockIdx.x >> 3);  // XCD swizzle
    int m0 = (sb >> 3) * 128;
    int n0 = (sb & 7) * 128;
    int tid = threadIdx.x;
    int l = tid & 63, w = tid >> 6;
    int lr = l & 15, g = l >> 4;
    int wm = w >> 1, wn = w & 1;

    int srow = tid >> 1, shalf = tid & 1;
    const float*  Ag = X  + (size_t)(m0 + srow) * 1024 + shalf * 16;
    const __bf16* Bg = WT + (size_t)(n0 + srow) * 1024 + shalf * 16;

    f32x4 acc[4][4] = {};
    float4 a0 = *(const float4*)(Ag);
    float4 a1 = *(const float4*)(Ag + 4);
    float4 a2 = *(const float4*)(Ag + 8);
    float4 a3 = *(const float4*)(Ag + 12);
    uint4  bv0 = *(const uint4*)(Bg);
    uint4  bv1 = *(const uint4*)(Bg + 8);

    for (int kt = 0; kt < 32; ++kt) {
        *(bf16x8*)(&As[srow][shalf * 16])     = cvt8(a0, a1);
        *(bf16x8*)(&As[srow][shalf * 16 + 8]) = cvt8(a2, a3);
        *(uint4*)(&Bs[srow][shalf * 16])      = bv0;
        *(uint4*)(&Bs[srow][shalf * 16 + 8])  = bv1;
        __syncthreads();
        if (kt < 31) {
            const float* An = Ag + (kt + 1) * 32;
            a0 = *(const float4*)(An);
            a1 = *(const float4*)(An + 4);
            a2 = *(const float4*)(An + 8);
            a3 = *(const float4*)(An + 12);
            bv0 = *(const uint4*)(Bg + (kt + 1) * 32);
            bv1 = *(const uint4*)(Bg + (kt + 1) * 32 + 8);
        }
        bf16x8 af[4], bfr[4];
#pragma unroll
        for (int mi = 0; mi < 4; ++mi)
            af[mi] = *(const bf16x8*)(&As[wm * 64 + mi * 16 + lr][g * 8]);
#pragma unroll
        for (int ni = 0; ni < 4; ++ni)
            bfr[ni] = *(const bf16x8*)(&Bs[wn * 64 + ni * 16 + lr][g * 8]);
#pragma unroll
        for (int mi = 0; mi < 4; ++mi)
#pragma unroll
            for (int ni = 0; ni < 4; ++ni)
                acc[mi][ni] = MFMA(af[mi], bfr[ni], acc[mi][ni]);
        __syncthreads();
    }

#pragma unroll
    for (int mi = 0; mi < 4; ++mi)
#pragma unroll
        for (int ni = 0; ni < 4; ++ni)
#pragma unroll
            for (int j = 0; j < 4; ++j) {
                int r = m0 + wm * 64 + mi * 16 + g * 4 + j;
                int n = n0 + wn * 64 + ni * 16 + lr;
                size_t o;
                if (mode == 0)
                    o = (size_t)(n >> 6) * 524288 + (size_t)(r >> 10) * 65536 +
                        (size_t)(r & 1023) * 64 + (n & 63);
                else
                    o = (size_t)(n >> 6) * 524288 + (size_t)(r >> 10) * 65536 +
                        (size_t)(n & 63) * 1024 + (r & 1023);
                out[o] = (__bf16)acc[mi][ni][j];
            }
}

// y = x(bf16 8192x1024) @ PW(fp32 [n][k])^T -> y bf16 row-major. grid 512.
__global__ __launch_bounds__(256, 4)
void gemm_out_kernel(const __bf16* __restrict__ X, const float* __restrict__ W,
                     __bf16* __restrict__ y) {
    __shared__ __bf16 As[128][32];
    __shared__ __bf16 Bs[128][32];
    int nb = gridDim.x;
    int sb = (blockIdx.x & 7) * (nb >> 3) + (blockIdx.x >> 3);  // XCD swizzle
    int m0 = (sb >> 3) * 128;
    int n0 = (sb & 7) * 128;
    int tid = threadIdx.x;
    int l = tid & 63, w = tid >> 6;
    int lr = l & 15, g = l >> 4;
    int wm = w >> 1, wn = w & 1;

    int srow = tid >> 1, shalf = tid & 1;
    const __bf16* Ag = X + (size_t)(m0 + srow) * 1024 + shalf * 16;
    const float*  Bg = W + (size_t)(n0 + srow) * 1024 + shalf * 16;

    f32x4 acc[4][4] = {};
    uint4  av0 = *(const uint4*)(Ag);
    uint4  av1 = *(const uint4*)(Ag + 8);
    float4 b0 = *(const float4*)(Bg);
    float4 b1 = *(const float4*)(Bg + 4);
    float4 b2 = *(const float4*)(Bg + 8);
    float4 b3 = *(const float4*)(Bg + 12);

    for (int kt = 0; kt < 32; ++kt) {
        *(uint4*)(&As[srow][shalf * 16])      = av0;
        *(uint4*)(&As[srow][shalf * 16 + 8])  = av1;
        *(bf16x8*)(&Bs[srow][shalf * 16])     = cvt8(b0, b1);
        *(bf16x8*)(&Bs[srow][shalf * 16 + 8]) = cvt8(b2, b3);
        __syncthreads();
        if (kt < 31) {
            av0 = *(const uint4*)(Ag + (kt + 1) * 32);
            av1 = *(const uint4*)(Ag + (kt + 1) * 32 + 8);
            const float* Bn = Bg + (kt + 1) * 32;
            b0 = *(const float4*)(Bn);
            b1 = *(const float4*)(Bn + 4);
            b2 = *(const float4*)(Bn + 8);
            b3 = *(const float4*)(Bn + 12);
        }
        bf16x8 af[4], bfr[4];
#pragma unroll
        for (int mi = 0; mi < 4; ++mi)
            af[mi] = *(const bf16x8*)(&As[wm * 64 + mi * 16 + lr][g * 8]);
#pragma unroll
        for (int ni = 0; ni < 4; ++ni)
            bfr[ni] = *(const bf16x8*)(&Bs[wn * 64 + ni * 16 + lr][g * 8]);
#pragma unroll
        for (int mi = 0; mi < 4; ++mi)
#pragma unroll
            for (int ni = 0; ni < 4; ++ni)
                acc[mi][ni] = MFMA(af[mi], bfr[ni], acc[mi][ni]);
        __syncthreads();
    }

#pragma unroll
    for (int mi = 0; mi < 4; ++mi)
#pragma unroll
        for (int ni = 0; ni < 4; ++ni)
#pragma unroll
            for (int j = 0; j < 4; ++j) {
                int r = m0 + wm * 64 + mi * 16 + g * 4 + j;
                int n = n0 + wn * 64 + ni * 16 + lr;
                y[(size_t)r * 1024 + n] = (__bf16)acc[mi][ni][j];
            }
}

// Fused scores+softmax+attns+PV. 1-D grid n = 64*nhb (n % 8 == 0), XCD-swizzled.
__global__ __launch_bounds__(256, 4)
void fused_attn_kernel(const __bf16* __restrict__ qsb, const __bf16* __restrict__ ksb,
                       const __bf16* __restrict__ vsb, size_t stride, int hb0,
                       const unsigned* __restrict__ mbits,
                       float* __restrict__ attnF, __bf16* __restrict__ x) {
    __shared__ __bf16 P[16][1040];           // pad -> conflict-free PV reads
    __shared__ float redm[4][16], reds[4][16];
    __shared__ unsigned mb[16][32];

    int nb = gridDim.x;
    int sb = (blockIdx.x & 7) * (nb >> 3) + (blockIdx.x >> 3);  // XCD swizzle
    int rel = sb >> 6;
    int q0  = (sb & 63) * 16;
    int hb  = hb0 + rel;
    int tid = threadIdx.x;
    int l = tid & 63, w = tid >> 6;
    int lr = l & 15, g = l >> 4;
    int b = hb & 7;

#pragma unroll
    for (int i = 0; i < 2; ++i) {
        int idx = i * 256 + tid;
        mb[idx >> 5][idx & 31] = mbits[((size_t)b * 1024 + q0 + (idx >> 5)) * 32 + (idx & 31)];
    }

    const __bf16* qb = qsb + rel * stride + (size_t)q0 * 64;
    const __bf16* ks = ksb + rel * stride;
    bf16x8 a0 = ld8(qb + lr * 64 + g * 8);
    bf16x8 a1 = ld8(qb + lr * 64 + 32 + g * 8);
    __syncthreads();

    float s[16][4];
    float mx[4] = {-INFINITY, -INFINITY, -INFINITY, -INFINITY};
#pragma unroll
    for (int kt = 0; kt < 16; ++kt) {
        int kcol = w * 256 + kt * 16;
        const __bf16* bp = ks + (size_t)(kcol + lr) * 64 + g * 8;
        f32x4 acc = {};
        acc = MFMA(a0, ld8(bp), acc);
        acc = MFMA(a1, ld8(bp + 32), acc);
#pragma unroll
        for (int j = 0; j < 4; ++j) {
            unsigned wbits = mb[g * 4 + j][w * 8 + (kt >> 1)];
            bool mk = (wbits >> ((kt & 1) * 16 + lr)) & 1u;
            float v = mk ? -INFINITY : acc[j] * 0.03125f;  // /TEMPER
            s[kt][j] = v;
            mx[j] = fmaxf(mx[j], v);
        }
    }
#pragma unroll
    for (int j = 0; j < 4; ++j) {
#pragma unroll
        for (int o = 8; o >= 1; o >>= 1) mx[j] = fmaxf(mx[j], __shfl_xor(mx[j], o));
    }
    if (lr == 0) {
#pragma unroll
        for (int j = 0; j < 4; ++j) redm[w][g * 4 + j] = mx[j];
    }
    __syncthreads();
#pragma unroll
    for (int j = 0; j < 4; ++j) {
        int row = g * 4 + j;
        mx[j] = fmaxf(fmaxf(redm[0][row], redm[1][row]), fmaxf(redm[2][row], redm[3][row]));
    }

    float sum[4] = {0.f, 0.f, 0.f, 0.f};
#pragma unroll
    for (int j = 0; j < 4; ++j) {
        int row = g * 4 + j;
        float m = (mx[j] == -INFINITY) ? 0.f : mx[j];
#pragma unroll
        for (int kt = 0; kt < 16; ++kt) {
            float v = s[kt][j];
            float e = (v == -INFINITY) ? 0.f : __expf(v - m);
            sum[j] += e;
            P[row][w * 256 + kt * 16 + lr] = (__bf16)e;
        }
    }
#pragma unroll
    for (int j = 0; j < 4; ++j) {
#pragma unroll
        for (int o = 8; o >= 1; o >>= 1) sum[j] += __shfl_xor(sum[j], o);
    }
    if (lr == 0) {
#pragma unroll
        for (int j = 0; j < 4; ++j) reds[w][g * 4 + j] = sum[j];
    }
    __syncthreads();

    // coalesced nontemporal attns write (attns never re-read)
    float* abase = attnF + (size_t)hb * 1048576 + (size_t)q0 * 1024;
#pragma unroll
    for (int i = 0; i < 8; ++i) {
        int idx = i * 256 + tid;
        int row = idx >> 7;
        int c8  = (idx & 127) * 8;
        float tot  = reds[0][row] + reds[1][row] + reds[2][row] + reds[3][row];
        float mrow = fmaxf(fmaxf(redm[0][row], redm[1][row]),
                           fmaxf(redm[2][row], redm[3][row]));
        float inv = (mrow == -INFINITY) ? 0.f : 1.0f / tot;
        bf16x8 pv = *reinterpret_cast<const bf16x8*>(&P[row][c8]);
        f32x4 f0 = {(float)pv[0] * inv, (float)pv[1] * inv,
                    (float)pv[2] * inv, (float)pv[3] * inv};
        f32x4 f1 = {(float)pv[4] * inv, (float)pv[5] * inv,
                    (float)pv[6] * inv, (float)pv[7] * inv};
        float* dst = abase + (size_t)row * 1024 + c8;
        __builtin_nontemporal_store(f0, reinterpret_cast<f32x4*>(dst));
        __builtin_nontemporal_store(f1, reinterpret_cast<f32x4*>(dst + 4));
    }

    const __bf16* vb = vsb + rel * stride;
    f32x4 acc2 = {};
    for (int kb = 0; kb < 32; ++kb) {
        bf16x8 pa  = *reinterpret_cast<const bf16x8*>(&P[lr][kb * 32 + g * 8]);
        bf16x8 vb8 = ld8(vb + (size_t)(w * 16 + lr) * 1024 + kb * 32 + g * 8);
        acc2 = MFMA(pa, vb8, acc2);
    }
    int h = hb >> 3;
#pragma unroll
    for (int j = 0; j < 4; ++j) {
        int row = g * 4 + j;
        float tot  = reds[0][row] + reds[1][row] + reds[2][row] + reds[3][row];
        float mrow = fmaxf(fmaxf(redm[0][row], redm[1][row]),
                           fmaxf(redm[2][row], redm[3][row]));
        float inv = (mrow == -INFINITY) ? 0.f : 1.0f / tot;
        int srow = q0 + row;
        int vv = w * 16 + lr;
        x[(size_t)b * 1048576 + (size_t)srow * 1024 + h * 64 + vv] = (__bf16)(acc2[j] * inv);
    }
}

// copy q_s/k_s/v_sT tail slices (hb 116..127) into reloc buffer
__global__ void reloc_kernel(const __bf16* qs, const __bf16* ks, const __bf16* vs,
                             __bf16* rel) {
    int i = blockIdx.x * 256 + threadIdx.x;  // uint4 units: 12*3*8192 = 294912
    if (i >= 294912) return;
    int hbi = i / 24576;
    int r   = i % 24576;
    int t   = r / 8192, j = r % 8192;
    const __bf16* src = ((t == 0) ? qs : (t == 1) ? ks : vs) + (size_t)(116 + hbi) * 65536;
    __bf16* dst = rel + (size_t)hbi * 196608 + t * 65536;
    reinterpret_cast<uint4*>(dst)[j] = reinterpret_cast<const uint4*>(src)[j];
}

// out fp32 rows [row0, row0+16*grid) = LN(y + pb + q)*lg + lb. No LDS; 16 rows/block.
__global__ __launch_bounds__(256, 4)
void ln_kernel(const __bf16* __restrict__ y, const float* __restrict__ pb,
               const float* __restrict__ q, const float* __restrict__ lg,
               const float* __restrict__ lb, float* __restrict__ out, int row0) {
    int tid = threadIdx.x;
    int row = tid >> 4, j16 = tid & 15;
    size_t r = (size_t)row0 + blockIdx.x * 16 + row;
    int c0 = j16 * 64;

    float v[64];
    float s1 = 0.f, s2 = 0.f;
#pragma unroll
    for (int i = 0; i < 8; ++i) {
        bf16x8 yv = ld8(y + r * 1024 + c0 + i * 8);
        float4 q0v = *(const float4*)(q + r * 1024 + c0 + i * 8);
        float4 q1v = *(const float4*)(q + r * 1024 + c0 + i * 8 + 4);
        float4 p0v = *(const float4*)(pb + c0 + i * 8);
        float4 p1v = *(const float4*)(pb + c0 + i * 8 + 4);
        float t0 = (float)yv[0] + p0v.x + q0v.x;
        float t1 = (float)yv[1] + p0v.y + q0v.y;
        float t2 = (float)yv[2] + p0v.z + q0v.z;
        float t3 = (float)yv[3] + p0v.w + q0v.w;
        float t4 = (float)yv[4] + p1v.x + q1v.x;
        float t5 = (float)yv[5] + p1v.y + q1v.y;
        float t6 = (float)yv[6] + p1v.z + q1v.z;
        float t7 = (float)yv[7] + p1v.w + q1v.w;
        v[i * 8 + 0] = t0; v[i * 8 + 1] = t1; v[i * 8 + 2] = t2; v[i * 8 + 3] = t3;
        v[i * 8 + 4] = t4; v[i * 8 + 5] = t5; v[i * 8 + 6] = t6; v[i * 8 + 7] = t7;
        s1 += t0 + t1 + t2 + t3 + t4 + t5 + t6 + t7;
        s2 += t0 * t0 + t1 * t1 + t2 * t2 + t3 * t3 + t4 * t4 + t5 * t5 + t6 * t6 + t7 * t7;
    }
#pragma unroll
    for (int m = 8; m >= 1; m >>= 1) {
        s1 += __shfl_xor(s1, m);
        s2 += __shfl_xor(s2, m);
    }
    float mu  = s1 * (1.0f / 1024.0f);
    float var = fmaxf(s2 * (1.0f / 1024.0f) - mu * mu, 0.f);
    float rs  = rsqrtf(var + 1e-5f);
#pragma unroll
    for (int i = 0; i < 16; ++i) {
        int c = c0 + i * 4;
        float4 gv = *(const float4*)(lg + c);
        float4 bv = *(const float4*)(lb + c);
        float4 o;
        o.x = (v[i * 4 + 0] - mu) * rs * gv.x + bv.x;
        o.y = (v[i * 4 + 1] - mu) * rs * gv.y + bv.y;
        o.z = (v[i * 4 + 2] - mu) * rs * gv.z + bv.z;
        o.w = (v[i * 4 + 3] - mu) * rs * gv.w + bv.w;
        *(float4*)(out + r * 1024 + c) = o;
    }
}

extern "C" void kernel_launch(void* const* d_in, const int* in_sizes, int n_in,
                              void* d_out, int out_size, void* d_ws, size_t ws_size,
                              hipStream_t stream) {
    const float* Q  = (const float*)d_in[0];
    const float* K  = (const float*)d_in[1];
    const float* V  = (const float*)d_in[2];
    const void*  M  = d_in[3];
    const float* WQ = (const float*)d_in[4];
    const float* WK = (const float*)d_in[5];
    const float* WV = (const float*)d_in[6];
    const float* PW = (const float*)d_in[7];
    const float* PB = (const float*)d_in[8];
    const float* LG = (const float*)d_in[9];
    const float* LB = (const float*)d_in[10];

    float* outF  = (float*)d_out;           // 8,388,608 fp32
    float* attnF = outF + 8388608;          // 134,217,728 fp32

    unsigned* mbits = (unsigned*)(outF + 5505024);   // out bytes [22MB,23MB), dead after fused
    __bf16*   y     = (__bf16*)(outF + 4194304);     // out bytes [16.7MB,33.5MB), after fused

    pack_mask_kernel<<<1024, 256, 0, stream>>>(M, mbits);

    __bf16* x;
    if (ws_size >= (size_t)73400320) {
        // ---------- Path A: intermediates in d_ws ----------
        char* ws = (char*)d_ws;
        __bf16* wqT  = (__bf16*)ws;                        // 2 MB
        __bf16* wkT  = (__bf16*)(ws + 2097152);            // 2 MB
        __bf16* wvT  = (__bf16*)(ws + 4194304);            // 2 MB
        __bf16* q_s  = (__bf16*)(ws + 6291456);            // 16 MB [hb][s][kk]
        __bf16* k_s  = (__bf16*)(ws + 23068672);           // 16 MB
        __bf16* v_sT = (__bf16*)(ws + 39845888);           // 16 MB [hb][vv][s]
        x            = (__bf16*)(ws + 56623104);           // 16 MB [b][s][h*64+vv]

        transpose_w_kernel<<<768, 256, 0, stream>>>(WQ, WK, WV, wqT, wkT, wvT);
        gemm_proj_kernel<<<512, 256, 0, stream>>>(Q, wqT, q_s, 0);
        gemm_proj_kernel<<<512, 256, 0, stream>>>(K, wkT, k_s, 0);
        gemm_proj_kernel<<<512, 256, 0, stream>>>(V, wvT, v_sT, 1);
        fused_attn_kernel<<<8192, 256, 0, stream>>>(q_s, k_s, v_sT, (size_t)65536, 0,
                                                    mbits, attnF, x);
    } else {
        // ---------- Path B: scratch carved from d_out ----------
        __bf16* wqT  = (__bf16*)attnF;                            // chunk 0
        __bf16* wkT  = (__bf16*)(attnF + 1048576);                // chunk 1
        __bf16* wvT  = (__bf16*)(attnF + 2097152);                // chunk 2
        __bf16* q_s  = (__bf16*)(attnF + (size_t)116 * 1048576);  // chunks 116-119
        __bf16* k_s  = q_s + 8388608;                             // chunks 120-123
        __bf16* v_sT = k_s + 8388608;                             // chunks 124-127
        x            = (__bf16*)outF;                     // out bytes [0, 16.7M)
        __bf16* rel  = (__bf16*)(outF + 4194304);         // out bytes [16.7M, 21.5M)

        transpose_w_kernel<<<768, 256, 0, stream>>>(WQ, WK, WV, wqT, wkT, wvT);
        gemm_proj_kernel<<<512, 256, 0, stream>>>(Q, wqT, q_s, 0);
        gemm_proj_kernel<<<512, 256, 0, stream>>>(K, wkT, k_s, 0);
        gemm_proj_kernel<<<512, 256, 0, stream>>>(V, wvT, v_sT, 1);
        fused_attn_kernel<<<64 * 116, 256, 0, stream>>>(q_s, k_s, v_sT, (size_t)65536, 0,
                                                        mbits, attnF, x);
        reloc_kernel<<<1152, 256, 0, stream>>>(q_s, k_s, v_sT, rel);
        fused_attn_kernel<<<64 * 12, 256, 0, stream>>>(rel, rel + 65536, rel + 131072,
                                                       (size_t)196608, 116, mbits, attnF, x);
    }

    // out-projection GEMM -> y (bf16, upper half of out region; mbits/rel dead by now)
    gemm_out_kernel<<<512, 256, 0, stream>>>(x, PW, y);

    // LN pass, ascending halving cascade: fp32 row r clobbers y rows 2r,2r+1, which are
    // always in the already-consumed (or same-single-block) range.
    static const int PH[11] = {0, 4096, 6144, 7168, 7680, 7936, 8064, 8128, 8160, 8176, 8192};
    for (int p = 0; p < 10; ++p) {
        int r0 = PH[p], r1 = PH[p + 1];
        ln_kernel<<<(r1 - r0) / 16, 256, 0, stream>>>(y, PB, Q, LG, LB, outF, r0);
    }
}

// Round 24
// 514.247 us; speedup vs baseline: 3.2751x; 1.2081x over previous
//
#include <hip/hip_runtime.h>
#include <hip/hip_bf16.h>

// B=8, S=1024, D=1024, H=16, DK=DV=64. TEMPER=32.
// Contract (verified r15+): documented input order, fp32 floats, i32-or-byte mask at d3,
// d_out FLOAT32: out (8,1024,1024) then attns (128,1024,1024).
// r24: (1) 3 projections merged into one 1536-block launch (6 blocks/CU vs 2);
// (2) y in d_ws when ws>=90.2MB -> single-launch LN (cascade fallback);
// (3) explicit 1-deep K/V prefetch in fused QK^T / PV loops.

typedef __bf16 bf16x8 __attribute__((ext_vector_type(8)));
typedef float f32x4 __attribute__((ext_vector_type(4)));

#define MFMA(a, b, c) __builtin_amdgcn_mfma_f32_16x16x32_bf16(a, b, c, 0, 0, 0)

static __device__ __forceinline__ bf16x8 ld8(const __bf16* p) {
    return *reinterpret_cast<const bf16x8*>(p);
}
static __device__ __forceinline__ bf16x8 cvt8(float4 x, float4 y) {
    bf16x8 r;
    r[0] = (__bf16)x.x; r[1] = (__bf16)x.y; r[2] = (__bf16)x.z; r[3] = (__bf16)x.w;
    r[4] = (__bf16)y.x; r[5] = (__bf16)y.y; r[6] = (__bf16)y.z; r[7] = (__bf16)y.w;
    return r;
}

// pack mask (int32 or bytes, autodetected) -> 1 bit/elem. 262144 u32 words, grid 1024.
__global__ void pack_mask_kernel(const void* mask, unsigned* mbits) {
    int l = threadIdx.x & 63;
    unsigned w0 = ((const unsigned*)mask)[l];
    int bytemask = __any(w0 > 1u) ? 1 : 0;
    int i = blockIdx.x * 256 + threadIdx.x;
    unsigned out = 0;
    if (bytemask) {
        const unsigned char* m8 = (const unsigned char*)mask + (size_t)i * 32;
#pragma unroll
        for (int bt = 0; bt < 32; ++bt)
            if (m8[bt]) out |= (1u << bt);
    } else {
        const int* m32 = (const int*)mask + (size_t)i * 32;
#pragma unroll
        for (int bt = 0; bt < 32; ++bt)
            if (m32[bt]) out |= (1u << bt);
    }
    mbits[i] = out;
}

// tiled w transpose: [h][d][kk] fp32 -> [h][kk][d] bf16. grid 768.
__global__ void transpose_w_kernel(const float* wq, const float* wk, const float* wv,
                                   __bf16* wqT, __bf16* wkT, __bf16* wvT) {
    __shared__ __bf16 tile[64][65];
    int bid = blockIdx.x;
    int m  = bid >> 8;
    int h  = (bid >> 4) & 15;
    int db = bid & 15;
    const float* in = (m == 0) ? wq : (m == 1) ? wk : wv;
    __bf16*     out = (m == 0) ? wqT : (m == 1) ? wkT : wvT;
    int t = threadIdx.x;
#pragma unroll
    for (int i = 0; i < 16; ++i) {
        int idx = i * 256 + t;
        int dd = idx >> 6, kk = idx & 63;
        tile[kk][dd] = (__bf16)in[h * 65536 + (db * 64 + dd) * 64 + kk];
    }
    __syncthreads();
#pragma unroll
    for (int i = 0; i < 16; ++i) {
        int idx = i * 256 + t;
        int kk = idx >> 6, dd = idx & 63;
        out[h * 65536 + kk * 1024 + db * 64 + dd] = tile[kk][dd];
    }
}

// All three projections in one launch. grid 1536 (3 x 512 tiles), XCD-swizzled.
// which = sb>>9: 0->q_s(mode0), 1->k_s(mode0), 2->v_sT(mode1).
__global__ __launch_bounds__(256, 4)
void proj3_kernel(const float* __restrict__ Q, const float* __restrict__ K,
                  const float* __restrict__ V, const __bf16* __restrict__ wqT,
                  const __bf16* __restrict__ wkT, const __bf16* __restrict__ wvT,
                  __bf16* __restrict__ q_s, __bf16* __restrict__ k_s,
                  __bf16* __restrict__ v_sT) {
    __shared__ __bf16 As[128][32];
    __shared__ __bf16 Bs[128][32];
    int nb = gridDim.x;
    int sb = (blockIdx.x & 7) * (nb >> 3) + (blockIdx.x >> 3);  // XCD swizzle
    int which = sb >> 9;
    int t     = sb & 511;
    const float*  X   = (which == 0) ? Q : (which == 1) ? K : V;
    const __bf16* WT  = (which == 0) ? wqT : (which == 1) ? wkT : wvT;
    __bf16*       out = (which == 0) ? q_s : (which == 1) ? k_s : v_sT;
    int mode = (which == 2) ? 1 : 0;
    int m0 = (t >> 3) * 128;
    int n0 = (t & 7) * 128;

    int tid = threadIdx.x;
    int l = tid & 63, w = tid >> 6;
    int lr = l & 15, g = l >> 4;
    int wm = w >> 1, wn = w & 1;

    int srow = tid >> 1, shalf = tid & 1;
    const float*  Ag = X  + (size_t)(m0 + srow) * 1024 + shalf * 16;
    const __bf16* Bg = WT + (size_t)(n0 + srow) * 1024 + shalf * 16;

    f32x4 acc[4][4] = {};
    float4 a0 = *(const float4*)(Ag);
    float4 a1 = *(const float4*)(Ag + 4);
    float4 a2 = *(const float4*)(Ag + 8);
    float4 a3 = *(const float4*)(Ag + 12);
    uint4  bv0 = *(const uint4*)(Bg);
    uint4  bv1 = *(const uint4*)(Bg + 8);

    for (int kt = 0; kt < 32; ++kt) {
        *(bf16x8*)(&As[srow][shalf * 16])     = cvt8(a0, a1);
        *(bf16x8*)(&As[srow][shalf * 16 + 8]) = cvt8(a2, a3);
        *(uint4*)(&Bs[srow][shalf * 16])      = bv0;
        *(uint4*)(&Bs[srow][shalf * 16 + 8])  = bv1;
        __syncthreads();
        if (kt < 31) {
            const float* An = Ag + (kt + 1) * 32;
            a0 = *(const float4*)(An);
            a1 = *(const float4*)(An + 4);
            a2 = *(const float4*)(An + 8);
            a3 = *(const float4*)(An + 12);
            bv0 = *(const uint4*)(Bg + (kt + 1) * 32);
            bv1 = *(const uint4*)(Bg + (kt + 1) * 32 + 8);
        }
        bf16x8 af[4], bfr[4];
#pragma unroll
        for (int mi = 0; mi < 4; ++mi)
            af[mi] = *(const bf16x8*)(&As[wm * 64 + mi * 16 + lr][g * 8]);
#pragma unroll
        for (int ni = 0; ni < 4; ++ni)
            bfr[ni] = *(const bf16x8*)(&Bs[wn * 64 + ni * 16 + lr][g * 8]);
#pragma unroll
        for (int mi = 0; mi < 4; ++mi)
#pragma unroll
            for (int ni = 0; ni < 4; ++ni)
                acc[mi][ni] = MFMA(af[mi], bfr[ni], acc[mi][ni]);
        __syncthreads();
    }

#pragma unroll
    for (int mi = 0; mi < 4; ++mi)
#pragma unroll
        for (int ni = 0; ni < 4; ++ni)
#pragma unroll
            for (int j = 0; j < 4; ++j) {
                int r = m0 + wm * 64 + mi * 16 + g * 4 + j;
                int n = n0 + wn * 64 + ni * 16 + lr;
                size_t o;
                if (mode == 0)
                    o = (size_t)(n >> 6) * 524288 + (size_t)(r >> 10) * 65536 +
                        (size_t)(r & 1023) * 64 + (n & 63);
                else
                    o = (size_t)(n >> 6) * 524288 + (size_t)(r >> 10) * 65536 +
                        (size_t)(n & 63) * 1024 + (r & 1023);
                out[o] = (__bf16)acc[mi][ni][j];
            }
}

// y = x(bf16 8192x1024) @ PW(fp32 [n][k])^T -> y bf16 row-major. grid 512.
__global__ __launch_bounds__(256, 4)
void gemm_out_kernel(const __bf16* __restrict__ X, const float* __restrict__ W,
                     __bf16* __restrict__ y) {
    __shared__ __bf16 As[128][32];
    __shared__ __bf16 Bs[128][32];
    int nb = gridDim.x;
    int sb = (blockIdx.x & 7) * (nb >> 3) + (blockIdx.x >> 3);  // XCD swizzle
    int m0 = (sb >> 3) * 128;
    int n0 = (sb & 7) * 128;
    int tid = threadIdx.x;
    int l = tid & 63, w = tid >> 6;
    int lr = l & 15, g = l >> 4;
    int wm = w >> 1, wn = w & 1;

    int srow = tid >> 1, shalf = tid & 1;
    const __bf16* Ag = X + (size_t)(m0 + srow) * 1024 + shalf * 16;
    const float*  Bg = W + (size_t)(n0 + srow) * 1024 + shalf * 16;

    f32x4 acc[4][4] = {};
    uint4  av0 = *(const uint4*)(Ag);
    uint4  av1 = *(const uint4*)(Ag + 8);
    float4 b0 = *(const float4*)(Bg);
    float4 b1 = *(const float4*)(Bg + 4);
    float4 b2 = *(const float4*)(Bg + 8);
    float4 b3 = *(const float4*)(Bg + 12);

    for (int kt = 0; kt < 32; ++kt) {
        *(uint4*)(&As[srow][shalf * 16])      = av0;
        *(uint4*)(&As[srow][shalf * 16 + 8])  = av1;
        *(bf16x8*)(&Bs[srow][shalf * 16])     = cvt8(b0, b1);
        *(bf16x8*)(&Bs[srow][shalf * 16 + 8]) = cvt8(b2, b3);
        __syncthreads();
        if (kt < 31) {
            av0 = *(const uint4*)(Ag + (kt + 1) * 32);
            av1 = *(const uint4*)(Ag + (kt + 1) * 32 + 8);
            const float* Bn = Bg + (kt + 1) * 32;
            b0 = *(const float4*)(Bn);
            b1 = *(const float4*)(Bn + 4);
            b2 = *(const float4*)(Bn + 8);
            b3 = *(const float4*)(Bn + 12);
        }
        bf16x8 af[4], bfr[4];
#pragma unroll
        for (int mi = 0; mi < 4; ++mi)
            af[mi] = *(const bf16x8*)(&As[wm * 64 + mi * 16 + lr][g * 8]);
#pragma unroll
        for (int ni = 0; ni < 4; ++ni)
            bfr[ni] = *(const bf16x8*)(&Bs[wn * 64 + ni * 16 + lr][g * 8]);
#pragma unroll
        for (int mi = 0; mi < 4; ++mi)
#pragma unroll
            for (int ni = 0; ni < 4; ++ni)
                acc[mi][ni] = MFMA(af[mi], bfr[ni], acc[mi][ni]);
        __syncthreads();
    }

#pragma unroll
    for (int mi = 0; mi < 4; ++mi)
#pragma unroll
        for (int ni = 0; ni < 4; ++ni)
#pragma unroll
            for (int j = 0; j < 4; ++j) {
                int r = m0 + wm * 64 + mi * 16 + g * 4 + j;
                int n = n0 + wn * 64 + ni * 16 + lr;
                y[(size_t)r * 1024 + n] = (__bf16)acc[mi][ni][j];
            }
}

// Fused scores+softmax+attns+PV. 1-D grid n = 64*nhb (n % 8 == 0), XCD-swizzled.
// K/V explicitly prefetched 1 iteration ahead.
__global__ __launch_bounds__(256, 4)
void fused_attn_kernel(const __bf16* __restrict__ qsb, const __bf16* __restrict__ ksb,
                       const __bf16* __restrict__ vsb, size_t stride, int hb0,
                       const unsigned* __restrict__ mbits,
                       float* __restrict__ attnF, __bf16* __restrict__ x) {
    __shared__ __bf16 P[16][1040];           // pad -> conflict-free PV reads
    __shared__ float redm[4][16], reds[4][16];
    __shared__ unsigned mb[16][32];

    int nb = gridDim.x;
    int sb = (blockIdx.x & 7) * (nb >> 3) + (blockIdx.x >> 3);  // XCD swizzle
    int rel = sb >> 6;
    int q0  = (sb & 63) * 16;
    int hb  = hb0 + rel;
    int tid = threadIdx.x;
    int l = tid & 63, w = tid >> 6;
    int lr = l & 15, g = l >> 4;
    int b = hb & 7;

#pragma unroll
    for (int i = 0; i < 2; ++i) {
        int idx = i * 256 + tid;
        mb[idx >> 5][idx & 31] = mbits[((size_t)b * 1024 + q0 + (idx >> 5)) * 32 + (idx & 31)];
    }

    const __bf16* qb = qsb + rel * stride + (size_t)q0 * 64;
    const __bf16* ks = ksb + rel * stride;
    bf16x8 a0 = ld8(qb + lr * 64 + g * 8);
    bf16x8 a1 = ld8(qb + lr * 64 + 32 + g * 8);
    __syncthreads();

    // QK^T with 1-deep K prefetch
    const __bf16* kbase = ks + (size_t)(w * 256 + lr) * 64 + g * 8;
    bf16x8 kA = ld8(kbase);
    bf16x8 kB = ld8(kbase + 32);
    float s[16][4];
    float mx[4] = {-INFINITY, -INFINITY, -INFINITY, -INFINITY};
#pragma unroll
    for (int kt = 0; kt < 16; ++kt) {
        bf16x8 curA = kA, curB = kB;
        if (kt < 15) {
            const __bf16* bpn = kbase + (size_t)(kt + 1) * 16 * 64;
            kA = ld8(bpn);
            kB = ld8(bpn + 32);
        }
        f32x4 acc = {};
        acc = MFMA(a0, curA, acc);
        acc = MFMA(a1, curB, acc);
#pragma unroll
        for (int j = 0; j < 4; ++j) {
            unsigned wbits = mb[g * 4 + j][w * 8 + (kt >> 1)];
            bool mk = (wbits >> ((kt & 1) * 16 + lr)) & 1u;
            float v = mk ? -INFINITY : acc[j] * 0.03125f;  // /TEMPER
            s[kt][j] = v;
            mx[j] = fmaxf(mx[j], v);
        }
    }
#pragma unroll
    for (int j = 0; j < 4; ++j) {
#pragma unroll
        for (int o = 8; o >= 1; o >>= 1) mx[j] = fmaxf(mx[j], __shfl_xor(mx[j], o));
    }
    if (lr == 0) {
#pragma unroll
        for (int j = 0; j < 4; ++j) redm[w][g * 4 + j] = mx[j];
    }
    __syncthreads();
#pragma unroll
    for (int j = 0; j < 4; ++j) {
        int row = g * 4 + j;
        mx[j] = fmaxf(fmaxf(redm[0][row], redm[1][row]), fmaxf(redm[2][row], redm[3][row]));
    }

    float sum[4] = {0.f, 0.f, 0.f, 0.f};
#pragma unroll
    for (int j = 0; j < 4; ++j) {
        int row = g * 4 + j;
        float m = (mx[j] == -INFINITY) ? 0.f : mx[j];
#pragma unroll
        for (int kt = 0; kt < 16; ++kt) {
            float v = s[kt][j];
            float e = (v == -INFINITY) ? 0.f : __expf(v - m);
            sum[j] += e;
            P[row][w * 256 + kt * 16 + lr] = (__bf16)e;
        }
    }
#pragma unroll
    for (int j = 0; j < 4; ++j) {
#pragma unroll
        for (int o = 8; o >= 1; o >>= 1) sum[j] += __shfl_xor(sum[j], o);
    }
    if (lr == 0) {
#pragma unroll
        for (int j = 0; j < 4; ++j) reds[w][g * 4 + j] = sum[j];
    }
    __syncthreads();

    // coalesced nontemporal attns write (attns never re-read)
    float* abase = attnF + (size_t)hb * 1048576 + (size_t)q0 * 1024;
#pragma unroll
    for (int i = 0; i < 8; ++i) {
        int idx = i * 256 + tid;
        int row = idx >> 7;
        int c8  = (idx & 127) * 8;
        float tot  = reds[0][row] + reds[1][row] + reds[2][row] + reds[3][row];
        float mrow = fmaxf(fmaxf(redm[0][row], redm[1][row]),
                           fmaxf(redm[2][row], redm[3][row]));
        float inv = (mrow == -INFINITY) ? 0.f : 1.0f / tot;
        bf16x8 pv = *reinterpret_cast<const bf16x8*>(&P[row][c8]);
        f32x4 f0 = {(float)pv[0] * inv, (float)pv[1] * inv,
                    (float)pv[2] * inv, (float)pv[3] * inv};
        f32x4 f1 = {(float)pv[4] * inv, (float)pv[5] * inv,
                    (float)pv[6] * inv, (float)pv[7] * inv};
        float* dst = abase + (size_t)row * 1024 + c8;
        __builtin_nontemporal_store(f0, reinterpret_cast<f32x4*>(dst));
        __builtin_nontemporal_store(f1, reinterpret_cast<f32x4*>(dst + 4));
    }

    // PV with 1-deep V prefetch
    const __bf16* vrow = vsb + rel * stride + (size_t)(w * 16 + lr) * 1024 + g * 8;
    bf16x8 vv8 = ld8(vrow);
    f32x4 acc2 = {};
    for (int kb = 0; kb < 32; ++kb) {
        bf16x8 cur = vv8;
        if (kb < 31) vv8 = ld8(vrow + (kb + 1) * 32);
        bf16x8 pa = *reinterpret_cast<const bf16x8*>(&P[lr][kb * 32 + g * 8]);
        acc2 = MFMA(pa, cur, acc2);
    }
    int h = hb >> 3;
#pragma unroll
    for (int j = 0; j < 4; ++j) {
        int row = g * 4 + j;
        float tot  = reds[0][row] + reds[1][row] + reds[2][row] + reds[3][row];
        float mrow = fmaxf(fmaxf(redm[0][row], redm[1][row]),
                           fmaxf(redm[2][row], redm[3][row]));
        float inv = (mrow == -INFINITY) ? 0.f : 1.0f / tot;
        int srow = q0 + row;
        int vv = w * 16 + lr;
        x[(size_t)b * 1048576 + (size_t)srow * 1024 + h * 64 + vv] = (__bf16)(acc2[j] * inv);
    }
}

// copy q_s/k_s/v_sT tail slices (hb 116..127) into reloc buffer
__global__ void reloc_kernel(const __bf16* qs, const __bf16* ks, const __bf16* vs,
                             __bf16* rel) {
    int i = blockIdx.x * 256 + threadIdx.x;  // uint4 units: 12*3*8192 = 294912
    if (i >= 294912) return;
    int hbi = i / 24576;
    int r   = i % 24576;
    int t   = r / 8192, j = r % 8192;
    const __bf16* src = ((t == 0) ? qs : (t == 1) ? ks : vs) + (size_t)(116 + hbi) * 65536;
    __bf16* dst = rel + (size_t)hbi * 196608 + t * 65536;
    reinterpret_cast<uint4*>(dst)[j] = reinterpret_cast<const uint4*>(src)[j];
}

// out fp32 rows [row0, row0+16*grid) = LN(y + pb + q)*lg + lb. No LDS; 16 rows/block.
__global__ __launch_bounds__(256, 4)
void ln_kernel(const __bf16* __restrict__ y, const float* __restrict__ pb,
               const float* __restrict__ q, const float* __restrict__ lg,
               const float* __restrict__ lb, float* __restrict__ out, int row0) {
    int tid = threadIdx.x;
    int row = tid >> 4, j16 = tid & 15;
    size_t r = (size_t)row0 + blockIdx.x * 16 + row;
    int c0 = j16 * 64;

    float v[64];
    float s1 = 0.f, s2 = 0.f;
#pragma unroll
    for (int i = 0; i < 8; ++i) {
        bf16x8 yv = ld8(y + r * 1024 + c0 + i * 8);
        float4 q0v = *(const float4*)(q + r * 1024 + c0 + i * 8);
        float4 q1v = *(const float4*)(q + r * 1024 + c0 + i * 8 + 4);
        float4 p0v = *(const float4*)(pb + c0 + i * 8);
        float4 p1v = *(const float4*)(pb + c0 + i * 8 + 4);
        float t0 = (float)yv[0] + p0v.x + q0v.x;
        float t1 = (float)yv[1] + p0v.y + q0v.y;
        float t2 = (float)yv[2] + p0v.z + q0v.z;
        float t3 = (float)yv[3] + p0v.w + q0v.w;
        float t4 = (float)yv[4] + p1v.x + q1v.x;
        float t5 = (float)yv[5] + p1v.y + q1v.y;
        float t6 = (float)yv[6] + p1v.z + q1v.z;
        float t7 = (float)yv[7] + p1v.w + q1v.w;
        v[i * 8 + 0] = t0; v[i * 8 + 1] = t1; v[i * 8 + 2] = t2; v[i * 8 + 3] = t3;
        v[i * 8 + 4] = t4; v[i * 8 + 5] = t5; v[i * 8 + 6] = t6; v[i * 8 + 7] = t7;
        s1 += t0 + t1 + t2 + t3 + t4 + t5 + t6 + t7;
        s2 += t0 * t0 + t1 * t1 + t2 * t2 + t3 * t3 + t4 * t4 + t5 * t5 + t6 * t6 + t7 * t7;
    }
#pragma unroll
    for (int m = 8; m >= 1; m >>= 1) {
        s1 += __shfl_xor(s1, m);
        s2 += __shfl_xor(s2, m);
    }
    float mu  = s1 * (1.0f / 1024.0f);
    float var = fmaxf(s2 * (1.0f / 1024.0f) - mu * mu, 0.f);
    float rs  = rsqrtf(var + 1e-5f);
#pragma unroll
    for (int i = 0; i < 16; ++i) {
        int c = c0 + i * 4;
        float4 gv = *(const float4*)(lg + c);
        float4 bv = *(const float4*)(lb + c);
        float4 o;
        o.x = (v[i * 4 + 0] - mu) * rs * gv.x + bv.x;
        o.y = (v[i * 4 + 1] - mu) * rs * gv.y + bv.y;
        o.z = (v[i * 4 + 2] - mu) * rs * gv.z + bv.z;
        o.w = (v[i * 4 + 3] - mu) * rs * gv.w + bv.w;
        *(float4*)(out + r * 1024 + c) = o;
    }
}

extern "C" void kernel_launch(void* const* d_in, const int* in_sizes, int n_in,
                              void* d_out, int out_size, void* d_ws, size_t ws_size,
                              hipStream_t stream) {
    const float* Q  = (const float*)d_in[0];
    const float* K  = (const float*)d_in[1];
    const float* V  = (const float*)d_in[2];
    const void*  M  = d_in[3];
    const float* WQ = (const float*)d_in[4];
    const float* WK = (const float*)d_in[5];
    const float* WV = (const float*)d_in[6];
    const float* PW = (const float*)d_in[7];
    const float* PB = (const float*)d_in[8];
    const float* LG = (const float*)d_in[9];
    const float* LB = (const float*)d_in[10];

    float* outF  = (float*)d_out;           // 8,388,608 fp32
    float* attnF = outF + 8388608;          // 134,217,728 fp32

    unsigned* mbits = (unsigned*)(outF + 5505024);   // out bytes [22MB,23MB), dead after fused
    __bf16*   y     = (__bf16*)(outF + 4194304);     // default: out bytes [16.7MB,33.5MB)
    bool y_in_ws = false;

    pack_mask_kernel<<<1024, 256, 0, stream>>>(M, mbits);

    __bf16* x;
    if (ws_size >= (size_t)73400320) {
        // ---------- Path A: intermediates in d_ws ----------
        char* ws = (char*)d_ws;
        __bf16* wqT  = (__bf16*)ws;                        // 2 MB
        __bf16* wkT  = (__bf16*)(ws + 2097152);            // 2 MB
        __bf16* wvT  = (__bf16*)(ws + 4194304);            // 2 MB
        __bf16* q_s  = (__bf16*)(ws + 6291456);            // 16 MB [hb][s][kk]
        __bf16* k_s  = (__bf16*)(ws + 23068672);           // 16 MB
        __bf16* v_sT = (__bf16*)(ws + 39845888);           // 16 MB [hb][vv][s]
        x            = (__bf16*)(ws + 56623104);           // 16 MB [b][s][h*64+vv]
        if (ws_size >= (size_t)90177536) {                 // +16 MB for y
            y = (__bf16*)(ws + 73400320);
            y_in_ws = true;
        }

        transpose_w_kernel<<<768, 256, 0, stream>>>(WQ, WK, WV, wqT, wkT, wvT);
        proj3_kernel<<<1536, 256, 0, stream>>>(Q, K, V, wqT, wkT, wvT, q_s, k_s, v_sT);
        fused_attn_kernel<<<8192, 256, 0, stream>>>(q_s, k_s, v_sT, (size_t)65536, 0,
                                                    mbits, attnF, x);
    } else {
        // ---------- Path B: scratch carved from d_out ----------
        __bf16* wqT  = (__bf16*)attnF;                            // chunk 0
        __bf16* wkT  = (__bf16*)(attnF + 1048576);                // chunk 1
        __bf16* wvT  = (__bf16*)(attnF + 2097152);                // chunk 2
        __bf16* q_s  = (__bf16*)(attnF + (size_t)116 * 1048576);  // chunks 116-119
        __bf16* k_s  = q_s + 8388608;                             // chunks 120-123
        __bf16* v_sT = k_s + 8388608;                             // chunks 124-127
        x            = (__bf16*)outF;                     // out bytes [0, 16.7M)
        __bf16* rel  = (__bf16*)(outF + 4194304);         // out bytes [16.7M, 21.5M)

        transpose_w_kernel<<<768, 256, 0, stream>>>(WQ, WK, WV, wqT, wkT, wvT);
        proj3_kernel<<<1536, 256, 0, stream>>>(Q, K, V, wqT, wkT, wvT, q_s, k_s, v_sT);
        fused_attn_kernel<<<64 * 116, 256, 0, stream>>>(q_s, k_s, v_sT, (size_t)65536, 0,
                                                        mbits, attnF, x);
        reloc_kernel<<<1152, 256, 0, stream>>>(q_s, k_s, v_sT, rel);
        fused_attn_kernel<<<64 * 12, 256, 0, stream>>>(rel, rel + 65536, rel + 131072,
                                                       (size_t)196608, 116, mbits, attnF, x);
    }

    // out-projection GEMM -> y
    gemm_out_kernel<<<512, 256, 0, stream>>>(x, PW, y);

    if (y_in_ws) {
        // no aliasing: single LN launch over all 8192 rows
        ln_kernel<<<512, 256, 0, stream>>>(y, PB, Q, LG, LB, outF, 0);
    } else {
        // LN cascade: fp32 row r clobbers y rows 2r,2r+1 (already consumed per phase)
        static const int PH[11] = {0, 4096, 6144, 7168, 7680, 7936, 8064, 8128, 8160, 8176, 8192};
        for (int p = 0; p < 10; ++p) {
            int r0 = PH[p], r1 = PH[p + 1];
            ln_kernel<<<(r1 - r0) / 16, 256, 0, stream>>>(y, PB, Q, LG, LB, outF, r0);
        }
    }
}

// Round 25
// 476.698 us; speedup vs baseline: 3.5331x; 1.0788x over previous
//
#include <hip/hip_runtime.h>
#include <hip/hip_bf16.h>

// B=8, S=1024, D=1024, H=16, DK=DV=64. TEMPER=32.
// Contract (verified r15+): documented input order, fp32 floats, i32-or-byte mask at d3,
// d_out FLOAT32: out (8,1024,1024) then attns (128,1024,1024).
// r25: fused kernel -> 32-row q-tile (halves K/V/mask traffic per row, 2x per-thread ILP;
// 2 blocks/CU, launch_bounds(256,2)). Rest identical to r24.

typedef __bf16 bf16x8 __attribute__((ext_vector_type(8)));
typedef float f32x4 __attribute__((ext_vector_type(4)));

#define MFMA(a, b, c) __builtin_amdgcn_mfma_f32_16x16x32_bf16(a, b, c, 0, 0, 0)

static __device__ __forceinline__ bf16x8 ld8(const __bf16* p) {
    return *reinterpret_cast<const bf16x8*>(p);
}
static __device__ __forceinline__ bf16x8 cvt8(float4 x, float4 y) {
    bf16x8 r;
    r[0] = (__bf16)x.x; r[1] = (__bf16)x.y; r[2] = (__bf16)x.z; r[3] = (__bf16)x.w;
    r[4] = (__bf16)y.x; r[5] = (__bf16)y.y; r[6] = (__bf16)y.z; r[7] = (__bf16)y.w;
    return r;
}

// pack mask (int32 or bytes, autodetected) -> 1 bit/elem. 262144 u32 words, grid 1024.
__global__ void pack_mask_kernel(const void* mask, unsigned* mbits) {
    int l = threadIdx.x & 63;
    unsigned w0 = ((const unsigned*)mask)[l];
    int bytemask = __any(w0 > 1u) ? 1 : 0;
    int i = blockIdx.x * 256 + threadIdx.x;
    unsigned out = 0;
    if (bytemask) {
        const unsigned char* m8 = (const unsigned char*)mask + (size_t)i * 32;
#pragma unroll
        for (int bt = 0; bt < 32; ++bt)
            if (m8[bt]) out |= (1u << bt);
    } else {
        const int* m32 = (const int*)mask + (size_t)i * 32;
#pragma unroll
        for (int bt = 0; bt < 32; ++bt)
            if (m32[bt]) out |= (1u << bt);
    }
    mbits[i] = out;
}

// tiled w transpose: [h][d][kk] fp32 -> [h][kk][d] bf16. grid 768.
__global__ void transpose_w_kernel(const float* wq, const float* wk, const float* wv,
                                   __bf16* wqT, __bf16* wkT, __bf16* wvT) {
    __shared__ __bf16 tile[64][65];
    int bid = blockIdx.x;
    int m  = bid >> 8;
    int h  = (bid >> 4) & 15;
    int db = bid & 15;
    const float* in = (m == 0) ? wq : (m == 1) ? wk : wv;
    __bf16*     out = (m == 0) ? wqT : (m == 1) ? wkT : wvT;
    int t = threadIdx.x;
#pragma unroll
    for (int i = 0; i < 16; ++i) {
        int idx = i * 256 + t;
        int dd = idx >> 6, kk = idx & 63;
        tile[kk][dd] = (__bf16)in[h * 65536 + (db * 64 + dd) * 64 + kk];
    }
    __syncthreads();
#pragma unroll
    for (int i = 0; i < 16; ++i) {
        int idx = i * 256 + t;
        int kk = idx >> 6, dd = idx & 63;
        out[h * 65536 + kk * 1024 + db * 64 + dd] = tile[kk][dd];
    }
}

// All three projections in one launch. grid 1536 (3 x 512 tiles), XCD-swizzled.
__global__ __launch_bounds__(256, 4)
void proj3_kernel(const float* __restrict__ Q, const float* __restrict__ K,
                  const float* __restrict__ V, const __bf16* __restrict__ wqT,
                  const __bf16* __restrict__ wkT, const __bf16* __restrict__ wvT,
                  __bf16* __restrict__ q_s, __bf16* __restrict__ k_s,
                  __bf16* __restrict__ v_sT) {
    __shared__ __bf16 As[128][32];
    __shared__ __bf16 Bs[128][32];
    int nb = gridDim.x;
    int sb = (blockIdx.x & 7) * (nb >> 3) + (blockIdx.x >> 3);  // XCD swizzle
    int which = sb >> 9;
    int t     = sb & 511;
    const float*  X   = (which == 0) ? Q : (which == 1) ? K : V;
    const __bf16* WT  = (which == 0) ? wqT : (which == 1) ? wkT : wvT;
    __bf16*       out = (which == 0) ? q_s : (which == 1) ? k_s : v_sT;
    int mode = (which == 2) ? 1 : 0;
    int m0 = (t >> 3) * 128;
    int n0 = (t & 7) * 128;

    int tid = threadIdx.x;
    int l = tid & 63, w = tid >> 6;
    int lr = l & 15, g = l >> 4;
    int wm = w >> 1, wn = w & 1;

    int srow = tid >> 1, shalf = tid & 1;
    const float*  Ag = X  + (size_t)(m0 + srow) * 1024 + shalf * 16;
    const __bf16* Bg = WT + (size_t)(n0 + srow) * 1024 + shalf * 16;

    f32x4 acc[4][4] = {};
    float4 a0 = *(const float4*)(Ag);
    float4 a1 = *(const float4*)(Ag + 4);
    float4 a2 = *(const float4*)(Ag + 8);
    float4 a3 = *(const float4*)(Ag + 12);
    uint4  bv0 = *(const uint4*)(Bg);
    uint4  bv1 = *(const uint4*)(Bg + 8);

    for (int kt = 0; kt < 32; ++kt) {
        *(bf16x8*)(&As[srow][shalf * 16])     = cvt8(a0, a1);
        *(bf16x8*)(&As[srow][shalf * 16 + 8]) = cvt8(a2, a3);
        *(uint4*)(&Bs[srow][shalf * 16])      = bv0;
        *(uint4*)(&Bs[srow][shalf * 16 + 8])  = bv1;
        __syncthreads();
        if (kt < 31) {
            const float* An = Ag + (kt + 1) * 32;
            a0 = *(const float4*)(An);
            a1 = *(const float4*)(An + 4);
            a2 = *(const float4*)(An + 8);
            a3 = *(const float4*)(An + 12);
            bv0 = *(const uint4*)(Bg + (kt + 1) * 32);
            bv1 = *(const uint4*)(Bg + (kt + 1) * 32 + 8);
        }
        bf16x8 af[4], bfr[4];
#pragma unroll
        for (int mi = 0; mi < 4; ++mi)
            af[mi] = *(const bf16x8*)(&As[wm * 64 + mi * 16 + lr][g * 8]);
#pragma unroll
        for (int ni = 0; ni < 4; ++ni)
            bfr[ni] = *(const bf16x8*)(&Bs[wn * 64 + ni * 16 + lr][g * 8]);
#pragma unroll
        for (int mi = 0; mi < 4; ++mi)
#pragma unroll
            for (int ni = 0; ni < 4; ++ni)
                acc[mi][ni] = MFMA(af[mi], bfr[ni], acc[mi][ni]);
        __syncthreads();
    }

#pragma unroll
    for (int mi = 0; mi < 4; ++mi)
#pragma unroll
        for (int ni = 0; ni < 4; ++ni)
#pragma unroll
            for (int j = 0; j < 4; ++j) {
                int r = m0 + wm * 64 + mi * 16 + g * 4 + j;
                int n = n0 + wn * 64 + ni * 16 + lr;
                size_t o;
                if (mode == 0)
                    o = (size_t)(n >> 6) * 524288 + (size_t)(r >> 10) * 65536 +
                        (size_t)(r & 1023) * 64 + (n & 63);
                else
                    o = (size_t)(n >> 6) * 524288 + (size_t)(r >> 10) * 65536 +
                        (size_t)(n & 63) * 1024 + (r & 1023);
                out[o] = (__bf16)acc[mi][ni][j];
            }
}

// y = x(bf16 8192x1024) @ PW(fp32 [n][k])^T -> y bf16 row-major. grid 512.
__global__ __launch_bounds__(256, 4)
void gemm_out_kernel(const __bf16* __restrict__ X, const float* __restrict__ W,
                     __bf16* __restrict__ y) {
    __shared__ __bf16 As[128][32];
    __shared__ __bf16 Bs[128][32];
    int nb = gridDim.x;
    int sb = (blockIdx.x & 7) * (nb >> 3) + (blockIdx.x >> 3);  // XCD swizzle
    int m0 = (sb >> 3) * 128;
    int n0 = (sb & 7) * 128;
    int tid = threadIdx.x;
    int l = tid & 63, w = tid >> 6;
    int lr = l & 15, g = l >> 4;
    int wm = w >> 1, wn = w & 1;

    int srow = tid >> 1, shalf = tid & 1;
    const __bf16* Ag = X + (size_t)(m0 + srow) * 1024 + shalf * 16;
    const float*  Bg = W + (size_t)(n0 + srow) * 1024 + shalf * 16;

    f32x4 acc[4][4] = {};
    uint4  av0 = *(const uint4*)(Ag);
    uint4  av1 = *(const uint4*)(Ag + 8);
    float4 b0 = *(const float4*)(Bg);
    float4 b1 = *(const float4*)(Bg + 4);
    float4 b2 = *(const float4*)(Bg + 8);
    float4 b3 = *(const float4*)(Bg + 12);

    for (int kt = 0; kt < 32; ++kt) {
        *(uint4*)(&As[srow][shalf * 16])      = av0;
        *(uint4*)(&As[srow][shalf * 16 + 8])  = av1;
        *(bf16x8*)(&Bs[srow][shalf * 16])     = cvt8(b0, b1);
        *(bf16x8*)(&Bs[srow][shalf * 16 + 8]) = cvt8(b2, b3);
        __syncthreads();
        if (kt < 31) {
            av0 = *(const uint4*)(Ag + (kt + 1) * 32);
            av1 = *(const uint4*)(Ag + (kt + 1) * 32 + 8);
            const float* Bn = Bg + (kt + 1) * 32;
            b0 = *(const float4*)(Bn);
            b1 = *(const float4*)(Bn + 4);
            b2 = *(const float4*)(Bn + 8);
            b3 = *(const float4*)(Bn + 12);
        }
        bf16x8 af[4], bfr[4];
#pragma unroll
        for (int mi = 0; mi < 4; ++mi)
            af[mi] = *(const bf16x8*)(&As[wm * 64 + mi * 16 + lr][g * 8]);
#pragma unroll
        for (int ni = 0; ni < 4; ++ni)
            bfr[ni] = *(const bf16x8*)(&Bs[wn * 64 + ni * 16 + lr][g * 8]);
#pragma unroll
        for (int mi = 0; mi < 4; ++mi)
#pragma unroll
            for (int ni = 0; ni < 4; ++ni)
                acc[mi][ni] = MFMA(af[mi], bfr[ni], acc[mi][ni]);
        __syncthreads();
    }

#pragma unroll
    for (int mi = 0; mi < 4; ++mi)
#pragma unroll
        for (int ni = 0; ni < 4; ++ni)
#pragma unroll
            for (int j = 0; j < 4; ++j) {
                int r = m0 + wm * 64 + mi * 16 + g * 4 + j;
                int n = n0 + wn * 64 + ni * 16 + lr;
                y[(size_t)r * 1024 + n] = (__bf16)acc[mi][ni][j];
            }
}

// Fused scores+softmax+attns+PV, 32-row q-tile. grid 32*nhb (divisible by 8), XCD-swizzled.
__global__ __launch_bounds__(256, 2)
void fused_attn_kernel(const __bf16* __restrict__ qsb, const __bf16* __restrict__ ksb,
                       const __bf16* __restrict__ vsb, size_t stride, int hb0,
                       const unsigned* __restrict__ mbits,
                       float* __restrict__ attnF, __bf16* __restrict__ x) {
    __shared__ __bf16 P[32][1040];           // 66.6 KB; row stride 8 banks -> conflict-free
    __shared__ float redm[4][32], reds[4][32];
    __shared__ unsigned mb[32][32];          // 4 KB

    int nb = gridDim.x;
    int sb = (blockIdx.x & 7) * (nb >> 3) + (blockIdx.x >> 3);  // XCD swizzle
    int rel = sb >> 5;
    int q0  = (sb & 31) * 32;
    int hb  = hb0 + rel;
    int tid = threadIdx.x;
    int l = tid & 63, w = tid >> 6;
    int lr = l & 15, g = l >> 4;
    int b = hb & 7;

#pragma unroll
    for (int i = 0; i < 4; ++i) {
        int idx = i * 256 + tid;
        mb[idx >> 5][idx & 31] = mbits[((size_t)b * 1024 + q0 + (idx >> 5)) * 32 + (idx & 31)];
    }

    const __bf16* qb = qsb + rel * stride + (size_t)q0 * 64;
    const __bf16* ks = ksb + rel * stride;
    bf16x8 aQ[2][2];
#pragma unroll
    for (int rh = 0; rh < 2; ++rh) {
        aQ[rh][0] = ld8(qb + (size_t)(rh * 16 + lr) * 64 + g * 8);
        aQ[rh][1] = ld8(qb + (size_t)(rh * 16 + lr) * 64 + 32 + g * 8);
    }
    __syncthreads();

    // QK^T with 1-deep K prefetch; two row-halves share each K fragment
    const __bf16* kbase = ks + (size_t)(w * 256 + lr) * 64 + g * 8;
    bf16x8 kA = ld8(kbase);
    bf16x8 kB = ld8(kbase + 32);
    float s_lo[16][4], s_hi[16][4];
    float mx_lo[4] = {-INFINITY, -INFINITY, -INFINITY, -INFINITY};
    float mx_hi[4] = {-INFINITY, -INFINITY, -INFINITY, -INFINITY};
#pragma unroll
    for (int kt = 0; kt < 16; ++kt) {
        bf16x8 curA = kA, curB = kB;
        if (kt < 15) {
            const __bf16* bpn = kbase + (size_t)(kt + 1) * 16 * 64;
            kA = ld8(bpn);
            kB = ld8(bpn + 32);
        }
        f32x4 accl = {}, acch = {};
        accl = MFMA(aQ[0][0], curA, accl);
        accl = MFMA(aQ[0][1], curB, accl);
        acch = MFMA(aQ[1][0], curA, acch);
        acch = MFMA(aQ[1][1], curB, acch);
#pragma unroll
        for (int j = 0; j < 4; ++j) {
            unsigned wl = mb[g * 4 + j][w * 8 + (kt >> 1)];
            unsigned wh = mb[16 + g * 4 + j][w * 8 + (kt >> 1)];
            int sh = (kt & 1) * 16 + lr;
            float vl = ((wl >> sh) & 1u) ? -INFINITY : accl[j] * 0.03125f;
            float vh = ((wh >> sh) & 1u) ? -INFINITY : acch[j] * 0.03125f;
            s_lo[kt][j] = vl;
            s_hi[kt][j] = vh;
            mx_lo[j] = fmaxf(mx_lo[j], vl);
            mx_hi[j] = fmaxf(mx_hi[j], vh);
        }
    }
#pragma unroll
    for (int j = 0; j < 4; ++j) {
#pragma unroll
        for (int o = 8; o >= 1; o >>= 1) {
            mx_lo[j] = fmaxf(mx_lo[j], __shfl_xor(mx_lo[j], o));
            mx_hi[j] = fmaxf(mx_hi[j], __shfl_xor(mx_hi[j], o));
        }
    }
    if (lr == 0) {
#pragma unroll
        for (int j = 0; j < 4; ++j) {
            redm[w][g * 4 + j]      = mx_lo[j];
            redm[w][16 + g * 4 + j] = mx_hi[j];
        }
    }
    __syncthreads();
#pragma unroll
    for (int j = 0; j < 4; ++j) {
        int rl = g * 4 + j, rh = 16 + g * 4 + j;
        mx_lo[j] = fmaxf(fmaxf(redm[0][rl], redm[1][rl]), fmaxf(redm[2][rl], redm[3][rl]));
        mx_hi[j] = fmaxf(fmaxf(redm[0][rh], redm[1][rh]), fmaxf(redm[2][rh], redm[3][rh]));
    }

    float sum_lo[4] = {0.f, 0.f, 0.f, 0.f}, sum_hi[4] = {0.f, 0.f, 0.f, 0.f};
#pragma unroll
    for (int j = 0; j < 4; ++j) {
        int rl = g * 4 + j, rh = 16 + g * 4 + j;
        float ml = (mx_lo[j] == -INFINITY) ? 0.f : mx_lo[j];
        float mh = (mx_hi[j] == -INFINITY) ? 0.f : mx_hi[j];
#pragma unroll
        for (int kt = 0; kt < 16; ++kt) {
            int col = w * 256 + kt * 16 + lr;
            float vl = s_lo[kt][j];
            float vh = s_hi[kt][j];
            float el = (vl == -INFINITY) ? 0.f : __expf(vl - ml);
            float eh = (vh == -INFINITY) ? 0.f : __expf(vh - mh);
            sum_lo[j] += el;
            sum_hi[j] += eh;
            P[rl][col] = (__bf16)el;
            P[rh][col] = (__bf16)eh;
        }
    }
#pragma unroll
    for (int j = 0; j < 4; ++j) {
#pragma unroll
        for (int o = 8; o >= 1; o >>= 1) {
            sum_lo[j] += __shfl_xor(sum_lo[j], o);
            sum_hi[j] += __shfl_xor(sum_hi[j], o);
        }
    }
    if (lr == 0) {
#pragma unroll
        for (int j = 0; j < 4; ++j) {
            reds[w][g * 4 + j]      = sum_lo[j];
            reds[w][16 + g * 4 + j] = sum_hi[j];
        }
    }
    __syncthreads();

    // coalesced nontemporal attns write (32 rows)
    float* abase = attnF + (size_t)hb * 1048576 + (size_t)q0 * 1024;
#pragma unroll
    for (int i = 0; i < 16; ++i) {
        int idx = i * 256 + tid;
        int row = idx >> 7;
        int c8  = (idx & 127) * 8;
        float tot  = reds[0][row] + reds[1][row] + reds[2][row] + reds[3][row];
        float mrow = fmaxf(fmaxf(redm[0][row], redm[1][row]),
                           fmaxf(redm[2][row], redm[3][row]));
        float inv = (mrow == -INFINITY) ? 0.f : 1.0f / tot;
        bf16x8 pv = *reinterpret_cast<const bf16x8*>(&P[row][c8]);
        f32x4 f0 = {(float)pv[0] * inv, (float)pv[1] * inv,
                    (float)pv[2] * inv, (float)pv[3] * inv};
        f32x4 f1 = {(float)pv[4] * inv, (float)pv[5] * inv,
                    (float)pv[6] * inv, (float)pv[7] * inv};
        float* dst = abase + (size_t)row * 1024 + c8;
        __builtin_nontemporal_store(f0, reinterpret_cast<f32x4*>(dst));
        __builtin_nontemporal_store(f1, reinterpret_cast<f32x4*>(dst + 4));
    }

    // PV with 1-deep V prefetch; V fragment shared by both row-halves
    const __bf16* vrow = vsb + rel * stride + (size_t)(w * 16 + lr) * 1024 + g * 8;
    bf16x8 vv8 = ld8(vrow);
    f32x4 acc2l = {}, acc2h = {};
    for (int kb = 0; kb < 32; ++kb) {
        bf16x8 cur = vv8;
        if (kb < 31) vv8 = ld8(vrow + (kb + 1) * 32);
        bf16x8 pal = *reinterpret_cast<const bf16x8*>(&P[lr][kb * 32 + g * 8]);
        bf16x8 pah = *reinterpret_cast<const bf16x8*>(&P[16 + lr][kb * 32 + g * 8]);
        acc2l = MFMA(pal, cur, acc2l);
        acc2h = MFMA(pah, cur, acc2h);
    }
    int h = hb >> 3;
#pragma unroll
    for (int j = 0; j < 4; ++j) {
        int rl = g * 4 + j, rh = 16 + g * 4 + j;
        float totl = reds[0][rl] + reds[1][rl] + reds[2][rl] + reds[3][rl];
        float toth = reds[0][rh] + reds[1][rh] + reds[2][rh] + reds[3][rh];
        float ml = fmaxf(fmaxf(redm[0][rl], redm[1][rl]), fmaxf(redm[2][rl], redm[3][rl]));
        float mh = fmaxf(fmaxf(redm[0][rh], redm[1][rh]), fmaxf(redm[2][rh], redm[3][rh]));
        float invl = (ml == -INFINITY) ? 0.f : 1.0f / totl;
        float invh = (mh == -INFINITY) ? 0.f : 1.0f / toth;
        int vv = w * 16 + lr;
        x[(size_t)b * 1048576 + (size_t)(q0 + rl) * 1024 + h * 64 + vv] = (__bf16)(acc2l[j] * invl);
        x[(size_t)b * 1048576 + (size_t)(q0 + rh) * 1024 + h * 64 + vv] = (__bf16)(acc2h[j] * invh);
    }
}

// copy q_s/k_s/v_sT tail slices (hb 116..127) into reloc buffer
__global__ void reloc_kernel(const __bf16* qs, const __bf16* ks, const __bf16* vs,
                             __bf16* rel) {
    int i = blockIdx.x * 256 + threadIdx.x;  // uint4 units: 12*3*8192 = 294912
    if (i >= 294912) return;
    int hbi = i / 24576;
    int r   = i % 24576;
    int t   = r / 8192, j = r % 8192;
    const __bf16* src = ((t == 0) ? qs : (t == 1) ? ks : vs) + (size_t)(116 + hbi) * 65536;
    __bf16* dst = rel + (size_t)hbi * 196608 + t * 65536;
    reinterpret_cast<uint4*>(dst)[j] = reinterpret_cast<const uint4*>(src)[j];
}

// out fp32 rows [row0, row0+16*grid) = LN(y + pb + q)*lg + lb. No LDS; 16 rows/block.
__global__ __launch_bounds__(256, 4)
void ln_kernel(const __bf16* __restrict__ y, const float* __restrict__ pb,
               const float* __restrict__ q, const float* __restrict__ lg,
               const float* __restrict__ lb, float* __restrict__ out, int row0) {
    int tid = threadIdx.x;
    int row = tid >> 4, j16 = tid & 15;
    size_t r = (size_t)row0 + blockIdx.x * 16 + row;
    int c0 = j16 * 64;

    float v[64];
    float s1 = 0.f, s2 = 0.f;
#pragma unroll
    for (int i = 0; i < 8; ++i) {
        bf16x8 yv = ld8(y + r * 1024 + c0 + i * 8);
        float4 q0v = *(const float4*)(q + r * 1024 + c0 + i * 8);
        float4 q1v = *(const float4*)(q + r * 1024 + c0 + i * 8 + 4);
        float4 p0v = *(const float4*)(pb + c0 + i * 8);
        float4 p1v = *(const float4*)(pb + c0 + i * 8 + 4);
        float t0 = (float)yv[0] + p0v.x + q0v.x;
        float t1 = (float)yv[1] + p0v.y + q0v.y;
        float t2 = (float)yv[2] + p0v.z + q0v.z;
        float t3 = (float)yv[3] + p0v.w + q0v.w;
        float t4 = (float)yv[4] + p1v.x + q1v.x;
        float t5 = (float)yv[5] + p1v.y + q1v.y;
        float t6 = (float)yv[6] + p1v.z + q1v.z;
        float t7 = (float)yv[7] + p1v.w + q1v.w;
        v[i * 8 + 0] = t0; v[i * 8 + 1] = t1; v[i * 8 + 2] = t2; v[i * 8 + 3] = t3;
        v[i * 8 + 4] = t4; v[i * 8 + 5] = t5; v[i * 8 + 6] = t6; v[i * 8 + 7] = t7;
        s1 += t0 + t1 + t2 + t3 + t4 + t5 + t6 + t7;
        s2 += t0 * t0 + t1 * t1 + t2 * t2 + t3 * t3 + t4 * t4 + t5 * t5 + t6 * t6 + t7 * t7;
    }
#pragma unroll
    for (int m = 8; m >= 1; m >>= 1) {
        s1 += __shfl_xor(s1, m);
        s2 += __shfl_xor(s2, m);
    }
    float mu  = s1 * (1.0f / 1024.0f);
    float var = fmaxf(s2 * (1.0f / 1024.0f) - mu * mu, 0.f);
    float rs  = rsqrtf(var + 1e-5f);
#pragma unroll
    for (int i = 0; i < 16; ++i) {
        int c = c0 + i * 4;
        float4 gv = *(const float4*)(lg + c);
        float4 bv = *(const float4*)(lb + c);
        float4 o;
        o.x = (v[i * 4 + 0] - mu) * rs * gv.x + bv.x;
        o.y = (v[i * 4 + 1] - mu) * rs * gv.y + bv.y;
        o.z = (v[i * 4 + 2] - mu) * rs * gv.z + bv.z;
        o.w = (v[i * 4 + 3] - mu) * rs * gv.w + bv.w;
        *(float4*)(out + r * 1024 + c) = o;
    }
}

extern "C" void kernel_launch(void* const* d_in, const int* in_sizes, int n_in,
                              void* d_out, int out_size, void* d_ws, size_t ws_size,
                              hipStream_t stream) {
    const float* Q  = (const float*)d_in[0];
    const float* K  = (const float*)d_in[1];
    const float* V  = (const float*)d_in[2];
    const void*  M  = d_in[3];
    const float* WQ = (const float*)d_in[4];
    const float* WK = (const float*)d_in[5];
    const float* WV = (const float*)d_in[6];
    const float* PW = (const float*)d_in[7];
    const float* PB = (const float*)d_in[8];
    const float* LG = (const float*)d_in[9];
    const float* LB = (const float*)d_in[10];

    float* outF  = (float*)d_out;           // 8,388,608 fp32
    float* attnF = outF + 8388608;          // 134,217,728 fp32

    unsigned* mbits = (unsigned*)(outF + 5505024);   // out bytes [22MB,23MB), dead after fused
    __bf16*   y     = (__bf16*)(outF + 4194304);     // default: out bytes [16.7MB,33.5MB)
    bool y_in_ws = false;

    pack_mask_kernel<<<1024, 256, 0, stream>>>(M, mbits);

    __bf16* x;
    if (ws_size >= (size_t)73400320) {
        // ---------- Path A: intermediates in d_ws ----------
        char* ws = (char*)d_ws;
        __bf16* wqT  = (__bf16*)ws;                        // 2 MB
        __bf16* wkT  = (__bf16*)(ws + 2097152);            // 2 MB
        __bf16* wvT  = (__bf16*)(ws + 4194304);            // 2 MB
        __bf16* q_s  = (__bf16*)(ws + 6291456);            // 16 MB [hb][s][kk]
        __bf16* k_s  = (__bf16*)(ws + 23068672);           // 16 MB
        __bf16* v_sT = (__bf16*)(ws + 39845888);           // 16 MB [hb][vv][s]
        x            = (__bf16*)(ws + 56623104);           // 16 MB [b][s][h*64+vv]
        if (ws_size >= (size_t)90177536) {                 // +16 MB for y
            y = (__bf16*)(ws + 73400320);
            y_in_ws = true;
        }

        transpose_w_kernel<<<768, 256, 0, stream>>>(WQ, WK, WV, wqT, wkT, wvT);
        proj3_kernel<<<1536, 256, 0, stream>>>(Q, K, V, wqT, wkT, wvT, q_s, k_s, v_sT);
        fused_attn_kernel<<<4096, 256, 0, stream>>>(q_s, k_s, v_sT, (size_t)65536, 0,
                                                    mbits, attnF, x);
    } else {
        // ---------- Path B: scratch carved from d_out ----------
        __bf16* wqT  = (__bf16*)attnF;                            // chunk 0
        __bf16* wkT  = (__bf16*)(attnF + 1048576);                // chunk 1
        __bf16* wvT  = (__bf16*)(attnF + 2097152);                // chunk 2
        __bf16* q_s  = (__bf16*)(attnF + (size_t)116 * 1048576);  // chunks 116-119
        __bf16* k_s  = q_s + 8388608;                             // chunks 120-123
        __bf16* v_sT = k_s + 8388608;                             // chunks 124-127
        x            = (__bf16*)outF;                     // out bytes [0, 16.7M)
        __bf16* rel  = (__bf16*)(outF + 4194304);         // out bytes [16.7M, 21.5M)

        transpose_w_kernel<<<768, 256, 0, stream>>>(WQ, WK, WV, wqT, wkT, wvT);
        proj3_kernel<<<1536, 256, 0, stream>>>(Q, K, V, wqT, wkT, wvT, q_s, k_s, v_sT);
        fused_attn_kernel<<<32 * 116, 256, 0, stream>>>(q_s, k_s, v_sT, (size_t)65536, 0,
                                                        mbits, attnF, x);
        reloc_kernel<<<1152, 256, 0, stream>>>(q_s, k_s, v_sT, rel);
        fused_attn_kernel<<<32 * 12, 256, 0, stream>>>(rel, rel + 65536, rel + 131072,
                                                       (size_t)196608, 116, mbits, attnF, x);
    }

    // out-projection GEMM -> y
    gemm_out_kernel<<<512, 256, 0, stream>>>(x, PW, y);

    if (y_in_ws) {
        ln_kernel<<<512, 256, 0, stream>>>(y, PB, Q, LG, LB, outF, 0);
    } else {
        static const int PH[11] = {0, 4096, 6144, 7168, 7680, 7936, 8064, 8128, 8160, 8176, 8192};
        for (int p = 0; p < 10; ++p) {
            int r0 = PH[p], r1 = PH[p + 1];
            ln_kernel<<<(r1 - r0) / 16, 256, 0, stream>>>(y, PB, Q, LG, LB, outF, r0);
        }
    }
}